// Round 12
// baseline (6951.290 us; speedup 1.0000x reference)
//
#include <hip/hip_runtime.h>
#include <hip/hip_bf16.h>
#include <math.h>
#include <stdint.h>

// Problem constants
#define BATCH 1024
#define TT    256
#define DD    256
#define HH    768
#define LL    6
#define KCONV 10
#define CHW   128
#define KPACK 1024     // D + H
#define G4    3072     // 4*H interleaved gate cols
#define BNT   192      // gate cols per block tile (48 channels x 4 gates)
#define GSTR  196      // epilogue LDS row stride (floats)

// persist LDS layout (depth-6 pipeline, 7 slots)
#define NSLOT   7
#define SLOT    17408      // A 4096 + B 13312
#define GL_OFF  121856     // 32 x GSTR f32 = 25088
#define ML_OFF  146944     // 64 x 16 f32 = 4096
#define BIAS_OFF 151040    // 192+192+16+16 f32 = 1664
#define SMEM_SZ 152704

typedef __attribute__((ext_vector_type(8))) __bf16 bf16x8;
typedef __attribute__((ext_vector_type(4))) float f32x4;

__device__ __forceinline__ float sigf(float v) { return 1.0f / (1.0f + expf(-v)); }

#define SEL6(a, l) ((l)==0?a[0]:(l)==1?a[1]:(l)==2?a[2]:(l)==3?a[3]:(l)==4?a[4]:a[5])

// async global->LDS, 16B per lane; cached (L1+L2)
__device__ __forceinline__ void gload16(const void* g, void* l) {
    __builtin_amdgcn_global_load_lds(
        (const __attribute__((address_space(1))) unsigned int*)g,
        (__attribute__((address_space(3))) unsigned int*)l, 16, 0, 0);
}
// bypass L1+L2 (SC0|SC1): read from device coherence point (fresh h)
__device__ __forceinline__ void gload16_nc(const void* g, void* l) {
    __builtin_amdgcn_global_load_lds(
        (const __attribute__((address_space(1))) unsigned int*)g,
        (__attribute__((address_space(3))) unsigned int*)l, 16, 0, 0x11);
}

__device__ __forceinline__ unsigned short bf16bits(float v) {
    __hip_bfloat16 h(v);
    return *(unsigned short*)&h;
}

// per-wave counted vmcnt: wave 0 stages 3 chunks/tile, waves 1-7 stage 2
#define WAITV(a, b) do { \
    if (tid < 64) asm volatile("s_waitcnt vmcnt(" #a ")" ::: "memory"); \
    else          asm volatile("s_waitcnt vmcnt(" #b ")" ::: "memory"); \
} while (0)

// ---------------------------------------------------------------------------
// W4[n][1024] bf16, n = 4*e + q  <->  orig gate row 2L + q*H + e
// ---------------------------------------------------------------------------
__global__ __launch_bounds__(256) void prep_w4(
    const float* __restrict__ kw, const float* __restrict__ kb,
    const float* __restrict__ rw, const float* __restrict__ rb,
    __hip_bfloat16* __restrict__ W4, float* __restrict__ bias4, float* __restrict__ tco4)
{
    int n = blockIdx.x;
    int e = n >> 2, q = n & 3;
    int orig = 2 * LL + q * HH + e;
    int tid = threadIdx.x;
#pragma unroll
    for (int k = 0; k < 4; ++k) {
        int col = tid + k * 256;
        float v = (col < DD) ? kw[(size_t)orig * (DD + 1) + col]
                             : rw[(size_t)orig * (HH + 1) + (col - DD)];
        W4[(size_t)n * KPACK + col] = __hip_bfloat16(v);
    }
    if (tid == 0) {
        bias4[n] = kb[orig] + rb[orig];
        tco4[n]  = kw[(size_t)orig * (DD + 1) + DD] + rw[(size_t)orig * (HH + 1) + HH];
    }
}

// Masters: Wm[16][1024], rows 0..11 = orig rows 0..11, rows 12..15 zero.
__global__ __launch_bounds__(256) void prep_wm(
    const float* __restrict__ kw, const float* __restrict__ kb,
    const float* __restrict__ rw, const float* __restrict__ rb,
    __hip_bfloat16* __restrict__ Wm, float* __restrict__ mbias, float* __restrict__ mtco)
{
    int j = blockIdx.x;
    int tid = threadIdx.x;
#pragma unroll
    for (int k = 0; k < 4; ++k) {
        int col = tid + k * 256;
        float v = 0.0f;
        if (j < 12)
            v = (col < DD) ? kw[(size_t)j * (DD + 1) + col]
                           : rw[(size_t)j * (HH + 1) + (col - DD)];
        Wm[(size_t)j * KPACK + col] = __hip_bfloat16(v);
    }
    if (tid == 0 && j < 12) {
        mbias[j] = kb[j] + rb[j];
        mtco[j]  = kw[(size_t)j * (DD + 1) + DD] + rw[(size_t)j * (HH + 1) + HH];
    }
}

__global__ __launch_bounds__(256) void cvt_kernel(
    const float* __restrict__ src, __hip_bfloat16* __restrict__ dst, int n)
{
    int i = blockIdx.x * 256 + threadIdx.x;
    if (i < n) dst[i] = __hip_bfloat16(src[i]);
}

// x[b][t][d] fp32 -> xb[t][b][d] bf16 (one-time)
__global__ __launch_bounds__(256) void xcvt_kernel(
    const float* __restrict__ x, __hip_bfloat16* __restrict__ xb)
{
    size_t o = ((size_t)blockIdx.x * 256 + threadIdx.x) * 8;
    int t = (int)(o >> 18);
    int b = (int)(o >> 8) & 1023;
    int d = (int)(o & 255);
    const float* src = x + ((size_t)b * TT + t) * DD + d;
    float4 a = *(const float4*)src;
    float4 c = *(const float4*)(src + 4);
    unsigned short tmp[8];
    tmp[0] = bf16bits(a.x); tmp[1] = bf16bits(a.y);
    tmp[2] = bf16bits(a.z); tmp[3] = bf16bits(a.w);
    tmp[4] = bf16bits(c.x); tmp[5] = bf16bits(c.y);
    tmp[6] = bf16bits(c.z); tmp[7] = bf16bits(c.w);
    *(uint4*)((char*)xb + o * 2) = *(const uint4*)tmp;
}

// ---------------------------------------------------------------------------
// Persistent fused recurrence (structure = round 11; all addressing hoisted).
// 256 blocks (16 bm x 16 bn), 512 threads = 8 waves (2x4), wave 32x48.
// Group-local sync (16 bm-groups of 16 blocks; 16 counters 256B apart).
// Depth-6 staging pipeline over 7 LDS slots; k-loop fully unrolled so slot
// offsets / tile offsets / x-vs-h branch / wait counts are compile-time.
// ---------------------------------------------------------------------------
__global__ __launch_bounds__(512, 1) void persist_kernel(
    __hip_bfloat16* __restrict__ Hb0,
    __hip_bfloat16* __restrict__ Hb1,
    const __hip_bfloat16* __restrict__ xb,
    const float* __restrict__ timep,
    const __hip_bfloat16* __restrict__ W4,
    const __hip_bfloat16* __restrict__ Wm,
    const float* __restrict__ bias4, const float* __restrict__ tco4,
    const float* __restrict__ mbias, const float* __restrict__ mtco,
    float* __restrict__ hwin,
    float* __restrict__ distp,
    unsigned* __restrict__ cnt)
{
    __shared__ __align__(16) char smem[SMEM_SZ];
    float* gl    = (float*)(smem + GL_OFF);    // 32 x GSTR
    float* ml    = (float*)(smem + ML_OFF);    // 64 x 16
    float* biasL = (float*)(smem + BIAS_OFF);  // 192
    float* tcoL  = biasL + 192;
    float* mbL   = tcoL + 192;
    float* mtL   = mbL + 16;

    const int tid = threadIdx.x;
    const int bid = blockIdx.x;
    const int swz = (bid & 7) * 32 + (bid >> 3);   // XCD swizzle
    const int bm = swz & 15;
    const int bn = swz >> 4;

    const int lane = tid & 63;
    const int wid  = tid >> 6;
    const int wr   = wid >> 2, wc = wid & 3;       // 2 x 4 wave grid
    const int kg   = lane >> 4;
    const int r15  = lane & 15;
    const bool domast = (wid == 3) || (wid == 4);
    const int rq = tid >> 4, q16 = tid & 15;       // cell mapping per phase
    unsigned* cntg = cnt + bm * 64;                // group counter (256B apart)

    if (tid < 192) { biasL[tid] = bias4[bn * BNT + tid]; tcoL[tid] = tco4[bn * BNT + tid]; }
    if (tid >= 256 && tid < 268) { mbL[tid - 256] = mbias[tid - 256]; mtL[tid - 256] = mtco[tid - 256]; }
    __syncthreads();

    // ---- hoisted per-thread bias/tcoef registers ----
    float gb[12], gt[12], mb[12], mt[12];
#pragma unroll
    for (int i = 0; i < 12; ++i) {
        gb[i] = biasL[q16 * 12 + i];
        gt[i] = tcoL[q16 * 12 + i];
        mb[i] = mbL[i];
        mt[i] = mtL[i];
    }

    float cst[6] = {0.f, 0.f, 0.f, 0.f, 0.f, 0.f};

    // ---- hoisted staging descriptors ----
    // A chunk (tid<256): c = tid
    const int rowA = tid >> 2, kcA = tid & 3;
    const int swA  = kcA ^ ((rowA >> 1) & 3);
    const size_t aXoff = ((size_t)(bm * 64 + rowA) * DD + swA * 8) * 2;  // byte
    const size_t aHoff = ((size_t)(bm * 64 + rowA) * HH + swA * 8) * 2;  // byte
    const int aLds = tid * 16;
    // B chunks: cb0 = tid-256 (tid>=256), cb1 = tid+256, cb2 = tid+768 (tid<64)
    auto bptr = [&](int cb) -> const char* {
        int row = cb >> 2, kc = cb & 3;
        int sw = kc ^ ((row >> 1) & 3);
        const __hip_bfloat16* src = (row < BNT)
            ? W4 + (size_t)(bn * BNT + row) * KPACK + sw * 8
            : Wm + (size_t)(row - BNT) * KPACK + sw * 8;
        return (const char*)src;
    };
    const char* bsrc0 = (tid >= 256) ? bptr(tid - 256) : (const char*)W4;
    const char* bsrc1 = bptr(tid + 256);
    const char* bsrc2 = (tid < 64) ? bptr(tid + 768) : (const char*)W4;
    const int bLds0 = 4096 + (tid - 256) * 16;
    const int bLds1 = 4096 + (tid + 256) * 16;
    const int bLds2 = 4096 + (tid + 768) * 16;

    // ---- hoisted compute frag LDS byte offsets ----
    int aOff[2], bOff[3];
#pragma unroll
    for (int m = 0; m < 2; ++m) {
        int ar = wr * 32 + m * 16 + r15;
        aOff[m] = (ar * 32 + ((kg ^ ((ar >> 1) & 3)) * 8)) * 2;
    }
#pragma unroll
    for (int n = 0; n < 3; ++n) {
        int br = wc * 48 + n * 16 + r15;
        bOff[n] = 4096 + (br * 32 + ((kg ^ ((br >> 1) & 3)) * 8)) * 2;
    }
    const int mrr = BNT + r15;
    const int mOff = 4096 + (mrr * 32 + ((kg ^ ((mrr >> 1) & 3)) * 8)) * 2;

    const char* hb0c = (const char*)Hb0;
    const char* hb1c = (const char*)Hb1;
    const char* xbt  = (const char*)xb;   // advances BATCH*DD*2 per step

    // stage tile `tile` into slot byte offset `slotOff` (compile-time under unroll)
    auto stage = [&](int slotOff, int tile, const char* xsrcT, const char* hbb) {
        const int toff = tile * 64;
        if (tid < 256) {
            if (tile < 8) gload16(xsrcT + aXoff + toff, smem + slotOff + aLds);
            else          gload16_nc(hbb + aHoff + (toff - 512), smem + slotOff + aLds);
        } else {
            gload16(bsrc0 + toff, smem + slotOff + bLds0);
        }
        gload16(bsrc1 + toff, smem + slotOff + bLds1);
        if (tid < 64) gload16(bsrc2 + toff, smem + slotOff + bLds2);
    };

    // initial prologue: tiles 0..5 of step 0 (all x, no h dep)
    stage(0 * SLOT, 0, xbt, hb0c); stage(1 * SLOT, 1, xbt, hb0c);
    stage(2 * SLOT, 2, xbt, hb0c); stage(3 * SLOT, 3, xbt, hb0c);
    stage(4 * SLOT, 4, xbt, hb0c); stage(5 * SLOT, 5, xbt, hb0c);

    for (int t = 0; t < TT; ++t) {
        const char* hbb = (t & 1) ? hb1c : hb0c;
        __hip_bfloat16* hbW = (t & 1) ? Hb0 : Hb1;

        f32x4 acc[2][3], accm[2];
#pragma unroll
        for (int m = 0; m < 2; ++m) {
#pragma unroll
            for (int n = 0; n < 3; ++n) acc[m][n] = (f32x4){0.f, 0.f, 0.f, 0.f};
            accm[m] = (f32x4){0.f, 0.f, 0.f, 0.f};
        }

        auto compute = [&](int slotOff) {
            const char* base = smem + slotOff;
            bf16x8 af[2], bv[3];
#pragma unroll
            for (int m = 0; m < 2; ++m) af[m] = *(const bf16x8*)(base + aOff[m]);
#pragma unroll
            for (int n = 0; n < 3; ++n) bv[n] = *(const bf16x8*)(base + bOff[n]);
#pragma unroll
            for (int m = 0; m < 2; ++m)
#pragma unroll
                for (int n = 0; n < 3; ++n)
                    acc[m][n] = __builtin_amdgcn_mfma_f32_16x16x32_bf16(
                        af[m], bv[n], acc[m][n], 0, 0, 0);
            if (domast) {
                bf16x8 bmf = *(const bf16x8*)(base + mOff);
#pragma unroll
                for (int m = 0; m < 2; ++m)
                    accm[m] = __builtin_amdgcn_mfma_f32_16x16x32_bf16(
                        af[m], bmf, accm[m], 0, 0, 0);
            }
        };

        // fully-unrolled k-loop: slots / tiles / waits compile-time
#pragma unroll
        for (int it = 0; it < 32; ++it) {
            if (it <= 26)      WAITV(15, 10);
            else if (it == 27) WAITV(12, 8);
            else if (it == 28) WAITV(9, 6);
            else if (it == 29) WAITV(6, 4);
            else if (it == 30) WAITV(3, 2);
            else { asm volatile("s_waitcnt vmcnt(0)" ::: "memory"); }
            __builtin_amdgcn_s_barrier();
            if (it <= 25) stage(((it + 6) % NSLOT) * SLOT, it + 6, xbt, hbb);
            compute((it % NSLOT) * SLOT);
        }

        // ---- epilogue: masters -> ml (all 64 rows), gates in 2 row-phases ----
        if (domast) {
#pragma unroll
            for (int m = 0; m < 2; ++m) {
                int rw0 = wr * 32 + m * 16 + kg * 4;
#pragma unroll
                for (int j = 0; j < 4; ++j)
                    ml[(rw0 + j) * 16 + r15] = accm[m][j];
            }
        }

        auto cellPhase = [&](int p) {
            const int bp = bm * 64 + p * 32 + rq;
            const float tv = timep[(size_t)bp * TT + t];
            float mv[12];
#pragma unroll
            for (int i2 = 0; i2 < 12; ++i2)
                mv[i2] = ml[(p * 32 + rq) * 16 + i2] + mb[i2] + tv * mt[i2];
            float mxf = mv[0], mxi = mv[6];
#pragma unroll
            for (int i2 = 1; i2 < 6; ++i2) { mxf = fmaxf(mxf, mv[i2]); mxi = fmaxf(mxi, mv[6 + i2]); }
            float fr[6], ir[6];
            float sf = 0.f, si = 0.f;
#pragma unroll
            for (int i2 = 0; i2 < 6; ++i2) {
                fr[i2] = expf(mv[i2] - mxf);     sf += fr[i2];
                ir[i2] = expf(mv[6 + i2] - mxi); si += ir[i2];
            }
            float fm[6], im[6];
            float rsf = 1.0f / sf, rsi = 1.0f / si;
            fm[0] = fr[0] * rsf;
#pragma unroll
            for (int i2 = 1; i2 < 6; ++i2) fm[i2] = fm[i2 - 1] + fr[i2] * rsf;
            im[5] = ir[5] * rsi;
#pragma unroll
            for (int i2 = 4; i2 >= 0; --i2) im[i2] = im[i2 + 1] + ir[i2] * rsi;

            if (bn == 0 && q16 == 0) {
                float dist = 1.0f - (fm[0] + fm[1] + fm[2] + fm[3] + fm[4] + fm[5]) * (1.0f / 6.0f);
                distp[(size_t)t * BATCH + bp] = dist;
            }

            const int e0 = bn * 48 + q16 * 3;
            const int lA = e0 >> 7, lB = (e0 + 2) >> 7;
            const float fmA = SEL6(fm, lA), imA = SEL6(im, lA);
            const float fmB = SEL6(fm, lB), imB = SEL6(im, lB);

            const bool wh = (t >= TT - KCONV);
            float* hw = hwin + (size_t)(t % KCONV) * BATCH * HH + (size_t)bp * HH;

            unsigned short hsv[3];
#pragma unroll
            for (int j = 0; j < 3; ++j) {
                int el = q16 * 3 + j;
                int e  = bn * 48 + el;
                f32x4 gv = *(const f32x4*)&gl[rq * GSTR + el * 4];
                float fg = sigf(gv[0] + gb[j * 4 + 0] + tv * gt[j * 4 + 0]);
                float ig = sigf(gv[1] + gb[j * 4 + 1] + tv * gt[j * 4 + 1]);
                float og = sigf(gv[2] + gb[j * 4 + 2] + tv * gt[j * 4 + 2]);
                float ci = tanhf(gv[3] + gb[j * 4 + 3] + tv * gt[j * 4 + 3]);
                float cl = cst[p * 3 + j];
                bool hi = (e >> 7) != lA;
                float fmv = hi ? fmB : fmA;
                float imv = hi ? imB : imA;
                float ov = fmv * imv;
                float cn = ov * (fg * cl + ig * ci) + (fmv - ov) * cl + (imv - ov) * ci;
                float hn = og * tanhf(cn);
                cst[p * 3 + j] = cn;
                hsv[j] = bf16bits(hn);
                if (wh) hw[e] = hn;
            }
            unsigned w0 = (unsigned)hsv[0] | ((unsigned)hsv[1] << 16);
            unsigned w1 = (unsigned)hsv[2];
            uint64_t ad = (uint64_t)(uintptr_t)(hbW + (size_t)bp * HH + e0);
            asm volatile(
                "global_store_dword %0, %1, off sc0 sc1\n\t"
                "global_store_short %0, %2, off offset:4 sc0 sc1"
                :: "v"(ad), "v"(w0), "v"(w1) : "memory");
        };

        // phase 0: rows 0..31
        if (wr == 0) {
#pragma unroll
            for (int m = 0; m < 2; ++m)
#pragma unroll
                for (int n = 0; n < 3; ++n) {
                    int col = wc * 48 + n * 16 + r15;
                    int rw0 = m * 16 + kg * 4;
#pragma unroll
                    for (int j = 0; j < 4; ++j)
                        gl[(rw0 + j) * GSTR + col] = acc[m][n][j];
                }
        }
        __syncthreads();
        cellPhase(0);
        __syncthreads();
        // phase 1: rows 32..63
        if (wr == 1) {
#pragma unroll
            for (int m = 0; m < 2; ++m)
#pragma unroll
                for (int n = 0; n < 3; ++n) {
                    int col = wc * 48 + n * 16 + r15;
                    int rw0 = m * 16 + kg * 4;
#pragma unroll
                    for (int j = 0; j < 4; ++j)
                        gl[(rw0 + j) * GSTR + col] = acc[m][n][j];
                }
        }
        __syncthreads();
        cellPhase(1);

        // ---- group barrier (16 participants) + overlapped x/W prefetch ----
        xbt += (size_t)BATCH * DD * 2;
        if (t + 1 < TT) {
            asm volatile("s_waitcnt vmcnt(0)" ::: "memory");  // h stores acked
            stage(0 * SLOT, 0, xbt, hbb); stage(1 * SLOT, 1, xbt, hbb);
            stage(2 * SLOT, 2, xbt, hbb); stage(3 * SLOT, 3, xbt, hbb);
            stage(4 * SLOT, 4, xbt, hbb); stage(5 * SLOT, 5, xbt, hbb);
            __builtin_amdgcn_s_barrier();                     // raw: no vm drain
            if (tid == 0) {
                __hip_atomic_fetch_add(cntg, 1u, __ATOMIC_RELAXED, __HIP_MEMORY_SCOPE_AGENT);
                unsigned target = (unsigned)(t + 1) * 16u;
                while (__hip_atomic_load(cntg, __ATOMIC_RELAXED, __HIP_MEMORY_SCOPE_AGENT) < target)
                    __builtin_amdgcn_s_sleep(1);
            }
            __builtin_amdgcn_s_barrier();
        }
    }
}

// ---------------------------------------------------------------------------
// bf16 MFMA NT GEMM for the conv einsum tail.
// ---------------------------------------------------------------------------
template <int SPLIT>
__global__ __launch_bounds__(256, 2) void gemm_mfma(
    const __hip_bfloat16* __restrict__ A, int lda,
    const __hip_bfloat16* __restrict__ W, int ldw,
    float* __restrict__ C, int ldc, size_t cstride, int Kdim, int nbm, int nbn)
{
    __shared__ unsigned short As[2][64 * 64];
    __shared__ unsigned short Bs[2][128 * 64];

    const int nwg = nbm * nbn * SPLIT;
    const int cpx = nwg >> 3;
    const int bid = blockIdx.x;
    const int swz = (bid & 7) * cpx + (bid >> 3);
    const int z   = swz % SPLIT;
    const int t2  = swz / SPLIT;
    const int bm  = t2 % nbm;
    const int bn  = t2 / nbm;
    const int kspan = Kdim / SPLIT;

    const int tid  = threadIdx.x;
    const int lane = tid & 63;
    const int wid  = tid >> 6;
    const int wr   = wid >> 1, wc = wid & 1;
    const int kg   = lane >> 4;
    const int r15  = lane & 15;

    f32x4 acc[2][4];
#pragma unroll
    for (int m = 0; m < 2; ++m)
#pragma unroll
        for (int n = 0; n < 4; ++n) acc[m][n] = (f32x4){0.f, 0.f, 0.f, 0.f};

    const __hip_bfloat16* Abase = A + (size_t)(bm * 64) * lda + (size_t)z * kspan;
    const __hip_bfloat16* Wbase = W + (size_t)(bn * 128) * ldw + (size_t)z * kspan;

    auto stage = [&](int buf, int k0) {
        unsigned short* Ad = &As[buf][0];
        unsigned short* Bd = &Bs[buf][0];
#pragma unroll
        for (int i = 0; i < 2; ++i) {
            int c = tid + i * 256;
            int row = c >> 3, kc = c & 7;
            gload16(Abase + (size_t)row * lda + k0 + ((kc ^ (row & 7)) * 8), Ad + c * 8);
        }
#pragma unroll
        for (int i = 0; i < 4; ++i) {
            int c = tid + i * 256;
            int row = c >> 3, kc = c & 7;
            gload16(Wbase + (size_t)row * ldw + k0 + ((kc ^ (row & 7)) * 8), Bd + c * 8);
        }
    };

    const int NIT = kspan / 64;
    stage(0, 0);
    int cur = 0;
    for (int it = 0; it < NIT; ++it) {
        if (it + 1 < NIT) {
            stage(cur ^ 1, (it + 1) * 64);
            asm volatile("s_waitcnt vmcnt(6)" ::: "memory");
        } else {
            asm volatile("s_waitcnt vmcnt(0)" ::: "memory");
        }
        __builtin_amdgcn_s_barrier();

#pragma unroll
        for (int ks = 0; ks < 2; ++ks) {
            const int kb = ks * 4 + kg;
            bf16x8 af[2], bv[4];
#pragma unroll
            for (int m = 0; m < 2; ++m) {
                int ar = wr * 32 + m * 16 + r15;
                af[m] = *(const bf16x8*)&As[cur][ar * 64 + ((kb ^ (ar & 7)) * 8)];
            }
#pragma unroll
            for (int n = 0; n < 4; ++n) {
                int br = wc * 64 + n * 16 + r15;
                bv[n] = *(const bf16x8*)&Bs[cur][br * 64 + ((kb ^ (br & 7)) * 8)];
            }
#pragma unroll
            for (int m = 0; m < 2; ++m)
#pragma unroll
                for (int n = 0; n < 4; ++n)
                    acc[m][n] = __builtin_amdgcn_mfma_f32_16x16x32_bf16(
                        af[m], bv[n], acc[m][n], 0, 0, 0);
        }
        __builtin_amdgcn_s_barrier();
        cur ^= 1;
    }

    float* Cp = C + (size_t)z * cstride;
    const int crow0 = bm * 64 + wr * 32 + (lane >> 4) * 4;
    const int ccol0 = bn * 128 + wc * 64 + r15;
#pragma unroll
    for (int m = 0; m < 2; ++m)
#pragma unroll
        for (int n = 0; n < 4; ++n)
#pragma unroll
            for (int j = 0; j < 4; ++j)
                Cp[(size_t)(crow0 + m * 16 + j) * ldc + ccol0 + n * 16] = acc[m][n][j];
}

// ---------------------------------------------------------------------------
// fp32 NT GEMM for the tiny tail matmuls. MODE 2: relu ; MODE 3: sigmoid
// ---------------------------------------------------------------------------
#define BM 64
#define BN 64
#define BK 32
template <int MODE>
__global__ __launch_bounds__(256) void gemm_nt(
    const float* __restrict__ A, int lda,
    const float* __restrict__ W, int ldw,
    const float* __restrict__ bias,
    float* __restrict__ C, int ldc, int M, int N, int Kdim)
{
    __shared__ float As[BK][BM + 4];
    __shared__ float Ws[BK][BN + 4];
    const int tid = threadIdx.x;
    const int bm = blockIdx.y * BM;
    const int bn = blockIdx.x * BN;
    const int tx = tid & 15;
    const int ty = tid >> 4;

    float acc[4][4];
#pragma unroll
    for (int i = 0; i < 4; ++i)
#pragma unroll
        for (int j = 0; j < 4; ++j) acc[i][j] = 0.0f;

    for (int k0 = 0; k0 < Kdim; k0 += BK) {
#pragma unroll
        for (int i = 0; i < (BM * BK) / 256; ++i) {
            int linear = tid + i * 256;
            int r = linear >> 5, kk = linear & 31;
            As[kk][r] = A[(size_t)(bm + r) * lda + k0 + kk];
        }
#pragma unroll
        for (int i = 0; i < (BN * BK) / 256; ++i) {
            int linear = tid + i * 256;
            int r = linear >> 5, kk = linear & 31;
            int gcol = bn + r;
            Ws[kk][r] = (gcol < N) ? W[(size_t)gcol * ldw + k0 + kk] : 0.0f;
        }
        __syncthreads();
#pragma unroll
        for (int kk = 0; kk < BK; ++kk) {
            float4 a4 = *(const float4*)&As[kk][ty * 4];
            float4 b4 = *(const float4*)&Ws[kk][tx * 4];
            float av[4] = {a4.x, a4.y, a4.z, a4.w};
            float bv[4] = {b4.x, b4.y, b4.z, b4.w};
#pragma unroll
            for (int i = 0; i < 4; ++i)
#pragma unroll
                for (int j = 0; j < 4; ++j)
                    acc[i][j] = fmaf(av[i], bv[j], acc[i][j]);
        }
        __syncthreads();
    }
#pragma unroll
    for (int i = 0; i < 4; ++i) {
        int row = bm + ty * 4 + i;
#pragma unroll
        for (int j = 0; j < 4; ++j) {
            int col = bn + tx * 4 + j;
            if (col < N) {
                float v = acc[i][j] + bias[col];
                if (MODE == 2) v = fmaxf(v, 0.0f);
                if (MODE == 3) v = sigf(v);
                C[(size_t)row * ldc + col] = v;
            }
        }
    }
}

// ---------------------------------------------------------------------------
__global__ __launch_bounds__(256) void window_kernel(
    const float* __restrict__ dist_out, float* __restrict__ ld)
{
    int b = blockIdx.x * blockDim.x + threadIdx.x;
    if (b >= BATCH) return;
    float w[KCONV];
    float run = 0.0f, m = -1e30f;
#pragma unroll
    for (int k = 0; k < KCONV; ++k) {
        run += dist_out[(size_t)(TT - KCONV + k) * BATCH + b];
        w[k] = run;
        m = fmaxf(m, run);
    }
    float s = 0.0f;
#pragma unroll
    for (int k = 0; k < KCONV; ++k) { w[k] = expf(w[k] - m); s += w[k]; }
    float inv = 1.0f / s;
#pragma unroll
    for (int k = 0; k < KCONV; ++k) ld[b * KCONV + k] = w[k] * inv;
}

__global__ __launch_bounds__(256) void localh_kernel(
    const float* __restrict__ hwin, const float* __restrict__ ld,
    __hip_bfloat16* __restrict__ Lhb, float* __restrict__ mh)
{
    int idx = blockIdx.x * 256 + threadIdx.x;
    int b = idx / HH;
    int e = idx - b * HH;
    float lv[KCONV];
#pragma unroll
    for (int k = 0; k < KCONV; ++k) lv[k] = ld[b * KCONV + k];
    float sum = 0.0f;
#pragma unroll
    for (int k = 0; k < KCONV; ++k) {
        int slot = (TT - KCONV + k) % KCONV;
        float v = hwin[(size_t)slot * BATCH * HH + (size_t)b * HH + e] * lv[k];
        Lhb[(size_t)b * (HH * KCONV) + e * KCONV + k] = __hip_bfloat16(v);
        sum += v;
    }
    mh[idx] = sum * (1.0f / KCONV);
}

__global__ __launch_bounds__(256) void out_kernel(
    const float* __restrict__ theme, const float* __restrict__ convp, size_t cstride,
    const float* __restrict__ conv_b, const float* __restrict__ hbuf,
    const float* __restrict__ out_w, const float* __restrict__ out_b,
    float* __restrict__ out)
{
    __shared__ float red[256];
    int b = blockIdx.x;
    float p = 0.0f;
    for (int e = threadIdx.x; e < HH; e += 256) {
        float cv = conv_b[e];
#pragma unroll
        for (int zz = 0; zz < 2; ++zz)
            cv += convp[(size_t)zz * cstride + (size_t)b * HH + e];
        p += (theme[(size_t)b * HH + e] * cv + hbuf[(size_t)b * HH + e]) * out_w[e];
    }
    red[threadIdx.x] = p;
    __syncthreads();
    for (int s = 128; s > 0; s >>= 1) {
        if (threadIdx.x < s) red[threadIdx.x] += red[threadIdx.x + s];
        __syncthreads();
    }
    if (threadIdx.x == 0) out[b] = sigf(red[0] + out_b[0]);
}

// ---------------------------------------------------------------------------
extern "C" void kernel_launch(void* const* d_in, const int* in_sizes, int n_in,
                              void* d_out, int out_size, void* d_ws, size_t ws_size,
                              hipStream_t stream)
{
    const float* x       = (const float*)d_in[0];
    const float* timep   = (const float*)d_in[1];
    const float* kw      = (const float*)d_in[2];
    const float* kb      = (const float*)d_in[3];
    const float* rw      = (const float*)d_in[4];
    const float* rb      = (const float*)d_in[5];
    const float* scale_w = (const float*)d_in[6];
    const float* scale_b = (const float*)d_in[7];
    const float* resc_w  = (const float*)d_in[8];
    const float* resc_b  = (const float*)d_in[9];
    const float* conv_w  = (const float*)d_in[10];
    const float* conv_b  = (const float*)d_in[11];
    const float* out_w   = (const float*)d_in[12];
    const float* out_b   = (const float*)d_in[13];

    float* outp  = (float*)d_out;
    float* distp = outp + BATCH;

    char* cur = (char*)d_ws;
    auto carve = [&](size_t bytes) {
        char* p = cur;
        cur += (bytes + 255) & ~(size_t)255;
        return (void*)p;
    };
    __hip_bfloat16* W4     = (__hip_bfloat16*)carve((size_t)G4 * KPACK * 2);
    __hip_bfloat16* Wm     = (__hip_bfloat16*)carve((size_t)16 * KPACK * 2);
    __hip_bfloat16* xb     = (__hip_bfloat16*)carve((size_t)TT * BATCH * DD * 2);
    __hip_bfloat16* Hb0    = (__hip_bfloat16*)carve((size_t)BATCH * HH * 2);
    __hip_bfloat16* Hb1    = (__hip_bfloat16*)carve((size_t)BATCH * HH * 2);
    __hip_bfloat16* Lhb    = (__hip_bfloat16*)carve((size_t)BATCH * HH * KCONV * 2);
    __hip_bfloat16* convwb = (__hip_bfloat16*)carve((size_t)HH * HH * KCONV * 2);
    float* bias4 = (float*)carve(G4 * 4);
    float* tco4  = (float*)carve(G4 * 4);
    float* mbias = (float*)carve(64);
    float* mtco  = (float*)carve(64);
    unsigned* cnt = (unsigned*)carve(4096);   // 16 group counters, 256B apart
    float* hwin  = (float*)carve((size_t)KCONV * BATCH * HH * 4);
    float* ld    = (float*)carve((size_t)BATCH * KCONV * 4);
    float* mh    = (float*)carve((size_t)BATCH * HH * 4);
    float* s1    = (float*)carve((size_t)BATCH * CHW * 4);
    float* theme = (float*)carve((size_t)BATCH * HH * 4);
    float* convp = (float*)carve(2 * (size_t)BATCH * HH * 4);

    hipMemsetAsync(cnt, 0, 4096, stream);
    hipMemsetAsync(Hb0, 0, (size_t)BATCH * HH * 2, stream);
    prep_w4<<<G4, 256, 0, stream>>>(kw, kb, rw, rb, W4, bias4, tco4);
    prep_wm<<<16, 256, 0, stream>>>(kw, kb, rw, rb, Wm, mbias, mtco);
    cvt_kernel<<<(HH * HH * KCONV + 255) / 256, 256, 0, stream>>>(
        conv_w, convwb, HH * HH * KCONV);
    xcvt_kernel<<<(TT * BATCH * DD / 8 + 255) / 256, 256, 0, stream>>>(x, xb);

    // persistent cooperative recurrence (all TT steps)
    {
        void* args[] = {
            (void*)&Hb0, (void*)&Hb1, (void*)&xb, (void*)&timep,
            (void*)&W4, (void*)&Wm, (void*)&bias4, (void*)&tco4,
            (void*)&mbias, (void*)&mtco, (void*)&hwin, (void*)&distp,
            (void*)&cnt
        };
        hipLaunchCooperativeKernel((void*)persist_kernel, dim3(256), dim3(512),
                                   args, 0, stream);
    }

    window_kernel<<<(BATCH + 255) / 256, 256, 0, stream>>>(distp, ld);
    localh_kernel<<<(BATCH * HH) / 256, 256, 0, stream>>>(hwin, ld, Lhb, mh);

    // conv einsum: [B,7680]bf16 x [768,7680]bf16^T, K-split x2
    gemm_mfma<2><<<16 * 6 * 2, 256, 0, stream>>>(
        Lhb, HH * KCONV, convwb, HH * KCONV, convp, HH, (size_t)BATCH * HH,
        HH * KCONV, 16, 6);
    // scale (relu): [B,768] x [128,768]^T
    gemm_nt<2><<<dim3(CHW / BN, BATCH / BM), 256, 0, stream>>>(
        mh, HH, scale_w, HH, scale_b, s1, CHW, BATCH, CHW, HH);
    // rescale (sigmoid): [B,128] x [768,128]^T
    gemm_nt<3><<<dim3(HH / BN, BATCH / BM), 256, 0, stream>>>(
        s1, CHW, resc_w, CHW, resc_b, theme, HH, BATCH, HH, CHW);

    out_kernel<<<BATCH, 256, 0, stream>>>(
        theme, convp, (size_t)BATCH * HH, conv_b,
        hwin + (size_t)((TT - 1) % KCONV) * BATCH * HH,   // h_last
        out_w, out_b, outp);
}

// Round 14
// 4804.045 us; speedup vs baseline: 1.4470x; 1.4470x over previous
//
#include <hip/hip_runtime.h>
#include <hip/hip_bf16.h>
#include <math.h>
#include <stdint.h>

// Problem constants
#define BATCH 1024
#define TT    256
#define DD    256
#define HH    768
#define LL    6
#define KCONV 10
#define CHW   128
#define KPACK 1024     // D + H
#define G4    3072     // 4*H interleaved gate cols
#define BNT   192      // gate cols per block tile (48 channels x 4 gates)
#define GSTR  196      // epilogue LDS row stride (floats)

// persist LDS layout (depth-6 pipeline, 8 slots: 2 computing + 6 in flight;
// gl/ml alias slots 0..3 post-loop)
#define NSLOT   8
#define SLOT    17408      // A 4096 + B 13312
#define NS      (NSLOT * SLOT)   // 139264
#define ML_OFF  52224      // 64 x 16 f32 (aliases slot 3)
#define BIAS_OFF 139264    // past slot region; persistent
#define SMEM_SZ 140928

typedef __attribute__((ext_vector_type(8))) __bf16 bf16x8;
typedef __attribute__((ext_vector_type(4))) float f32x4;

__device__ __forceinline__ float sigf(float v) { return 1.0f / (1.0f + expf(-v)); }

#define SEL6(a, l) ((l)==0?a[0]:(l)==1?a[1]:(l)==2?a[2]:(l)==3?a[3]:(l)==4?a[4]:a[5])

// async global->LDS, 16B per lane; cached (L1+L2)
__device__ __forceinline__ void gload16(const void* g, void* l) {
    __builtin_amdgcn_global_load_lds(
        (const __attribute__((address_space(1))) unsigned int*)g,
        (__attribute__((address_space(3))) unsigned int*)l, 16, 0, 0);
}
// bypass L1+L2 (SC0|SC1): read from device coherence point (fresh h)
__device__ __forceinline__ void gload16_nc(const void* g, void* l) {
    __builtin_amdgcn_global_load_lds(
        (const __attribute__((address_space(1))) unsigned int*)g,
        (__attribute__((address_space(3))) unsigned int*)l, 16, 0, 0x11);
}

__device__ __forceinline__ unsigned short bf16bits(float v) {
    __hip_bfloat16 h(v);
    return *(unsigned short*)&h;
}

// per-wave counted vmcnt: wave 0 stages 3 chunks/tile (6/pair), others 2 (4/pair)
#define WAITV(a, b) do { \
    if (tid < 64) asm volatile("s_waitcnt vmcnt(" #a ")" ::: "memory"); \
    else          asm volatile("s_waitcnt vmcnt(" #b ")" ::: "memory"); \
} while (0)

// ---------------------------------------------------------------------------
// W4[n][1024] bf16, n = 4*e + q  <->  orig gate row 2L + q*H + e
// ---------------------------------------------------------------------------
__global__ __launch_bounds__(256) void prep_w4(
    const float* __restrict__ kw, const float* __restrict__ kb,
    const float* __restrict__ rw, const float* __restrict__ rb,
    __hip_bfloat16* __restrict__ W4, float* __restrict__ bias4, float* __restrict__ tco4)
{
    int n = blockIdx.x;
    int e = n >> 2, q = n & 3;
    int orig = 2 * LL + q * HH + e;
    int tid = threadIdx.x;
#pragma unroll
    for (int k = 0; k < 4; ++k) {
        int col = tid + k * 256;
        float v = (col < DD) ? kw[(size_t)orig * (DD + 1) + col]
                             : rw[(size_t)orig * (HH + 1) + (col - DD)];
        W4[(size_t)n * KPACK + col] = __hip_bfloat16(v);
    }
    if (tid == 0) {
        bias4[n] = kb[orig] + rb[orig];
        tco4[n]  = kw[(size_t)orig * (DD + 1) + DD] + rw[(size_t)orig * (HH + 1) + HH];
    }
}

// Masters: Wm[16][1024], rows 0..11 = orig rows 0..11, rows 12..15 zero.
__global__ __launch_bounds__(256) void prep_wm(
    const float* __restrict__ kw, const float* __restrict__ kb,
    const float* __restrict__ rw, const float* __restrict__ rb,
    __hip_bfloat16* __restrict__ Wm, float* __restrict__ mbias, float* __restrict__ mtco)
{
    int j = blockIdx.x;
    int tid = threadIdx.x;
#pragma unroll
    for (int k = 0; k < 4; ++k) {
        int col = tid + k * 256;
        float v = 0.0f;
        if (j < 12)
            v = (col < DD) ? kw[(size_t)j * (DD + 1) + col]
                           : rw[(size_t)j * (HH + 1) + (col - DD)];
        Wm[(size_t)j * KPACK + col] = __hip_bfloat16(v);
    }
    if (tid == 0 && j < 12) {
        mbias[j] = kb[j] + rb[j];
        mtco[j]  = kw[(size_t)j * (DD + 1) + DD] + rw[(size_t)j * (HH + 1) + HH];
    }
}

__global__ __launch_bounds__(256) void cvt_kernel(
    const float* __restrict__ src, __hip_bfloat16* __restrict__ dst, int n)
{
    int i = blockIdx.x * 256 + threadIdx.x;
    if (i < n) dst[i] = __hip_bfloat16(src[i]);
}

// x[b][t][d] fp32 -> xb[t][b][d] bf16 (one-time)
__global__ __launch_bounds__(256) void xcvt_kernel(
    const float* __restrict__ x, __hip_bfloat16* __restrict__ xb)
{
    size_t o = ((size_t)blockIdx.x * 256 + threadIdx.x) * 8;
    int t = (int)(o >> 18);
    int b = (int)(o >> 8) & 1023;
    int d = (int)(o & 255);
    const float* src = x + ((size_t)b * TT + t) * DD + d;
    float4 a = *(const float4*)src;
    float4 c = *(const float4*)(src + 4);
    unsigned short tmp[8];
    tmp[0] = bf16bits(a.x); tmp[1] = bf16bits(a.y);
    tmp[2] = bf16bits(a.z); tmp[3] = bf16bits(a.w);
    tmp[4] = bf16bits(c.x); tmp[5] = bf16bits(c.y);
    tmp[6] = bf16bits(c.z); tmp[7] = bf16bits(c.w);
    *(uint4*)((char*)xb + o * 2) = *(const uint4*)tmp;
}

// ---------------------------------------------------------------------------
// Persistent fused recurrence (r11 structure; rolled loop, hoisted addressing,
// 2 tiles per barrier with 8 slots, single-phase epilogue aliased over slots).
// 256 blocks (16 bm x 16 bn), 512 threads = 8 waves (2x4), wave 32x48.
// Group-local sync (16 bm-groups of 16 blocks; 16 counters 256B apart).
// ---------------------------------------------------------------------------
__global__ __launch_bounds__(512, 1) void persist_kernel(
    __hip_bfloat16* __restrict__ Hb0,
    __hip_bfloat16* __restrict__ Hb1,
    const __hip_bfloat16* __restrict__ xb,
    const float* __restrict__ timep,
    const __hip_bfloat16* __restrict__ W4,
    const __hip_bfloat16* __restrict__ Wm,
    const float* __restrict__ bias4, const float* __restrict__ tco4,
    const float* __restrict__ mbias, const float* __restrict__ mtco,
    float* __restrict__ hwin,
    float* __restrict__ distp,
    unsigned* __restrict__ cnt)
{
    __shared__ __align__(16) char smem[SMEM_SZ];
    float* gl    = (float*)smem;               // 64 x GSTR (aliases slots 0..2)
    float* ml    = (float*)(smem + ML_OFF);    // 64 x 16 (aliases slot 3)
    float* biasL = (float*)(smem + BIAS_OFF);  // 192
    float* tcoL  = biasL + 192;
    float* mbL   = tcoL + 192;
    float* mtL   = mbL + 16;

    const int tid = threadIdx.x;
    const int bid = blockIdx.x;
    const int swz = (bid & 7) * 32 + (bid >> 3);   // XCD swizzle
    const int bm = swz & 15;
    const int bn = swz >> 4;

    const int lane = tid & 63;
    const int wid  = tid >> 6;
    const int wr   = wid >> 2, wc = wid & 3;       // 2 x 4 wave grid
    const int kg   = lane >> 4;
    const int r15  = lane & 15;
    const bool domast = (wid == 3) || (wid == 4);
    const int r  = tid >> 3;        // cell row 0..63
    const int qq = tid & 7;         // 6 channels at qq*6
    const int b  = bm * 64 + r;
    unsigned* cntg = cnt + bm * 64; // group counter (256B apart)

    if (tid < 192) { biasL[tid] = bias4[bn * BNT + tid]; tcoL[tid] = tco4[bn * BNT + tid]; }
    if (tid >= 256 && tid < 268) { mbL[tid - 256] = mbias[tid - 256]; mtL[tid - 256] = mtco[tid - 256]; }
    __syncthreads();

    float cst[6] = {0.f, 0.f, 0.f, 0.f, 0.f, 0.f};

    // ---- hoisted staging descriptors ----
    const int rowA = tid >> 2, kcA = tid & 3;
    const int swA  = kcA ^ ((rowA >> 1) & 3);
    const size_t aXoff = ((size_t)(bm * 64 + rowA) * DD + swA * 8) * 2;  // bytes
    const size_t aHoff = ((size_t)(bm * 64 + rowA) * HH + swA * 8) * 2;  // bytes
    const int aLds = tid * 16;
    auto bptr = [&](int cb) -> const char* {
        int row = cb >> 2, kc = cb & 3;
        int sw = kc ^ ((row >> 1) & 3);
        const __hip_bfloat16* src = (row < BNT)
            ? W4 + (size_t)(bn * BNT + row) * KPACK + sw * 8
            : Wm + (size_t)(row - BNT) * KPACK + sw * 8;
        return (const char*)src;
    };
    const char* bsrc0 = (tid >= 256) ? bptr(tid - 256) : (const char*)W4;
    const char* bsrc1 = bptr(tid + 256);
    const char* bsrc2 = (tid < 64) ? bptr(tid + 768) : (const char*)W4;
    const int bLds0 = 4096 + (tid - 256) * 16;
    const int bLds1 = 4096 + (tid + 256) * 16;
    const int bLds2 = 4096 + (tid + 768) * 16;

    // ---- hoisted compute frag LDS byte offsets ----
    int aOff[2], bOff[3];
#pragma unroll
    for (int m = 0; m < 2; ++m) {
        int ar = wr * 32 + m * 16 + r15;
        aOff[m] = (ar * 32 + ((kg ^ ((ar >> 1) & 3)) * 8)) * 2;
    }
#pragma unroll
    for (int n = 0; n < 3; ++n) {
        int br = wc * 48 + n * 16 + r15;
        bOff[n] = 4096 + (br * 32 + ((kg ^ ((br >> 1) & 3)) * 8)) * 2;
    }
    const int mrr = BNT + r15;
    const int mOff = 4096 + (mrr * 32 + ((kg ^ ((mrr >> 1) & 3)) * 8)) * 2;

    const char* hb0c = (const char*)Hb0;
    const char* hb1c = (const char*)Hb1;
    const char* xbt  = (const char*)xb;

    // per-step base pointers for A staging (set each step)
    const char* pxA = xbt + aXoff;
    const char* phA = hb0c + aHoff;

    auto stage = [&](int slotOff, int tile) {
        const int toff = tile * 64;
        if (tid < 256) {
            if (tile < 8) gload16(pxA + toff, smem + slotOff + aLds);
            else          gload16_nc(phA + (toff - 512), smem + slotOff + aLds);
        } else {
            gload16(bsrc0 + toff, smem + slotOff + bLds0);
        }
        gload16(bsrc1 + toff, smem + slotOff + bLds1);
        if (tid < 64) gload16(bsrc2 + toff, smem + slotOff + bLds2);
    };

    // initial prologue: tiles 0..5 of step 0 (all x, no h dep)
    stage(0 * SLOT, 0); stage(1 * SLOT, 1); stage(2 * SLOT, 2);
    stage(3 * SLOT, 3); stage(4 * SLOT, 4); stage(5 * SLOT, 5);

    for (int t = 0; t < TT; ++t) {
        const char* hbb = (t & 1) ? hb1c : hb0c;
        __hip_bfloat16* hbW = (t & 1) ? Hb0 : Hb1;
        phA = hbb + aHoff;

        f32x4 acc[2][3], accm[2];
#pragma unroll
        for (int m = 0; m < 2; ++m) {
#pragma unroll
            for (int n = 0; n < 3; ++n) acc[m][n] = (f32x4){0.f, 0.f, 0.f, 0.f};
            accm[m] = (f32x4){0.f, 0.f, 0.f, 0.f};
        }

        auto compute = [&](int slotOff) {
            const char* base = smem + slotOff;
            bf16x8 af[2], bv[3];
#pragma unroll
            for (int m = 0; m < 2; ++m) af[m] = *(const bf16x8*)(base + aOff[m]);
#pragma unroll
            for (int n = 0; n < 3; ++n) bv[n] = *(const bf16x8*)(base + bOff[n]);
#pragma unroll
            for (int m = 0; m < 2; ++m)
#pragma unroll
                for (int n = 0; n < 3; ++n)
                    acc[m][n] = __builtin_amdgcn_mfma_f32_16x16x32_bf16(
                        af[m], bv[n], acc[m][n], 0, 0, 0);
            if (domast) {
                bf16x8 bmf = *(const bf16x8*)(base + mOff);
#pragma unroll
                for (int m = 0; m < 2; ++m)
                    accm[m] = __builtin_amdgcn_mfma_f32_16x16x32_bf16(
                        af[m], bmf, accm[m], 0, 0, 0);
            }
        };

        // rolled pair loop: 2 tiles per barrier; tile k -> slot k & 7
        int c0 = 0;             // slot byte offset of tile it
        int s0 = 6 * SLOT;      // slot byte offset of tile it+6
#pragma unroll 1
        for (int it = 0; it < 32; it += 2) {
            if (it <= 26)      WAITV(12, 8);
            else if (it == 28) WAITV(6, 4);
            else { asm volatile("s_waitcnt vmcnt(0)" ::: "memory"); }
            __builtin_amdgcn_s_barrier();
            int c1 = c0 + SLOT; if (c1 >= NS) c1 -= NS;
            if (it <= 24) {
                int s1 = s0 + SLOT; if (s1 >= NS) s1 -= NS;
                stage(s0, it + 6); stage(s1, it + 7);
                s0 = s1 + SLOT; if (s0 >= NS) s0 -= NS;
            }
            compute(c0); compute(c1);
            c0 = c1 + SLOT; if (c0 >= NS) c0 -= NS;
        }
        __syncthreads();   // all ds_reads done -> gl/ml may alias slots

        // ---- epilogue: single-phase acc -> gl (64 rows), masters -> ml ----
#pragma unroll
        for (int m = 0; m < 2; ++m)
#pragma unroll
            for (int n = 0; n < 3; ++n) {
                int col = wc * 48 + n * 16 + r15;
                int rw0 = wr * 32 + m * 16 + kg * 4;
#pragma unroll
                for (int j = 0; j < 4; ++j)
                    gl[(rw0 + j) * GSTR + col] = acc[m][n][j];
            }
        if (domast) {
#pragma unroll
            for (int m = 0; m < 2; ++m) {
                int rw0 = wr * 32 + m * 16 + kg * 4;
#pragma unroll
                for (int j = 0; j < 4; ++j)
                    ml[(rw0 + j) * 16 + r15] = accm[m][j];
            }
        }
        __syncthreads();

        // ---- cell: row r, 6 channels at qq*6 ----
        const float tv = timep[(size_t)b * TT + t];

        float mv[12];
#pragma unroll
        for (int i2 = 0; i2 < 12; ++i2)
            mv[i2] = ml[r * 16 + i2] + mbL[i2] + tv * mtL[i2];

        float mxf = mv[0], mxi = mv[6];
#pragma unroll
        for (int i2 = 1; i2 < 6; ++i2) { mxf = fmaxf(mxf, mv[i2]); mxi = fmaxf(mxi, mv[6 + i2]); }
        float fr[6], ir[6];
        float sf = 0.f, si = 0.f;
#pragma unroll
        for (int i2 = 0; i2 < 6; ++i2) {
            fr[i2] = expf(mv[i2] - mxf);     sf += fr[i2];
            ir[i2] = expf(mv[6 + i2] - mxi); si += ir[i2];
        }
        float fm[6], im[6];
        float rsf = 1.0f / sf, rsi = 1.0f / si;
        fm[0] = fr[0] * rsf;
#pragma unroll
        for (int i2 = 1; i2 < 6; ++i2) fm[i2] = fm[i2 - 1] + fr[i2] * rsf;
        im[5] = ir[5] * rsi;
#pragma unroll
        for (int i2 = 4; i2 >= 0; --i2) im[i2] = im[i2 + 1] + ir[i2] * rsi;

        if (bn == 0 && qq == 0) {
            float dist = 1.0f - (fm[0] + fm[1] + fm[2] + fm[3] + fm[4] + fm[5]) * (1.0f / 6.0f);
            distp[(size_t)t * BATCH + b] = dist;
        }

        const int e0 = bn * 48 + qq * 6;
        const int l0 = e0 >> 7, l1 = (e0 + 5) >> 7;
        const float fmA = SEL6(fm, l0), imA = SEL6(im, l0);
        const float fmB = SEL6(fm, l1), imB = SEL6(im, l1);

        const bool wh = (t >= TT - KCONV);
        float* hw = hwin + (size_t)(t % KCONV) * BATCH * HH + (size_t)b * HH;

        unsigned short hsv[6];
#pragma unroll
        for (int j = 0; j < 6; ++j) {
            int el = qq * 6 + j;
            int e  = bn * 48 + el;
            f32x4 gv = *(const f32x4*)&gl[r * GSTR + el * 4];
            float fg = sigf(gv[0] + biasL[el * 4 + 0] + tv * tcoL[el * 4 + 0]);
            float ig = sigf(gv[1] + biasL[el * 4 + 1] + tv * tcoL[el * 4 + 1]);
            float og = sigf(gv[2] + biasL[el * 4 + 2] + tv * tcoL[el * 4 + 2]);
            float ci = tanhf(gv[3] + biasL[el * 4 + 3] + tv * tcoL[el * 4 + 3]);
            float cl = cst[j];
            bool hi = (e >> 7) != l0;
            float fmv = hi ? fmB : fmA;
            float imv = hi ? imB : imA;
            float ov = fmv * imv;
            float cn = ov * (fg * cl + ig * ci) + (fmv - ov) * cl + (imv - ov) * ci;
            float hn = og * tanhf(cn);
            cst[j] = cn;
            hsv[j] = bf16bits(hn);
            if (wh) hw[e] = hn;
        }
        {   // h -> hbW[b][e0..e0+5], write-through to coherence point
            unsigned w0 = (unsigned)hsv[0] | ((unsigned)hsv[1] << 16);
            unsigned w1 = (unsigned)hsv[2] | ((unsigned)hsv[3] << 16);
            unsigned w2 = (unsigned)hsv[4] | ((unsigned)hsv[5] << 16);
            uint64_t ad = (uint64_t)(uintptr_t)(hbW + (size_t)b * HH + e0);
            asm volatile(
                "global_store_dword %0, %1, off sc0 sc1\n\t"
                "global_store_dword %0, %2, off offset:4 sc0 sc1\n\t"
                "global_store_dword %0, %3, off offset:8 sc0 sc1"
                :: "v"(ad), "v"(w0), "v"(w1), "v"(w2) : "memory");
        }
        __syncthreads();   // gl/ml reads done -> prefetch may overwrite slots

        // ---- group barrier (16 participants) + overlapped x/W prefetch ----
        xbt += (size_t)BATCH * DD * 2;
        pxA = xbt + aXoff;
        if (t + 1 < TT) {
            asm volatile("s_waitcnt vmcnt(0)" ::: "memory");  // h stores acked
            stage(0 * SLOT, 0); stage(1 * SLOT, 1); stage(2 * SLOT, 2);
            stage(3 * SLOT, 3); stage(4 * SLOT, 4); stage(5 * SLOT, 5);
            __builtin_amdgcn_s_barrier();                     // raw: no vm drain
            if (tid == 0) {
                __hip_atomic_fetch_add(cntg, 1u, __ATOMIC_RELAXED, __HIP_MEMORY_SCOPE_AGENT);
                unsigned target = (unsigned)(t + 1) * 16u;
                while (__hip_atomic_load(cntg, __ATOMIC_RELAXED, __HIP_MEMORY_SCOPE_AGENT) < target)
                    __builtin_amdgcn_s_sleep(1);
            }
            __builtin_amdgcn_s_barrier();
        }
    }
}

// ---------------------------------------------------------------------------
// bf16 MFMA NT GEMM for the conv einsum tail.
// ---------------------------------------------------------------------------
template <int SPLIT>
__global__ __launch_bounds__(256, 2) void gemm_mfma(
    const __hip_bfloat16* __restrict__ A, int lda,
    const __hip_bfloat16* __restrict__ W, int ldw,
    float* __restrict__ C, int ldc, size_t cstride, int Kdim, int nbm, int nbn)
{
    __shared__ unsigned short As[2][64 * 64];
    __shared__ unsigned short Bs[2][128 * 64];

    const int nwg = nbm * nbn * SPLIT;
    const int cpx = nwg >> 3;
    const int bid = blockIdx.x;
    const int swz = (bid & 7) * cpx + (bid >> 3);
    const int z   = swz % SPLIT;
    const int t2  = swz / SPLIT;
    const int bm  = t2 % nbm;
    const int bn  = t2 / nbm;
    const int kspan = Kdim / SPLIT;

    const int tid  = threadIdx.x;
    const int lane = tid & 63;
    const int wid  = tid >> 6;
    const int wr   = wid >> 1, wc = wid & 1;
    const int kg   = lane >> 4;
    const int r15  = lane & 15;

    f32x4 acc[2][4];
#pragma unroll
    for (int m = 0; m < 2; ++m)
#pragma unroll
        for (int n = 0; n < 4; ++n) acc[m][n] = (f32x4){0.f, 0.f, 0.f, 0.f};

    const __hip_bfloat16* Abase = A + (size_t)(bm * 64) * lda + (size_t)z * kspan;
    const __hip_bfloat16* Wbase = W + (size_t)(bn * 128) * ldw + (size_t)z * kspan;

    auto stage = [&](int buf, int k0) {
        unsigned short* Ad = &As[buf][0];
        unsigned short* Bd = &Bs[buf][0];
#pragma unroll
        for (int i = 0; i < 2; ++i) {
            int c = tid + i * 256;
            int row = c >> 3, kc = c & 7;
            gload16(Abase + (size_t)row * lda + k0 + ((kc ^ (row & 7)) * 8), Ad + c * 8);
        }
#pragma unroll
        for (int i = 0; i < 4; ++i) {
            int c = tid + i * 256;
            int row = c >> 3, kc = c & 7;
            gload16(Wbase + (size_t)row * ldw + k0 + ((kc ^ (row & 7)) * 8), Bd + c * 8);
        }
    };

    const int NIT = kspan / 64;
    stage(0, 0);
    int cur = 0;
    for (int it = 0; it < NIT; ++it) {
        if (it + 1 < NIT) {
            stage(cur ^ 1, (it + 1) * 64);
            asm volatile("s_waitcnt vmcnt(6)" ::: "memory");
        } else {
            asm volatile("s_waitcnt vmcnt(0)" ::: "memory");
        }
        __builtin_amdgcn_s_barrier();

#pragma unroll
        for (int ks = 0; ks < 2; ++ks) {
            const int kb = ks * 4 + kg;
            bf16x8 af[2], bv[4];
#pragma unroll
            for (int m = 0; m < 2; ++m) {
                int ar = wr * 32 + m * 16 + r15;
                af[m] = *(const bf16x8*)&As[cur][ar * 64 + ((kb ^ (ar & 7)) * 8)];
            }
#pragma unroll
            for (int n = 0; n < 4; ++n) {
                int br = wc * 64 + n * 16 + r15;
                bv[n] = *(const bf16x8*)&Bs[cur][br * 64 + ((kb ^ (br & 7)) * 8)];
            }
#pragma unroll
            for (int m = 0; m < 2; ++m)
#pragma unroll
                for (int n = 0; n < 4; ++n)
                    acc[m][n] = __builtin_amdgcn_mfma_f32_16x16x32_bf16(
                        af[m], bv[n], acc[m][n], 0, 0, 0);
        }
        __builtin_amdgcn_s_barrier();
        cur ^= 1;
    }

    float* Cp = C + (size_t)z * cstride;
    const int crow0 = bm * 64 + wr * 32 + (lane >> 4) * 4;
    const int ccol0 = bn * 128 + wc * 64 + r15;
#pragma unroll
    for (int m = 0; m < 2; ++m)
#pragma unroll
        for (int n = 0; n < 4; ++n)
#pragma unroll
            for (int j = 0; j < 4; ++j)
                Cp[(size_t)(crow0 + m * 16 + j) * ldc + ccol0 + n * 16] = acc[m][n][j];
}

// ---------------------------------------------------------------------------
// fp32 NT GEMM for the tiny tail matmuls. MODE 2: relu ; MODE 3: sigmoid
// ---------------------------------------------------------------------------
#define BM 64
#define BN 64
#define BK 32
template <int MODE>
__global__ __launch_bounds__(256) void gemm_nt(
    const float* __restrict__ A, int lda,
    const float* __restrict__ W, int ldw,
    const float* __restrict__ bias,
    float* __restrict__ C, int ldc, int M, int N, int Kdim)
{
    __shared__ float As[BK][BM + 4];
    __shared__ float Ws[BK][BN + 4];
    const int tid = threadIdx.x;
    const int bm = blockIdx.y * BM;
    const int bn = blockIdx.x * BN;
    const int tx = tid & 15;
    const int ty = tid >> 4;

    float acc[4][4];
#pragma unroll
    for (int i = 0; i < 4; ++i)
#pragma unroll
        for (int j = 0; j < 4; ++j) acc[i][j] = 0.0f;

    for (int k0 = 0; k0 < Kdim; k0 += BK) {
#pragma unroll
        for (int i = 0; i < (BM * BK) / 256; ++i) {
            int linear = tid + i * 256;
            int r = linear >> 5, kk = linear & 31;
            As[kk][r] = A[(size_t)(bm + r) * lda + k0 + kk];
        }
#pragma unroll
        for (int i = 0; i < (BN * BK) / 256; ++i) {
            int linear = tid + i * 256;
            int r = linear >> 5, kk = linear & 31;
            int gcol = bn + r;
            Ws[kk][r] = (gcol < N) ? W[(size_t)gcol * ldw + k0 + kk] : 0.0f;
        }
        __syncthreads();
#pragma unroll
        for (int kk = 0; kk < BK; ++kk) {
            float4 a4 = *(const float4*)&As[kk][ty * 4];
            float4 b4 = *(const float4*)&Ws[kk][tx * 4];
            float av[4] = {a4.x, a4.y, a4.z, a4.w};
            float bv[4] = {b4.x, b4.y, b4.z, b4.w};
#pragma unroll
            for (int i = 0; i < 4; ++i)
#pragma unroll
                for (int j = 0; j < 4; ++j)
                    acc[i][j] = fmaf(av[i], bv[j], acc[i][j]);
        }
        __syncthreads();
    }
#pragma unroll
    for (int i = 0; i < 4; ++i) {
        int row = bm + ty * 4 + i;
#pragma unroll
        for (int j = 0; j < 4; ++j) {
            int col = bn + tx * 4 + j;
            if (col < N) {
                float v = acc[i][j] + bias[col];
                if (MODE == 2) v = fmaxf(v, 0.0f);
                if (MODE == 3) v = sigf(v);
                C[(size_t)row * ldc + col] = v;
            }
        }
    }
}

// ---------------------------------------------------------------------------
__global__ __launch_bounds__(256) void window_kernel(
    const float* __restrict__ dist_out, float* __restrict__ ld)
{
    int b = blockIdx.x * blockDim.x + threadIdx.x;
    if (b >= BATCH) return;
    float w[KCONV];
    float run = 0.0f, m = -1e30f;
#pragma unroll
    for (int k = 0; k < KCONV; ++k) {
        run += dist_out[(size_t)(TT - KCONV + k) * BATCH + b];
        w[k] = run;
        m = fmaxf(m, run);
    }
    float s = 0.0f;
#pragma unroll
    for (int k = 0; k < KCONV; ++k) { w[k] = expf(w[k] - m); s += w[k]; }
    float inv = 1.0f / s;
#pragma unroll
    for (int k = 0; k < KCONV; ++k) ld[b * KCONV + k] = w[k] * inv;
}

__global__ __launch_bounds__(256) void localh_kernel(
    const float* __restrict__ hwin, const float* __restrict__ ld,
    __hip_bfloat16* __restrict__ Lhb, float* __restrict__ mh)
{
    int idx = blockIdx.x * 256 + threadIdx.x;
    int b = idx / HH;
    int e = idx - b * HH;
    float lv[KCONV];
#pragma unroll
    for (int k = 0; k < KCONV; ++k) lv[k] = ld[b * KCONV + k];
    float sum = 0.0f;
#pragma unroll
    for (int k = 0; k < KCONV; ++k) {
        int slot = (TT - KCONV + k) % KCONV;
        float v = hwin[(size_t)slot * BATCH * HH + (size_t)b * HH + e] * lv[k];
        Lhb[(size_t)b * (HH * KCONV) + e * KCONV + k] = __hip_bfloat16(v);
        sum += v;
    }
    mh[idx] = sum * (1.0f / KCONV);
}

__global__ __launch_bounds__(256) void out_kernel(
    const float* __restrict__ theme, const float* __restrict__ convp, size_t cstride,
    const float* __restrict__ conv_b, const float* __restrict__ hbuf,
    const float* __restrict__ out_w, const float* __restrict__ out_b,
    float* __restrict__ out)
{
    __shared__ float red[256];
    int b = blockIdx.x;
    float p = 0.0f;
    for (int e = threadIdx.x; e < HH; e += 256) {
        float cv = conv_b[e];
#pragma unroll
        for (int zz = 0; zz < 2; ++zz)
            cv += convp[(size_t)zz * cstride + (size_t)b * HH + e];
        p += (theme[(size_t)b * HH + e] * cv + hbuf[(size_t)b * HH + e]) * out_w[e];
    }
    red[threadIdx.x] = p;
    __syncthreads();
    for (int s = 128; s > 0; s >>= 1) {
        if (threadIdx.x < s) red[threadIdx.x] += red[threadIdx.x + s];
        __syncthreads();
    }
    if (threadIdx.x == 0) out[b] = sigf(red[0] + out_b[0]);
}

// ---------------------------------------------------------------------------
extern "C" void kernel_launch(void* const* d_in, const int* in_sizes, int n_in,
                              void* d_out, int out_size, void* d_ws, size_t ws_size,
                              hipStream_t stream)
{
    const float* x       = (const float*)d_in[0];
    const float* timep   = (const float*)d_in[1];
    const float* kw      = (const float*)d_in[2];
    const float* kb      = (const float*)d_in[3];
    const float* rw      = (const float*)d_in[4];
    const float* rb      = (const float*)d_in[5];
    const float* scale_w = (const float*)d_in[6];
    const float* scale_b = (const float*)d_in[7];
    const float* resc_w  = (const float*)d_in[8];
    const float* resc_b  = (const float*)d_in[9];
    const float* conv_w  = (const float*)d_in[10];
    const float* conv_b  = (const float*)d_in[11];
    const float* out_w   = (const float*)d_in[12];
    const float* out_b   = (const float*)d_in[13];

    float* outp  = (float*)d_out;
    float* distp = outp + BATCH;

    char* cur = (char*)d_ws;
    auto carve = [&](size_t bytes) {
        char* p = cur;
        cur += (bytes + 255) & ~(size_t)255;
        return (void*)p;
    };
    __hip_bfloat16* W4     = (__hip_bfloat16*)carve((size_t)G4 * KPACK * 2);
    __hip_bfloat16* Wm     = (__hip_bfloat16*)carve((size_t)16 * KPACK * 2);
    __hip_bfloat16* xb     = (__hip_bfloat16*)carve((size_t)TT * BATCH * DD * 2);
    __hip_bfloat16* Hb0    = (__hip_bfloat16*)carve((size_t)BATCH * HH * 2);
    __hip_bfloat16* Hb1    = (__hip_bfloat16*)carve((size_t)BATCH * HH * 2);
    __hip_bfloat16* Lhb    = (__hip_bfloat16*)carve((size_t)BATCH * HH * KCONV * 2);
    __hip_bfloat16* convwb = (__hip_bfloat16*)carve((size_t)HH * HH * KCONV * 2);
    float* bias4 = (float*)carve(G4 * 4);
    float* tco4  = (float*)carve(G4 * 4);
    float* mbias = (float*)carve(64);
    float* mtco  = (float*)carve(64);
    unsigned* cnt = (unsigned*)carve(4096);   // 16 group counters, 256B apart
    float* hwin  = (float*)carve((size_t)KCONV * BATCH * HH * 4);
    float* ld    = (float*)carve((size_t)BATCH * KCONV * 4);
    float* mh    = (float*)carve((size_t)BATCH * HH * 4);
    float* s1    = (float*)carve((size_t)BATCH * CHW * 4);
    float* theme = (float*)carve((size_t)BATCH * HH * 4);
    float* convp = (float*)carve(2 * (size_t)BATCH * HH * 4);

    hipMemsetAsync(cnt, 0, 4096, stream);
    hipMemsetAsync(Hb0, 0, (size_t)BATCH * HH * 2, stream);
    prep_w4<<<G4, 256, 0, stream>>>(kw, kb, rw, rb, W4, bias4, tco4);
    prep_wm<<<16, 256, 0, stream>>>(kw, kb, rw, rb, Wm, mbias, mtco);
    cvt_kernel<<<(HH * HH * KCONV + 255) / 256, 256, 0, stream>>>(
        conv_w, convwb, HH * HH * KCONV);
    xcvt_kernel<<<(TT * BATCH * DD / 8 + 255) / 256, 256, 0, stream>>>(x, xb);

    // persistent cooperative recurrence (all TT steps)
    {
        void* args[] = {
            (void*)&Hb0, (void*)&Hb1, (void*)&xb, (void*)&timep,
            (void*)&W4, (void*)&Wm, (void*)&bias4, (void*)&tco4,
            (void*)&mbias, (void*)&mtco, (void*)&hwin, (void*)&distp,
            (void*)&cnt
        };
        hipLaunchCooperativeKernel((void*)persist_kernel, dim3(256), dim3(512),
                                   args, 0, stream);
    }

    window_kernel<<<(BATCH + 255) / 256, 256, 0, stream>>>(distp, ld);
    localh_kernel<<<(BATCH * HH) / 256, 256, 0, stream>>>(hwin, ld, Lhb, mh);

    // conv einsum: [B,7680]bf16 x [768,7680]bf16^T, K-split x2
    gemm_mfma<2><<<16 * 6 * 2, 256, 0, stream>>>(
        Lhb, HH * KCONV, convwb, HH * KCONV, convp, HH, (size_t)BATCH * HH,
        HH * KCONV, 16, 6);
    // scale (relu): [B,768] x [128,768]^T
    gemm_nt<2><<<dim3(CHW / BN, BATCH / BM), 256, 0, stream>>>(
        mh, HH, scale_w, HH, scale_b, s1, CHW, BATCH, CHW, HH);
    // rescale (sigmoid): [B,128] x [768,128]^T
    gemm_nt<3><<<dim3(HH / BN, BATCH / BM), 256, 0, stream>>>(
        s1, CHW, resc_w, CHW, resc_b, theme, HH, BATCH, HH, CHW);

    out_kernel<<<BATCH, 256, 0, stream>>>(
        theme, convp, (size_t)BATCH * HH, conv_b,
        hwin + (size_t)((TT - 1) % KCONV) * BATCH * HH,   // h_last
        out_w, out_b, outp);
}

// Round 15
// 4789.442 us; speedup vs baseline: 1.4514x; 1.0030x over previous
//
#include <hip/hip_runtime.h>
#include <hip/hip_bf16.h>
#include <math.h>
#include <stdint.h>

// Problem constants
#define BATCH 1024
#define TT    256
#define DD    256
#define HH    768
#define LL    6
#define KCONV 10
#define CHW   128
#define KPACK 1024     // D + H
#define G4    3072     // 4*H interleaved gate cols
#define BNT   192      // gate cols per block tile (48 channels x 4 gates)
#define GSTR  196      // epilogue LDS row stride (floats)

// persist LDS layout (depth-6 pipeline, 8 slots; gl/ml alias slots post-loop)
#define NSLOT   8
#define SLOT    17408      // A 4096 + B 13312
#define NS      (NSLOT * SLOT)   // 139264
#define ML_OFF  52224      // 64 x 16 f32 (aliases slot 3)
#define BIAS_OFF 139264    // past slot region; persistent
#define SMEM_SZ 140928

typedef __attribute__((ext_vector_type(8))) __bf16 bf16x8;
typedef __attribute__((ext_vector_type(4))) float f32x4;

__device__ __forceinline__ float sigf(float v) { return 1.0f / (1.0f + expf(-v)); }

#define SEL6(a, l) ((l)==0?a[0]:(l)==1?a[1]:(l)==2?a[2]:(l)==3?a[3]:(l)==4?a[4]:a[5])

// async global->LDS, 16B per lane; cached (L1+L2)
__device__ __forceinline__ void gload16(const void* g, void* l) {
    __builtin_amdgcn_global_load_lds(
        (const __attribute__((address_space(1))) unsigned int*)g,
        (__attribute__((address_space(3))) unsigned int*)l, 16, 0, 0);
}
// bypass L1+L2 (SC0|SC1): read from device coherence point (fresh h)
__device__ __forceinline__ void gload16_nc(const void* g, void* l) {
    __builtin_amdgcn_global_load_lds(
        (const __attribute__((address_space(1))) unsigned int*)g,
        (__attribute__((address_space(3))) unsigned int*)l, 16, 0, 0x11);
}

__device__ __forceinline__ unsigned short bf16bits(float v) {
    __hip_bfloat16 h(v);
    return *(unsigned short*)&h;
}

// per-wave counted vmcnt: tid<64 threads stage 2 chunks/tile, others 1
#define WAITV(a, b) do { \
    if (tid < 64) asm volatile("s_waitcnt vmcnt(" #a ")" ::: "memory"); \
    else          asm volatile("s_waitcnt vmcnt(" #b ")" ::: "memory"); \
} while (0)

// ---------------------------------------------------------------------------
// W4[n][1024] bf16, n = 4*e + q  <->  orig gate row 2L + q*H + e
// ---------------------------------------------------------------------------
__global__ __launch_bounds__(256) void prep_w4(
    const float* __restrict__ kw, const float* __restrict__ kb,
    const float* __restrict__ rw, const float* __restrict__ rb,
    __hip_bfloat16* __restrict__ W4, float* __restrict__ bias4, float* __restrict__ tco4)
{
    int n = blockIdx.x;
    int e = n >> 2, q = n & 3;
    int orig = 2 * LL + q * HH + e;
    int tid = threadIdx.x;
#pragma unroll
    for (int k = 0; k < 4; ++k) {
        int col = tid + k * 256;
        float v = (col < DD) ? kw[(size_t)orig * (DD + 1) + col]
                             : rw[(size_t)orig * (HH + 1) + (col - DD)];
        W4[(size_t)n * KPACK + col] = __hip_bfloat16(v);
    }
    if (tid == 0) {
        bias4[n] = kb[orig] + rb[orig];
        tco4[n]  = kw[(size_t)orig * (DD + 1) + DD] + rw[(size_t)orig * (HH + 1) + HH];
    }
}

// Masters: Wm[16][1024], rows 0..11 = orig rows 0..11, rows 12..15 zero.
__global__ __launch_bounds__(256) void prep_wm(
    const float* __restrict__ kw, const float* __restrict__ kb,
    const float* __restrict__ rw, const float* __restrict__ rb,
    __hip_bfloat16* __restrict__ Wm, float* __restrict__ mbias, float* __restrict__ mtco)
{
    int j = blockIdx.x;
    int tid = threadIdx.x;
#pragma unroll
    for (int k = 0; k < 4; ++k) {
        int col = tid + k * 256;
        float v = 0.0f;
        if (j < 12)
            v = (col < DD) ? kw[(size_t)j * (DD + 1) + col]
                           : rw[(size_t)j * (HH + 1) + (col - DD)];
        Wm[(size_t)j * KPACK + col] = __hip_bfloat16(v);
    }
    if (tid == 0 && j < 12) {
        mbias[j] = kb[j] + rb[j];
        mtco[j]  = kw[(size_t)j * (DD + 1) + DD] + rw[(size_t)j * (HH + 1) + HH];
    }
}

__global__ __launch_bounds__(256) void cvt_kernel(
    const float* __restrict__ src, __hip_bfloat16* __restrict__ dst, int n)
{
    int i = blockIdx.x * 256 + threadIdx.x;
    if (i < n) dst[i] = __hip_bfloat16(src[i]);
}

// x[b][t][d] fp32 -> xb[t][b][d] bf16 (one-time)
__global__ __launch_bounds__(256) void xcvt_kernel(
    const float* __restrict__ x, __hip_bfloat16* __restrict__ xb)
{
    size_t o = ((size_t)blockIdx.x * 256 + threadIdx.x) * 8;
    int t = (int)(o >> 18);
    int b = (int)(o >> 8) & 1023;
    int d = (int)(o & 255);
    const float* src = x + ((size_t)b * TT + t) * DD + d;
    float4 a = *(const float4*)src;
    float4 c = *(const float4*)(src + 4);
    unsigned short tmp[8];
    tmp[0] = bf16bits(a.x); tmp[1] = bf16bits(a.y);
    tmp[2] = bf16bits(a.z); tmp[3] = bf16bits(a.w);
    tmp[4] = bf16bits(c.x); tmp[5] = bf16bits(c.y);
    tmp[6] = bf16bits(c.z); tmp[7] = bf16bits(c.w);
    *(uint4*)((char*)xb + o * 2) = *(const uint4*)tmp;
}

// ---------------------------------------------------------------------------
// Persistent fused recurrence. 256 blocks (16 bm x 16 bn), 1024 threads =
// 16 waves (4 wave-rows x 4 wave-cols; wr = wid&3 for SIMD balance), wave
// tile 16x48 (acc 1x3); masters on waves wc==3 (one per SIMD).
// Depth-6 staging pipeline over 8 slots, 2 tiles per barrier.
// Group-local sync (16 bm-groups of 16 blocks; 16 counters 256B apart).
// ---------------------------------------------------------------------------
__global__ __launch_bounds__(1024, 1) void persist_kernel(
    __hip_bfloat16* __restrict__ Hb0,
    __hip_bfloat16* __restrict__ Hb1,
    const __hip_bfloat16* __restrict__ xb,
    const float* __restrict__ timep,
    const __hip_bfloat16* __restrict__ W4,
    const __hip_bfloat16* __restrict__ Wm,
    const float* __restrict__ bias4, const float* __restrict__ tco4,
    const float* __restrict__ mbias, const float* __restrict__ mtco,
    float* __restrict__ hwin,
    float* __restrict__ distp,
    unsigned* __restrict__ cnt)
{
    __shared__ __align__(16) char smem[SMEM_SZ];
    float* gl    = (float*)smem;               // 64 x GSTR (aliases slots 0..2)
    float* ml    = (float*)(smem + ML_OFF);    // 64 x 16 (aliases slot 3)
    float* biasL = (float*)(smem + BIAS_OFF);  // 192
    float* tcoL  = biasL + 192;
    float* mbL   = tcoL + 192;
    float* mtL   = mbL + 16;

    const int tid = threadIdx.x;
    const int bid = blockIdx.x;
    const int swz = (bid & 7) * 32 + (bid >> 3);   // XCD swizzle
    const int bm = swz & 15;
    const int bn = swz >> 4;

    const int lane = tid & 63;
    const int wid  = tid >> 6;                     // 0..15
    const int wr   = wid & 3, wc = wid >> 2;       // 4x4; wr spans SIMDs
    const int kg   = lane >> 4;
    const int r15  = lane & 15;
    const bool domast = (wc == 3);                 // one master wave per SIMD
    const int r   = tid >> 4;       // cell row 0..63
    const int q16 = tid & 15;       // 3 channels at q16*3
    const int b   = bm * 64 + r;
    unsigned* cntg = cnt + bm * 64; // group counter (256B apart)

    if (tid < 192) { biasL[tid] = bias4[bn * BNT + tid]; tcoL[tid] = tco4[bn * BNT + tid]; }
    if (tid >= 256 && tid < 268) { mbL[tid - 256] = mbias[tid - 256]; mtL[tid - 256] = mtco[tid - 256]; }
    __syncthreads();

    float cst[3] = {0.f, 0.f, 0.f};

    // ---- hoisted staging descriptors ----
    // A chunks: 256 (threads 0..255); B chunks: 832 (threads 256..1023 take
    // cb = tid-256; threads 0..63 take a second chunk cb = 768+tid).
    const int rowA = tid >> 2, kcA = tid & 3;
    const int swA  = kcA ^ ((rowA >> 1) & 3);
    const size_t aXoff = ((size_t)(bm * 64 + rowA) * DD + swA * 8) * 2;  // bytes
    const size_t aHoff = ((size_t)(bm * 64 + rowA) * HH + swA * 8) * 2;  // bytes
    const int aLds = tid * 16;
    auto bptr = [&](int cb) -> const char* {
        int row = cb >> 2, kc = cb & 3;
        int sw = kc ^ ((row >> 1) & 3);
        const __hip_bfloat16* src = (row < BNT)
            ? W4 + (size_t)(bn * BNT + row) * KPACK + sw * 8
            : Wm + (size_t)(row - BNT) * KPACK + sw * 8;
        return (const char*)src;
    };
    const char* bsrc0 = (tid >= 256) ? bptr(tid - 256) : (const char*)W4;
    const char* bsrc2 = (tid < 64) ? bptr(tid + 768) : (const char*)W4;
    const int bLds0 = 4096 + (tid - 256) * 16;
    const int bLds2 = 4096 + (tid + 768) * 16;

    // ---- hoisted compute frag LDS byte offsets ----
    int aOff, bOff[3];
    {
        int ar = wr * 16 + r15;
        aOff = (ar * 32 + ((kg ^ ((ar >> 1) & 3)) * 8)) * 2;
    }
#pragma unroll
    for (int n = 0; n < 3; ++n) {
        int br = wc * 48 + n * 16 + r15;
        bOff[n] = 4096 + (br * 32 + ((kg ^ ((br >> 1) & 3)) * 8)) * 2;
    }
    const int mrr = BNT + r15;
    const int mOff = 4096 + (mrr * 32 + ((kg ^ ((mrr >> 1) & 3)) * 8)) * 2;

    const char* hb0c = (const char*)Hb0;
    const char* hb1c = (const char*)Hb1;
    const char* xbt  = (const char*)xb;

    const char* pxA = xbt + aXoff;
    const char* phA = hb0c + aHoff;

    auto stage = [&](int slotOff, int tile) {
        const int toff = tile * 64;
        if (tid < 256) {
            if (tile < 8) gload16(pxA + toff, smem + slotOff + aLds);
            else          gload16_nc(phA + (toff - 512), smem + slotOff + aLds);
        } else {
            gload16(bsrc0 + toff, smem + slotOff + bLds0);
        }
        if (tid < 64) gload16(bsrc2 + toff, smem + slotOff + bLds2);
    };

    // initial prologue: tiles 0..5 of step 0 (all x, no h dep)
    stage(0 * SLOT, 0); stage(1 * SLOT, 1); stage(2 * SLOT, 2);
    stage(3 * SLOT, 3); stage(4 * SLOT, 4); stage(5 * SLOT, 5);

    for (int t = 0; t < TT; ++t) {
        const char* hbb = (t & 1) ? hb1c : hb0c;
        __hip_bfloat16* hbW = (t & 1) ? Hb0 : Hb1;
        phA = hbb + aHoff;

        f32x4 acc[3], accm;
#pragma unroll
        for (int n = 0; n < 3; ++n) acc[n] = (f32x4){0.f, 0.f, 0.f, 0.f};
        accm = (f32x4){0.f, 0.f, 0.f, 0.f};

        auto compute = [&](int slotOff) {
            const char* base = smem + slotOff;
            bf16x8 af = *(const bf16x8*)(base + aOff);
            bf16x8 bv[3];
#pragma unroll
            for (int n = 0; n < 3; ++n) bv[n] = *(const bf16x8*)(base + bOff[n]);
#pragma unroll
            for (int n = 0; n < 3; ++n)
                acc[n] = __builtin_amdgcn_mfma_f32_16x16x32_bf16(
                    af, bv[n], acc[n], 0, 0, 0);
            if (domast) {
                bf16x8 bmf = *(const bf16x8*)(base + mOff);
                accm = __builtin_amdgcn_mfma_f32_16x16x32_bf16(
                    af, bmf, accm, 0, 0, 0);
            }
        };

        // rolled pair loop: 2 tiles per barrier; tile k -> slot k & 7
        int c0 = 0;             // slot byte offset of tile it
        int s0 = 6 * SLOT;      // slot byte offset of tile it+6
#pragma unroll 1
        for (int it = 0; it < 32; it += 2) {
            if (it <= 26)      WAITV(8, 4);
            else if (it == 28) WAITV(4, 2);
            else { asm volatile("s_waitcnt vmcnt(0)" ::: "memory"); }
            __builtin_amdgcn_s_barrier();
            int c1 = c0 + SLOT; if (c1 >= NS) c1 -= NS;
            if (it <= 24) {
                int s1 = s0 + SLOT; if (s1 >= NS) s1 -= NS;
                stage(s0, it + 6); stage(s1, it + 7);
                s0 = s1 + SLOT; if (s0 >= NS) s0 -= NS;
            }
            compute(c0); compute(c1);
            c0 = c1 + SLOT; if (c0 >= NS) c0 -= NS;
        }
        __syncthreads();   // all ds_reads done -> gl/ml may alias slots

        // ---- epilogue: acc -> gl (64 rows), masters -> ml ----
#pragma unroll
        for (int n = 0; n < 3; ++n) {
            int col = wc * 48 + n * 16 + r15;
            int rw0 = wr * 16 + kg * 4;
#pragma unroll
            for (int j = 0; j < 4; ++j)
                gl[(rw0 + j) * GSTR + col] = acc[n][j];
        }
        if (domast) {
            int rw0 = wr * 16 + kg * 4;
#pragma unroll
            for (int j = 0; j < 4; ++j)
                ml[(rw0 + j) * 16 + r15] = accm[j];
        }
        __syncthreads();

        // ---- cell: row r, 3 channels at q16*3 ----
        const float tv = timep[(size_t)b * TT + t];

        float mv[12];
#pragma unroll
        for (int i2 = 0; i2 < 12; ++i2)
            mv[i2] = ml[r * 16 + i2] + mbL[i2] + tv * mtL[i2];

        float mxf = mv[0], mxi = mv[6];
#pragma unroll
        for (int i2 = 1; i2 < 6; ++i2) { mxf = fmaxf(mxf, mv[i2]); mxi = fmaxf(mxi, mv[6 + i2]); }
        float fr[6], ir[6];
        float sf = 0.f, si = 0.f;
#pragma unroll
        for (int i2 = 0; i2 < 6; ++i2) {
            fr[i2] = expf(mv[i2] - mxf);     sf += fr[i2];
            ir[i2] = expf(mv[6 + i2] - mxi); si += ir[i2];
        }
        float fm[6], im[6];
        float rsf = 1.0f / sf, rsi = 1.0f / si;
        fm[0] = fr[0] * rsf;
#pragma unroll
        for (int i2 = 1; i2 < 6; ++i2) fm[i2] = fm[i2 - 1] + fr[i2] * rsf;
        im[5] = ir[5] * rsi;
#pragma unroll
        for (int i2 = 4; i2 >= 0; --i2) im[i2] = im[i2 + 1] + ir[i2] * rsi;

        if (bn == 0 && q16 == 0) {
            float dist = 1.0f - (fm[0] + fm[1] + fm[2] + fm[3] + fm[4] + fm[5]) * (1.0f / 6.0f);
            distp[(size_t)t * BATCH + b] = dist;
        }

        const int e0 = bn * 48 + q16 * 3;
        const int l0 = e0 >> 7, l1 = (e0 + 2) >> 7;
        const float fmA = SEL6(fm, l0), imA = SEL6(im, l0);
        const float fmB = SEL6(fm, l1), imB = SEL6(im, l1);

        const bool wh = (t >= TT - KCONV);
        float* hw = hwin + (size_t)(t % KCONV) * BATCH * HH + (size_t)b * HH;

        unsigned short hsv[3];
#pragma unroll
        for (int j = 0; j < 3; ++j) {
            int el = q16 * 3 + j;
            int e  = bn * 48 + el;
            f32x4 gv = *(const f32x4*)&gl[r * GSTR + el * 4];
            float fg = sigf(gv[0] + biasL[el * 4 + 0] + tv * tcoL[el * 4 + 0]);
            float ig = sigf(gv[1] + biasL[el * 4 + 1] + tv * tcoL[el * 4 + 1]);
            float og = sigf(gv[2] + biasL[el * 4 + 2] + tv * tcoL[el * 4 + 2]);
            float ci = tanhf(gv[3] + biasL[el * 4 + 3] + tv * tcoL[el * 4 + 3]);
            float cl = cst[j];
            bool hi = (e >> 7) != l0;
            float fmv = hi ? fmB : fmA;
            float imv = hi ? imB : imA;
            float ov = fmv * imv;
            float cn = ov * (fg * cl + ig * ci) + (fmv - ov) * cl + (imv - ov) * ci;
            float hn = og * tanhf(cn);
            cst[j] = cn;
            hsv[j] = bf16bits(hn);
            if (wh) hw[e] = hn;
        }
        {   // h -> hbW[b][e0..e0+2], write-through to coherence point
            unsigned w0 = (unsigned)hsv[0] | ((unsigned)hsv[1] << 16);
            unsigned w1 = (unsigned)hsv[2];
            uint64_t ad = (uint64_t)(uintptr_t)(hbW + (size_t)b * HH + e0);
            asm volatile(
                "global_store_dword %0, %1, off sc0 sc1\n\t"
                "global_store_short %0, %2, off offset:4 sc0 sc1"
                :: "v"(ad), "v"(w0), "v"(w1) : "memory");
        }
        __syncthreads();   // gl/ml reads done -> prefetch may overwrite slots

        // ---- group barrier (16 participants) + overlapped x/W prefetch ----
        xbt += (size_t)BATCH * DD * 2;
        pxA = xbt + aXoff;
        if (t + 1 < TT) {
            asm volatile("s_waitcnt vmcnt(0)" ::: "memory");  // h stores acked
            stage(0 * SLOT, 0); stage(1 * SLOT, 1); stage(2 * SLOT, 2);
            stage(3 * SLOT, 3); stage(4 * SLOT, 4); stage(5 * SLOT, 5);
            __builtin_amdgcn_s_barrier();                     // raw: no vm drain
            if (tid == 0) {
                __hip_atomic_fetch_add(cntg, 1u, __ATOMIC_RELAXED, __HIP_MEMORY_SCOPE_AGENT);
                unsigned target = (unsigned)(t + 1) * 16u;
                while (__hip_atomic_load(cntg, __ATOMIC_RELAXED, __HIP_MEMORY_SCOPE_AGENT) < target)
                    __builtin_amdgcn_s_sleep(1);
            }
            __builtin_amdgcn_s_barrier();
        }
    }
}

// ---------------------------------------------------------------------------
// bf16 MFMA NT GEMM for the conv einsum tail.
// ---------------------------------------------------------------------------
template <int SPLIT>
__global__ __launch_bounds__(256, 2) void gemm_mfma(
    const __hip_bfloat16* __restrict__ A, int lda,
    const __hip_bfloat16* __restrict__ W, int ldw,
    float* __restrict__ C, int ldc, size_t cstride, int Kdim, int nbm, int nbn)
{
    __shared__ unsigned short As[2][64 * 64];
    __shared__ unsigned short Bs[2][128 * 64];

    const int nwg = nbm * nbn * SPLIT;
    const int cpx = nwg >> 3;
    const int bid = blockIdx.x;
    const int swz = (bid & 7) * cpx + (bid >> 3);
    const int z   = swz % SPLIT;
    const int t2  = swz / SPLIT;
    const int bm  = t2 % nbm;
    const int bn  = t2 / nbm;
    const int kspan = Kdim / SPLIT;

    const int tid  = threadIdx.x;
    const int lane = tid & 63;
    const int wid  = tid >> 6;
    const int wr   = wid >> 1, wc = wid & 1;
    const int kg   = lane >> 4;
    const int r15  = lane & 15;

    f32x4 acc[2][4];
#pragma unroll
    for (int m = 0; m < 2; ++m)
#pragma unroll
        for (int n = 0; n < 4; ++n) acc[m][n] = (f32x4){0.f, 0.f, 0.f, 0.f};

    const __hip_bfloat16* Abase = A + (size_t)(bm * 64) * lda + (size_t)z * kspan;
    const __hip_bfloat16* Wbase = W + (size_t)(bn * 128) * ldw + (size_t)z * kspan;

    auto stage = [&](int buf, int k0) {
        unsigned short* Ad = &As[buf][0];
        unsigned short* Bd = &Bs[buf][0];
#pragma unroll
        for (int i = 0; i < 2; ++i) {
            int c = tid + i * 256;
            int row = c >> 3, kc = c & 7;
            gload16(Abase + (size_t)row * lda + k0 + ((kc ^ (row & 7)) * 8), Ad + c * 8);
        }
#pragma unroll
        for (int i = 0; i < 4; ++i) {
            int c = tid + i * 256;
            int row = c >> 3, kc = c & 7;
            gload16(Wbase + (size_t)row * ldw + k0 + ((kc ^ (row & 7)) * 8), Bd + c * 8);
        }
    };

    const int NIT = kspan / 64;
    stage(0, 0);
    int cur = 0;
    for (int it = 0; it < NIT; ++it) {
        if (it + 1 < NIT) {
            stage(cur ^ 1, (it + 1) * 64);
            asm volatile("s_waitcnt vmcnt(6)" ::: "memory");
        } else {
            asm volatile("s_waitcnt vmcnt(0)" ::: "memory");
        }
        __builtin_amdgcn_s_barrier();

#pragma unroll
        for (int ks = 0; ks < 2; ++ks) {
            const int kb = ks * 4 + kg;
            bf16x8 af[2], bv[4];
#pragma unroll
            for (int m = 0; m < 2; ++m) {
                int ar = wr * 32 + m * 16 + r15;
                af[m] = *(const bf16x8*)&As[cur][ar * 64 + ((kb ^ (ar & 7)) * 8)];
            }
#pragma unroll
            for (int n = 0; n < 4; ++n) {
                int br = wc * 64 + n * 16 + r15;
                bv[n] = *(const bf16x8*)&Bs[cur][br * 64 + ((kb ^ (br & 7)) * 8)];
            }
#pragma unroll
            for (int m = 0; m < 2; ++m)
#pragma unroll
                for (int n = 0; n < 4; ++n)
                    acc[m][n] = __builtin_amdgcn_mfma_f32_16x16x32_bf16(
                        af[m], bv[n], acc[m][n], 0, 0, 0);
        }
        __builtin_amdgcn_s_barrier();
        cur ^= 1;
    }

    float* Cp = C + (size_t)z * cstride;
    const int crow0 = bm * 64 + wr * 32 + (lane >> 4) * 4;
    const int ccol0 = bn * 128 + wc * 64 + r15;
#pragma unroll
    for (int m = 0; m < 2; ++m)
#pragma unroll
        for (int n = 0; n < 4; ++n)
#pragma unroll
            for (int j = 0; j < 4; ++j)
                Cp[(size_t)(crow0 + m * 16 + j) * ldc + ccol0 + n * 16] = acc[m][n][j];
}

// ---------------------------------------------------------------------------
// fp32 NT GEMM for the tiny tail matmuls. MODE 2: relu ; MODE 3: sigmoid
// ---------------------------------------------------------------------------
#define BM 64
#define BN 64
#define BK 32
template <int MODE>
__global__ __launch_bounds__(256) void gemm_nt(
    const float* __restrict__ A, int lda,
    const float* __restrict__ W, int ldw,
    const float* __restrict__ bias,
    float* __restrict__ C, int ldc, int M, int N, int Kdim)
{
    __shared__ float As[BK][BM + 4];
    __shared__ float Ws[BK][BN + 4];
    const int tid = threadIdx.x;
    const int bm = blockIdx.y * BM;
    const int bn = blockIdx.x * BN;
    const int tx = tid & 15;
    const int ty = tid >> 4;

    float acc[4][4];
#pragma unroll
    for (int i = 0; i < 4; ++i)
#pragma unroll
        for (int j = 0; j < 4; ++j) acc[i][j] = 0.0f;

    for (int k0 = 0; k0 < Kdim; k0 += BK) {
#pragma unroll
        for (int i = 0; i < (BM * BK) / 256; ++i) {
            int linear = tid + i * 256;
            int r = linear >> 5, kk = linear & 31;
            As[kk][r] = A[(size_t)(bm + r) * lda + k0 + kk];
        }
#pragma unroll
        for (int i = 0; i < (BN * BK) / 256; ++i) {
            int linear = tid + i * 256;
            int r = linear >> 5, kk = linear & 31;
            int gcol = bn + r;
            Ws[kk][r] = (gcol < N) ? W[(size_t)gcol * ldw + k0 + kk] : 0.0f;
        }
        __syncthreads();
#pragma unroll
        for (int kk = 0; kk < BK; ++kk) {
            float4 a4 = *(const float4*)&As[kk][ty * 4];
            float4 b4 = *(const float4*)&Ws[kk][tx * 4];
            float av[4] = {a4.x, a4.y, a4.z, a4.w};
            float bv[4] = {b4.x, b4.y, b4.z, b4.w};
#pragma unroll
            for (int i = 0; i < 4; ++i)
#pragma unroll
                for (int j = 0; j < 4; ++j)
                    acc[i][j] = fmaf(av[i], bv[j], acc[i][j]);
        }
        __syncthreads();
    }
#pragma unroll
    for (int i = 0; i < 4; ++i) {
        int row = bm + ty * 4 + i;
#pragma unroll
        for (int j = 0; j < 4; ++j) {
            int col = bn + tx * 4 + j;
            if (col < N) {
                float v = acc[i][j] + bias[col];
                if (MODE == 2) v = fmaxf(v, 0.0f);
                if (MODE == 3) v = sigf(v);
                C[(size_t)row * ldc + col] = v;
            }
        }
    }
}

// ---------------------------------------------------------------------------
__global__ __launch_bounds__(256) void window_kernel(
    const float* __restrict__ dist_out, float* __restrict__ ld)
{
    int b = blockIdx.x * blockDim.x + threadIdx.x;
    if (b >= BATCH) return;
    float w[KCONV];
    float run = 0.0f, m = -1e30f;
#pragma unroll
    for (int k = 0; k < KCONV; ++k) {
        run += dist_out[(size_t)(TT - KCONV + k) * BATCH + b];
        w[k] = run;
        m = fmaxf(m, run);
    }
    float s = 0.0f;
#pragma unroll
    for (int k = 0; k < KCONV; ++k) { w[k] = expf(w[k] - m); s += w[k]; }
    float inv = 1.0f / s;
#pragma unroll
    for (int k = 0; k < KCONV; ++k) ld[b * KCONV + k] = w[k] * inv;
}

__global__ __launch_bounds__(256) void localh_kernel(
    const float* __restrict__ hwin, const float* __restrict__ ld,
    __hip_bfloat16* __restrict__ Lhb, float* __restrict__ mh)
{
    int idx = blockIdx.x * 256 + threadIdx.x;
    int b = idx / HH;
    int e = idx - b * HH;
    float lv[KCONV];
#pragma unroll
    for (int k = 0; k < KCONV; ++k) lv[k] = ld[b * KCONV + k];
    float sum = 0.0f;
#pragma unroll
    for (int k = 0; k < KCONV; ++k) {
        int slot = (TT - KCONV + k) % KCONV;
        float v = hwin[(size_t)slot * BATCH * HH + (size_t)b * HH + e] * lv[k];
        Lhb[(size_t)b * (HH * KCONV) + e * KCONV + k] = __hip_bfloat16(v);
        sum += v;
    }
    mh[idx] = sum * (1.0f / KCONV);
}

__global__ __launch_bounds__(256) void out_kernel(
    const float* __restrict__ theme, const float* __restrict__ convp, size_t cstride,
    const float* __restrict__ conv_b, const float* __restrict__ hbuf,
    const float* __restrict__ out_w, const float* __restrict__ out_b,
    float* __restrict__ out)
{
    __shared__ float red[256];
    int b = blockIdx.x;
    float p = 0.0f;
    for (int e = threadIdx.x; e < HH; e += 256) {
        float cv = conv_b[e];
#pragma unroll
        for (int zz = 0; zz < 2; ++zz)
            cv += convp[(size_t)zz * cstride + (size_t)b * HH + e];
        p += (theme[(size_t)b * HH + e] * cv + hbuf[(size_t)b * HH + e]) * out_w[e];
    }
    red[threadIdx.x] = p;
    __syncthreads();
    for (int s = 128; s > 0; s >>= 1) {
        if (threadIdx.x < s) red[threadIdx.x] += red[threadIdx.x + s];
        __syncthreads();
    }
    if (threadIdx.x == 0) out[b] = sigf(red[0] + out_b[0]);
}

// ---------------------------------------------------------------------------
extern "C" void kernel_launch(void* const* d_in, const int* in_sizes, int n_in,
                              void* d_out, int out_size, void* d_ws, size_t ws_size,
                              hipStream_t stream)
{
    const float* x       = (const float*)d_in[0];
    const float* timep   = (const float*)d_in[1];
    const float* kw      = (const float*)d_in[2];
    const float* kb      = (const float*)d_in[3];
    const float* rw      = (const float*)d_in[4];
    const float* rb      = (const float*)d_in[5];
    const float* scale_w = (const float*)d_in[6];
    const float* scale_b = (const float*)d_in[7];
    const float* resc_w  = (const float*)d_in[8];
    const float* resc_b  = (const float*)d_in[9];
    const float* conv_w  = (const float*)d_in[10];
    const float* conv_b  = (const float*)d_in[11];
    const float* out_w   = (const float*)d_in[12];
    const float* out_b   = (const float*)d_in[13];

    float* outp  = (float*)d_out;
    float* distp = outp + BATCH;

    char* cur = (char*)d_ws;
    auto carve = [&](size_t bytes) {
        char* p = cur;
        cur += (bytes + 255) & ~(size_t)255;
        return (void*)p;
    };
    __hip_bfloat16* W4     = (__hip_bfloat16*)carve((size_t)G4 * KPACK * 2);
    __hip_bfloat16* Wm     = (__hip_bfloat16*)carve((size_t)16 * KPACK * 2);
    __hip_bfloat16* xb     = (__hip_bfloat16*)carve((size_t)TT * BATCH * DD * 2);
    __hip_bfloat16* Hb0    = (__hip_bfloat16*)carve((size_t)BATCH * HH * 2);
    __hip_bfloat16* Hb1    = (__hip_bfloat16*)carve((size_t)BATCH * HH * 2);
    __hip_bfloat16* Lhb    = (__hip_bfloat16*)carve((size_t)BATCH * HH * KCONV * 2);
    __hip_bfloat16* convwb = (__hip_bfloat16*)carve((size_t)HH * HH * KCONV * 2);
    float* bias4 = (float*)carve(G4 * 4);
    float* tco4  = (float*)carve(G4 * 4);
    float* mbias = (float*)carve(64);
    float* mtco  = (float*)carve(64);
    unsigned* cnt = (unsigned*)carve(4096);   // 16 group counters, 256B apart
    float* hwin  = (float*)carve((size_t)KCONV * BATCH * HH * 4);
    float* ld    = (float*)carve((size_t)BATCH * KCONV * 4);
    float* mh    = (float*)carve((size_t)BATCH * HH * 4);
    float* s1    = (float*)carve((size_t)BATCH * CHW * 4);
    float* theme = (float*)carve((size_t)BATCH * HH * 4);
    float* convp = (float*)carve(2 * (size_t)BATCH * HH * 4);

    hipMemsetAsync(cnt, 0, 4096, stream);
    hipMemsetAsync(Hb0, 0, (size_t)BATCH * HH * 2, stream);
    prep_w4<<<G4, 256, 0, stream>>>(kw, kb, rw, rb, W4, bias4, tco4);
    prep_wm<<<16, 256, 0, stream>>>(kw, kb, rw, rb, Wm, mbias, mtco);
    cvt_kernel<<<(HH * HH * KCONV + 255) / 256, 256, 0, stream>>>(
        conv_w, convwb, HH * HH * KCONV);
    xcvt_kernel<<<(TT * BATCH * DD / 8 + 255) / 256, 256, 0, stream>>>(x, xb);

    // persistent cooperative recurrence (all TT steps)
    {
        void* args[] = {
            (void*)&Hb0, (void*)&Hb1, (void*)&xb, (void*)&timep,
            (void*)&W4, (void*)&Wm, (void*)&bias4, (void*)&tco4,
            (void*)&mbias, (void*)&mtco, (void*)&hwin, (void*)&distp,
            (void*)&cnt
        };
        hipLaunchCooperativeKernel((void*)persist_kernel, dim3(256), dim3(1024),
                                   args, 0, stream);
    }

    window_kernel<<<(BATCH + 255) / 256, 256, 0, stream>>>(distp, ld);
    localh_kernel<<<(BATCH * HH) / 256, 256, 0, stream>>>(hwin, ld, Lhb, mh);

    // conv einsum: [B,7680]bf16 x [768,7680]bf16^T, K-split x2
    gemm_mfma<2><<<16 * 6 * 2, 256, 0, stream>>>(
        Lhb, HH * KCONV, convwb, HH * KCONV, convp, HH, (size_t)BATCH * HH,
        HH * KCONV, 16, 6);
    // scale (relu): [B,768] x [128,768]^T
    gemm_nt<2><<<dim3(CHW / BN, BATCH / BM), 256, 0, stream>>>(
        mh, HH, scale_w, HH, scale_b, s1, CHW, BATCH, CHW, HH);
    // rescale (sigmoid): [B,128] x [768,128]^T
    gemm_nt<3><<<dim3(HH / BN, BATCH / BM), 256, 0, stream>>>(
        s1, CHW, resc_w, CHW, resc_b, theme, HH, BATCH, HH, CHW);

    out_kernel<<<BATCH, 256, 0, stream>>>(
        theme, convp, (size_t)BATCH * HH, conv_b,
        hwin + (size_t)((TT - 1) % KCONV) * BATCH * HH,   // h_last
        out_w, out_b, outp);
}

// Round 17
// 4694.275 us; speedup vs baseline: 1.4808x; 1.0203x over previous
//
#include <hip/hip_runtime.h>
#include <hip/hip_bf16.h>
#include <math.h>
#include <stdint.h>

// Problem constants
#define BATCH 1024
#define TT    256
#define DD    256
#define HH    768
#define LL    6
#define KCONV 10
#define CHW   128
#define KPACK 1024     // D + H
#define G4    3072     // 4*H interleaved gate cols
#define BNT   192      // gate cols per block tile (48 channels x 4 gates)
#define GSTR  196      // epilogue LDS row stride (floats)

// persist LDS layout (depth-6 pipeline, 8 slots: 2 computing + 6 in flight;
// gl/ml alias slots 0..3 post-loop)
#define NSLOT   8
#define SLOT    17408      // A 4096 + B 13312
#define NS      (NSLOT * SLOT)   // 139264
#define ML_OFF  52224      // 64 x 16 f32 (aliases slot 3)
#define BIAS_OFF 139264    // past slot region; persistent
#define SMEM_SZ 140928

typedef __attribute__((ext_vector_type(8))) __bf16 bf16x8;
typedef __attribute__((ext_vector_type(4))) float f32x4;

__device__ __forceinline__ float sigf(float v) { return 1.0f / (1.0f + expf(-v)); }

#define SEL6(a, l) ((l)==0?a[0]:(l)==1?a[1]:(l)==2?a[2]:(l)==3?a[3]:(l)==4?a[4]:a[5])

// async global->LDS, 16B per lane; cached (L1+L2)
__device__ __forceinline__ void gload16(const void* g, void* l) {
    __builtin_amdgcn_global_load_lds(
        (const __attribute__((address_space(1))) unsigned int*)g,
        (__attribute__((address_space(3))) unsigned int*)l, 16, 0, 0);
}
// bypass L1+L2 (SC0|SC1): read from device coherence point (fresh h)
__device__ __forceinline__ void gload16_nc(const void* g, void* l) {
    __builtin_amdgcn_global_load_lds(
        (const __attribute__((address_space(1))) unsigned int*)g,
        (__attribute__((address_space(3))) unsigned int*)l, 16, 0, 0x11);
}

__device__ __forceinline__ unsigned short bf16bits(float v) {
    __hip_bfloat16 h(v);
    return *(unsigned short*)&h;
}

// per-wave counted vmcnt: wave 0 stages 3 chunks/tile (6/pair), others 2 (4/pair)
#define WAITV(a, b) do { \
    if (tid < 64) asm volatile("s_waitcnt vmcnt(" #a ")" ::: "memory"); \
    else          asm volatile("s_waitcnt vmcnt(" #b ")" ::: "memory"); \
} while (0)

// ---------------------------------------------------------------------------
// W4[n][1024] bf16, n = 4*e + q  <->  orig gate row 2L + q*H + e
// ---------------------------------------------------------------------------
__global__ __launch_bounds__(256) void prep_w4(
    const float* __restrict__ kw, const float* __restrict__ kb,
    const float* __restrict__ rw, const float* __restrict__ rb,
    __hip_bfloat16* __restrict__ W4, float* __restrict__ bias4, float* __restrict__ tco4)
{
    int n = blockIdx.x;
    int e = n >> 2, q = n & 3;
    int orig = 2 * LL + q * HH + e;
    int tid = threadIdx.x;
#pragma unroll
    for (int k = 0; k < 4; ++k) {
        int col = tid + k * 256;
        float v = (col < DD) ? kw[(size_t)orig * (DD + 1) + col]
                             : rw[(size_t)orig * (HH + 1) + (col - DD)];
        W4[(size_t)n * KPACK + col] = __hip_bfloat16(v);
    }
    if (tid == 0) {
        bias4[n] = kb[orig] + rb[orig];
        tco4[n]  = kw[(size_t)orig * (DD + 1) + DD] + rw[(size_t)orig * (HH + 1) + HH];
    }
}

// Masters: Wm[16][1024], rows 0..11 = orig rows 0..11, rows 12..15 zero.
__global__ __launch_bounds__(256) void prep_wm(
    const float* __restrict__ kw, const float* __restrict__ kb,
    const float* __restrict__ rw, const float* __restrict__ rb,
    __hip_bfloat16* __restrict__ Wm, float* __restrict__ mbias, float* __restrict__ mtco)
{
    int j = blockIdx.x;
    int tid = threadIdx.x;
#pragma unroll
    for (int k = 0; k < 4; ++k) {
        int col = tid + k * 256;
        float v = 0.0f;
        if (j < 12)
            v = (col < DD) ? kw[(size_t)j * (DD + 1) + col]
                           : rw[(size_t)j * (HH + 1) + (col - DD)];
        Wm[(size_t)j * KPACK + col] = __hip_bfloat16(v);
    }
    if (tid == 0 && j < 12) {
        mbias[j] = kb[j] + rb[j];
        mtco[j]  = kw[(size_t)j * (DD + 1) + DD] + rw[(size_t)j * (HH + 1) + HH];
    }
}

__global__ __launch_bounds__(256) void cvt_kernel(
    const float* __restrict__ src, __hip_bfloat16* __restrict__ dst, int n)
{
    int i = blockIdx.x * 256 + threadIdx.x;
    if (i < n) dst[i] = __hip_bfloat16(src[i]);
}

// x[b][t][d] fp32 -> xb[t][b][d] bf16 (one-time)
__global__ __launch_bounds__(256) void xcvt_kernel(
    const float* __restrict__ x, __hip_bfloat16* __restrict__ xb)
{
    size_t o = ((size_t)blockIdx.x * 256 + threadIdx.x) * 8;
    int t = (int)(o >> 18);
    int b = (int)(o >> 8) & 1023;
    int d = (int)(o & 255);
    const float* src = x + ((size_t)b * TT + t) * DD + d;
    float4 a = *(const float4*)src;
    float4 c = *(const float4*)(src + 4);
    unsigned short tmp[8];
    tmp[0] = bf16bits(a.x); tmp[1] = bf16bits(a.y);
    tmp[2] = bf16bits(a.z); tmp[3] = bf16bits(a.w);
    tmp[4] = bf16bits(c.x); tmp[5] = bf16bits(c.y);
    tmp[6] = bf16bits(c.z); tmp[7] = bf16bits(c.w);
    *(uint4*)((char*)xb + o * 2) = *(const uint4*)tmp;
}

// ---------------------------------------------------------------------------
// Persistent fused recurrence (r14 structure + deferred group poll).
// 256 blocks (16 bm x 16 bn), 512 threads = 8 waves (2x4), wave 32x48.
// Group-local sync (16 bm-groups of 16 blocks; 16 counters 256B apart);
// poll runs AFTER the x-only peeled round, overlapping compute; the next
// barrier gates the first h-tile staging behind the poll.
// ---------------------------------------------------------------------------
__global__ __launch_bounds__(512, 1) void persist_kernel(
    __hip_bfloat16* __restrict__ Hb0,
    __hip_bfloat16* __restrict__ Hb1,
    const __hip_bfloat16* __restrict__ xb,
    const float* __restrict__ timep,
    const __hip_bfloat16* __restrict__ W4,
    const __hip_bfloat16* __restrict__ Wm,
    const float* __restrict__ bias4, const float* __restrict__ tco4,
    const float* __restrict__ mbias, const float* __restrict__ mtco,
    float* __restrict__ hwin,
    float* __restrict__ distp,
    unsigned* __restrict__ cnt)
{
    __shared__ __align__(16) char smem[SMEM_SZ];
    float* gl    = (float*)smem;               // 64 x GSTR (aliases slots 0..2)
    float* ml    = (float*)(smem + ML_OFF);    // 64 x 16 (aliases slot 3)
    float* biasL = (float*)(smem + BIAS_OFF);  // 192
    float* tcoL  = biasL + 192;
    float* mbL   = tcoL + 192;
    float* mtL   = mbL + 16;

    const int tid = threadIdx.x;
    const int bid = blockIdx.x;
    const int swz = (bid & 7) * 32 + (bid >> 3);   // XCD swizzle
    const int bm = swz & 15;
    const int bn = swz >> 4;

    const int lane = tid & 63;
    const int wid  = tid >> 6;
    const int wr   = wid >> 2, wc = wid & 3;       // 2 x 4 wave grid
    const int kg   = lane >> 4;
    const int r15  = lane & 15;
    const bool domast = (wid == 3) || (wid == 4);
    const int r  = tid >> 3;        // cell row 0..63
    const int qq = tid & 7;         // 6 channels at qq*6
    const int b  = bm * 64 + r;
    unsigned* cntg = cnt + bm * 64; // group counter (256B apart)

    if (tid < 192) { biasL[tid] = bias4[bn * BNT + tid]; tcoL[tid] = tco4[bn * BNT + tid]; }
    if (tid >= 256 && tid < 268) { mbL[tid - 256] = mbias[tid - 256]; mtL[tid - 256] = mtco[tid - 256]; }
    __syncthreads();

    float cst[6] = {0.f, 0.f, 0.f, 0.f, 0.f, 0.f};

    // ---- hoisted staging descriptors ----
    const int rowA = tid >> 2, kcA = tid & 3;
    const int swA  = kcA ^ ((rowA >> 1) & 3);
    const size_t aXoff = ((size_t)(bm * 64 + rowA) * DD + swA * 8) * 2;  // bytes
    const size_t aHoff = ((size_t)(bm * 64 + rowA) * HH + swA * 8) * 2;  // bytes
    const int aLds = tid * 16;
    auto bptr = [&](int cb) -> const char* {
        int row = cb >> 2, kc = cb & 3;
        int sw = kc ^ ((row >> 1) & 3);
        const __hip_bfloat16* src = (row < BNT)
            ? W4 + (size_t)(bn * BNT + row) * KPACK + sw * 8
            : Wm + (size_t)(row - BNT) * KPACK + sw * 8;
        return (const char*)src;
    };
    const char* bsrc0 = (tid >= 256) ? bptr(tid - 256) : (const char*)W4;
    const char* bsrc1 = bptr(tid + 256);
    const char* bsrc2 = (tid < 64) ? bptr(tid + 768) : (const char*)W4;
    const int bLds0 = 4096 + (tid - 256) * 16;
    const int bLds1 = 4096 + (tid + 256) * 16;
    const int bLds2 = 4096 + (tid + 768) * 16;

    // ---- hoisted compute frag LDS byte offsets ----
    int aOff[2], bOff[3];
#pragma unroll
    for (int m = 0; m < 2; ++m) {
        int ar = wr * 32 + m * 16 + r15;
        aOff[m] = (ar * 32 + ((kg ^ ((ar >> 1) & 3)) * 8)) * 2;
    }
#pragma unroll
    for (int n = 0; n < 3; ++n) {
        int br = wc * 48 + n * 16 + r15;
        bOff[n] = 4096 + (br * 32 + ((kg ^ ((br >> 1) & 3)) * 8)) * 2;
    }
    const int mrr = BNT + r15;
    const int mOff = 4096 + (mrr * 32 + ((kg ^ ((mrr >> 1) & 3)) * 8)) * 2;

    const char* hb0c = (const char*)Hb0;
    const char* hb1c = (const char*)Hb1;
    const char* xbt  = (const char*)xb;

    // per-step base pointers for A staging (set each step)
    const char* pxA = xbt + aXoff;
    const char* phA = hb0c + aHoff;

    auto stage = [&](int slotOff, int tile) {
        const int toff = tile * 64;
        if (tid < 256) {
            if (tile < 8) gload16(pxA + toff, smem + slotOff + aLds);
            else          gload16_nc(phA + (toff - 512), smem + slotOff + aLds);
        } else {
            gload16(bsrc0 + toff, smem + slotOff + bLds0);
        }
        gload16(bsrc1 + toff, smem + slotOff + bLds1);
        if (tid < 64) gload16(bsrc2 + toff, smem + slotOff + bLds2);
    };

    // initial prologue: tiles 0..5 of step 0 (all x, no h dep)
    stage(0 * SLOT, 0); stage(1 * SLOT, 1); stage(2 * SLOT, 2);
    stage(3 * SLOT, 3); stage(4 * SLOT, 4); stage(5 * SLOT, 5);

    for (int t = 0; t < TT; ++t) {
        const char* hbb = (t & 1) ? hb1c : hb0c;
        __hip_bfloat16* hbW = (t & 1) ? Hb0 : Hb1;
        phA = hbb + aHoff;

        f32x4 acc[2][3], accm[2];
#pragma unroll
        for (int m = 0; m < 2; ++m) {
#pragma unroll
            for (int n = 0; n < 3; ++n) acc[m][n] = (f32x4){0.f, 0.f, 0.f, 0.f};
            accm[m] = (f32x4){0.f, 0.f, 0.f, 0.f};
        }

        auto compute = [&](int slotOff) {
            const char* base = smem + slotOff;
            bf16x8 af[2], bv[3];
#pragma unroll
            for (int m = 0; m < 2; ++m) af[m] = *(const bf16x8*)(base + aOff[m]);
#pragma unroll
            for (int n = 0; n < 3; ++n) bv[n] = *(const bf16x8*)(base + bOff[n]);
#pragma unroll
            for (int m = 0; m < 2; ++m)
#pragma unroll
                for (int n = 0; n < 3; ++n)
                    acc[m][n] = __builtin_amdgcn_mfma_f32_16x16x32_bf16(
                        af[m], bv[n], acc[m][n], 0, 0, 0);
            if (domast) {
                bf16x8 bmf = *(const bf16x8*)(base + mOff);
#pragma unroll
                for (int m = 0; m < 2; ++m)
                    accm[m] = __builtin_amdgcn_mfma_f32_16x16x32_bf16(
                        af[m], bmf, accm[m], 0, 0, 0);
            }
        };

        // peeled round it=0: compute tiles 0,1; stage x tiles 6,7 -> slots 6,7
        WAITV(12, 8);
        __builtin_amdgcn_s_barrier();
        stage(6 * SLOT, 6); stage(7 * SLOT, 7);
        compute(0 * SLOT); compute(1 * SLOT);

        // deferred group poll (overlaps the peeled round's latency); wave 0
        // reaches the next barrier only after the poll, gating stage(8).
        if (t > 0 && tid == 0) {
            unsigned target = (unsigned)t * 16u;
            while (__hip_atomic_load(cntg, __ATOMIC_RELAXED, __HIP_MEMORY_SCOPE_AGENT) < target)
                __builtin_amdgcn_s_sleep(1);
        }

        // main pair loop: 2 tiles per barrier; tile k -> slot k & 7
        int c0 = 2 * SLOT;      // slot byte offset of tile it (it=2)
        int s0 = 0;             // slot byte offset of tile it+6 (8 -> slot 0)
#pragma unroll 1
        for (int it = 2; it < 32; it += 2) {
            if (it <= 26)      WAITV(12, 8);
            else if (it == 28) WAITV(6, 4);
            else { asm volatile("s_waitcnt vmcnt(0)" ::: "memory"); }
            __builtin_amdgcn_s_barrier();
            int c1 = c0 + SLOT; if (c1 >= NS) c1 -= NS;
            if (it <= 24) {
                int s1 = s0 + SLOT; if (s1 >= NS) s1 -= NS;
                stage(s0, it + 6); stage(s1, it + 7);
                s0 = s1 + SLOT; if (s0 >= NS) s0 -= NS;
            }
            compute(c0); compute(c1);
            c0 = c1 + SLOT; if (c0 >= NS) c0 -= NS;
        }
        __syncthreads();   // all ds_reads done -> gl/ml may alias slots

        // ---- epilogue: single-phase acc -> gl (64 rows), masters -> ml ----
#pragma unroll
        for (int m = 0; m < 2; ++m)
#pragma unroll
            for (int n = 0; n < 3; ++n) {
                int col = wc * 48 + n * 16 + r15;
                int rw0 = wr * 32 + m * 16 + kg * 4;
#pragma unroll
                for (int j = 0; j < 4; ++j)
                    gl[(rw0 + j) * GSTR + col] = acc[m][n][j];
            }
        if (domast) {
#pragma unroll
            for (int m = 0; m < 2; ++m) {
                int rw0 = wr * 32 + m * 16 + kg * 4;
#pragma unroll
                for (int j = 0; j < 4; ++j)
                    ml[(rw0 + j) * 16 + r15] = accm[m][j];
            }
        }
        __syncthreads();

        // ---- cell: row r, 6 channels at qq*6 ----
        const float tv = timep[(size_t)b * TT + t];

        float mv[12];
#pragma unroll
        for (int i2 = 0; i2 < 12; ++i2)
            mv[i2] = ml[r * 16 + i2] + mbL[i2] + tv * mtL[i2];

        float mxf = mv[0], mxi = mv[6];
#pragma unroll
        for (int i2 = 1; i2 < 6; ++i2) { mxf = fmaxf(mxf, mv[i2]); mxi = fmaxf(mxi, mv[6 + i2]); }
        float fr[6], ir[6];
        float sf = 0.f, si = 0.f;
#pragma unroll
        for (int i2 = 0; i2 < 6; ++i2) {
            fr[i2] = expf(mv[i2] - mxf);     sf += fr[i2];
            ir[i2] = expf(mv[6 + i2] - mxi); si += ir[i2];
        }
        float fm[6], im[6];
        float rsf = 1.0f / sf, rsi = 1.0f / si;
        fm[0] = fr[0] * rsf;
#pragma unroll
        for (int i2 = 1; i2 < 6; ++i2) fm[i2] = fm[i2 - 1] + fr[i2] * rsf;
        im[5] = ir[5] * rsi;
#pragma unroll
        for (int i2 = 4; i2 >= 0; --i2) im[i2] = im[i2 + 1] + ir[i2] * rsi;

        if (bn == 0 && qq == 0) {
            float dist = 1.0f - (fm[0] + fm[1] + fm[2] + fm[3] + fm[4] + fm[5]) * (1.0f / 6.0f);
            distp[(size_t)t * BATCH + b] = dist;
        }

        const int e0 = bn * 48 + qq * 6;
        const int l0 = e0 >> 7, l1 = (e0 + 5) >> 7;
        const float fmA = SEL6(fm, l0), imA = SEL6(im, l0);
        const float fmB = SEL6(fm, l1), imB = SEL6(im, l1);

        const bool wh = (t >= TT - KCONV);
        float* hw = hwin + (size_t)(t % KCONV) * BATCH * HH + (size_t)b * HH;

        unsigned short hsv[6];
#pragma unroll
        for (int j = 0; j < 6; ++j) {
            int el = qq * 6 + j;
            int e  = bn * 48 + el;
            f32x4 gv = *(const f32x4*)&gl[r * GSTR + el * 4];
            float fg = sigf(gv[0] + biasL[el * 4 + 0] + tv * tcoL[el * 4 + 0]);
            float ig = sigf(gv[1] + biasL[el * 4 + 1] + tv * tcoL[el * 4 + 1]);
            float og = sigf(gv[2] + biasL[el * 4 + 2] + tv * tcoL[el * 4 + 2]);
            float ci = tanhf(gv[3] + biasL[el * 4 + 3] + tv * tcoL[el * 4 + 3]);
            float cl = cst[j];
            bool hi = (e >> 7) != l0;
            float fmv = hi ? fmB : fmA;
            float imv = hi ? imB : imA;
            float ov = fmv * imv;
            float cn = ov * (fg * cl + ig * ci) + (fmv - ov) * cl + (imv - ov) * ci;
            float hn = og * tanhf(cn);
            cst[j] = cn;
            hsv[j] = bf16bits(hn);
            if (wh) hw[e] = hn;
        }
        {   // h -> hbW[b][e0..e0+5], write-through to coherence point
            unsigned w0 = (unsigned)hsv[0] | ((unsigned)hsv[1] << 16);
            unsigned w1 = (unsigned)hsv[2] | ((unsigned)hsv[3] << 16);
            unsigned w2 = (unsigned)hsv[4] | ((unsigned)hsv[5] << 16);
            uint64_t ad = (uint64_t)(uintptr_t)(hbW + (size_t)b * HH + e0);
            asm volatile(
                "global_store_dword %0, %1, off sc0 sc1\n\t"
                "global_store_dword %0, %2, off offset:4 sc0 sc1\n\t"
                "global_store_dword %0, %3, off offset:8 sc0 sc1"
                :: "v"(ad), "v"(w0), "v"(w1), "v"(w2) : "memory");
        }
        __syncthreads();   // gl/ml reads done; drains h stores (barrier drain)

        // ---- boundary: arrive, prefetch x tiles 0-5; no extra barriers ----
        xbt += (size_t)BATCH * DD * 2;
        pxA = xbt + aXoff;
        if (t + 1 < TT) {
            asm volatile("s_waitcnt vmcnt(0)" ::: "memory");  // h stores acked
            if (tid == 0)
                __hip_atomic_fetch_add(cntg, 1u, __ATOMIC_RELAXED, __HIP_MEMORY_SCOPE_AGENT);
            stage(0 * SLOT, 0); stage(1 * SLOT, 1); stage(2 * SLOT, 2);
            stage(3 * SLOT, 3); stage(4 * SLOT, 4); stage(5 * SLOT, 5);
            // next step's first WAITV + barrier provides the sync
        }
    }
}

// ---------------------------------------------------------------------------
// bf16 MFMA NT GEMM for the conv einsum tail.
// ---------------------------------------------------------------------------
template <int SPLIT>
__global__ __launch_bounds__(256, 2) void gemm_mfma(
    const __hip_bfloat16* __restrict__ A, int lda,
    const __hip_bfloat16* __restrict__ W, int ldw,
    float* __restrict__ C, int ldc, size_t cstride, int Kdim, int nbm, int nbn)
{
    __shared__ unsigned short As[2][64 * 64];
    __shared__ unsigned short Bs[2][128 * 64];

    const int nwg = nbm * nbn * SPLIT;
    const int cpx = nwg >> 3;
    const int bid = blockIdx.x;
    const int swz = (bid & 7) * cpx + (bid >> 3);
    const int z   = swz % SPLIT;
    const int t2  = swz / SPLIT;
    const int bm  = t2 % nbm;
    const int bn  = t2 / nbm;
    const int kspan = Kdim / SPLIT;

    const int tid  = threadIdx.x;
    const int lane = tid & 63;
    const int wid  = tid >> 6;
    const int wr   = wid >> 1, wc = wid & 1;
    const int kg   = lane >> 4;
    const int r15  = lane & 15;

    f32x4 acc[2][4];
#pragma unroll
    for (int m = 0; m < 2; ++m)
#pragma unroll
        for (int n = 0; n < 4; ++n) acc[m][n] = (f32x4){0.f, 0.f, 0.f, 0.f};

    const __hip_bfloat16* Abase = A + (size_t)(bm * 64) * lda + (size_t)z * kspan;
    const __hip_bfloat16* Wbase = W + (size_t)(bn * 128) * ldw + (size_t)z * kspan;

    auto stage = [&](int buf, int k0) {
        unsigned short* Ad = &As[buf][0];
        unsigned short* Bd = &Bs[buf][0];
#pragma unroll
        for (int i = 0; i < 2; ++i) {
            int c = tid + i * 256;
            int row = c >> 3, kc = c & 7;
            gload16(Abase + (size_t)row * lda + k0 + ((kc ^ (row & 7)) * 8), Ad + c * 8);
        }
#pragma unroll
        for (int i = 0; i < 4; ++i) {
            int c = tid + i * 256;
            int row = c >> 3, kc = c & 7;
            gload16(Wbase + (size_t)row * ldw + k0 + ((kc ^ (row & 7)) * 8), Bd + c * 8);
        }
    };

    const int NIT = kspan / 64;
    stage(0, 0);
    int cur = 0;
    for (int it = 0; it < NIT; ++it) {
        if (it + 1 < NIT) {
            stage(cur ^ 1, (it + 1) * 64);
            asm volatile("s_waitcnt vmcnt(6)" ::: "memory");
        } else {
            asm volatile("s_waitcnt vmcnt(0)" ::: "memory");
        }
        __builtin_amdgcn_s_barrier();

#pragma unroll
        for (int ks = 0; ks < 2; ++ks) {
            const int kb = ks * 4 + kg;
            bf16x8 af[2], bv[4];
#pragma unroll
            for (int m = 0; m < 2; ++m) {
                int ar = wr * 32 + m * 16 + r15;
                af[m] = *(const bf16x8*)&As[cur][ar * 64 + ((kb ^ (ar & 7)) * 8)];
            }
#pragma unroll
            for (int n = 0; n < 4; ++n) {
                int br = wc * 64 + n * 16 + r15;
                bv[n] = *(const bf16x8*)&Bs[cur][br * 64 + ((kb ^ (br & 7)) * 8)];
            }
#pragma unroll
            for (int m = 0; m < 2; ++m)
#pragma unroll
                for (int n = 0; n < 4; ++n)
                    acc[m][n] = __builtin_amdgcn_mfma_f32_16x16x32_bf16(
                        af[m], bv[n], acc[m][n], 0, 0, 0);
        }
        __builtin_amdgcn_s_barrier();
        cur ^= 1;
    }

    float* Cp = C + (size_t)z * cstride;
    const int crow0 = bm * 64 + wr * 32 + (lane >> 4) * 4;
    const int ccol0 = bn * 128 + wc * 64 + r15;
#pragma unroll
    for (int m = 0; m < 2; ++m)
#pragma unroll
        for (int n = 0; n < 4; ++n)
#pragma unroll
            for (int j = 0; j < 4; ++j)
                Cp[(size_t)(crow0 + m * 16 + j) * ldc + ccol0 + n * 16] = acc[m][n][j];
}

// ---------------------------------------------------------------------------
// fp32 NT GEMM for the tiny tail matmuls. MODE 2: relu ; MODE 3: sigmoid
// ---------------------------------------------------------------------------
#define BM 64
#define BN 64
#define BK 32
template <int MODE>
__global__ __launch_bounds__(256) void gemm_nt(
    const float* __restrict__ A, int lda,
    const float* __restrict__ W, int ldw,
    const float* __restrict__ bias,
    float* __restrict__ C, int ldc, int M, int N, int Kdim)
{
    __shared__ float As[BK][BM + 4];
    __shared__ float Ws[BK][BN + 4];
    const int tid = threadIdx.x;
    const int bm = blockIdx.y * BM;
    const int bn = blockIdx.x * BN;
    const int tx = tid & 15;
    const int ty = tid >> 4;

    float acc[4][4];
#pragma unroll
    for (int i = 0; i < 4; ++i)
#pragma unroll
        for (int j = 0; j < 4; ++j) acc[i][j] = 0.0f;

    for (int k0 = 0; k0 < Kdim; k0 += BK) {
#pragma unroll
        for (int i = 0; i < (BM * BK) / 256; ++i) {
            int linear = tid + i * 256;
            int r = linear >> 5, kk = linear & 31;
            As[kk][r] = A[(size_t)(bm + r) * lda + k0 + kk];
        }
#pragma unroll
        for (int i = 0; i < (BN * BK) / 256; ++i) {
            int linear = tid + i * 256;
            int r = linear >> 5, kk = linear & 31;
            int gcol = bn + r;
            Ws[kk][r] = (gcol < N) ? W[(size_t)gcol * ldw + k0 + kk] : 0.0f;
        }
        __syncthreads();
#pragma unroll
        for (int kk = 0; kk < BK; ++kk) {
            float4 a4 = *(const float4*)&As[kk][ty * 4];
            float4 b4 = *(const float4*)&Ws[kk][tx * 4];
            float av[4] = {a4.x, a4.y, a4.z, a4.w};
            float bv[4] = {b4.x, b4.y, b4.z, b4.w};
#pragma unroll
            for (int i = 0; i < 4; ++i)
#pragma unroll
                for (int j = 0; j < 4; ++j)
                    acc[i][j] = fmaf(av[i], bv[j], acc[i][j]);
        }
        __syncthreads();
    }
#pragma unroll
    for (int i = 0; i < 4; ++i) {
        int row = bm + ty * 4 + i;
#pragma unroll
        for (int j = 0; j < 4; ++j) {
            int col = bn + tx * 4 + j;
            if (col < N) {
                float v = acc[i][j] + bias[col];
                if (MODE == 2) v = fmaxf(v, 0.0f);
                if (MODE == 3) v = sigf(v);
                C[(size_t)row * ldc + col] = v;
            }
        }
    }
}

// ---------------------------------------------------------------------------
__global__ __launch_bounds__(256) void window_kernel(
    const float* __restrict__ dist_out, float* __restrict__ ld)
{
    int b = blockIdx.x * blockDim.x + threadIdx.x;
    if (b >= BATCH) return;
    float w[KCONV];
    float run = 0.0f, m = -1e30f;
#pragma unroll
    for (int k = 0; k < KCONV; ++k) {
        run += dist_out[(size_t)(TT - KCONV + k) * BATCH + b];
        w[k] = run;
        m = fmaxf(m, run);
    }
    float s = 0.0f;
#pragma unroll
    for (int k = 0; k < KCONV; ++k) { w[k] = expf(w[k] - m); s += w[k]; }
    float inv = 1.0f / s;
#pragma unroll
    for (int k = 0; k < KCONV; ++k) ld[b * KCONV + k] = w[k] * inv;
}

__global__ __launch_bounds__(256) void localh_kernel(
    const float* __restrict__ hwin, const float* __restrict__ ld,
    __hip_bfloat16* __restrict__ Lhb, float* __restrict__ mh)
{
    int idx = blockIdx.x * 256 + threadIdx.x;
    int b = idx / HH;
    int e = idx - b * HH;
    float lv[KCONV];
#pragma unroll
    for (int k = 0; k < KCONV; ++k) lv[k] = ld[b * KCONV + k];
    float sum = 0.0f;
#pragma unroll
    for (int k = 0; k < KCONV; ++k) {
        int slot = (TT - KCONV + k) % KCONV;
        float v = hwin[(size_t)slot * BATCH * HH + (size_t)b * HH + e] * lv[k];
        Lhb[(size_t)b * (HH * KCONV) + e * KCONV + k] = __hip_bfloat16(v);
        sum += v;
    }
    mh[idx] = sum * (1.0f / KCONV);
}

__global__ __launch_bounds__(256) void out_kernel(
    const float* __restrict__ theme, const float* __restrict__ convp, size_t cstride,
    const float* __restrict__ conv_b, const float* __restrict__ hbuf,
    const float* __restrict__ out_w, const float* __restrict__ out_b,
    float* __restrict__ out)
{
    __shared__ float red[256];
    int b = blockIdx.x;
    float p = 0.0f;
    for (int e = threadIdx.x; e < HH; e += 256) {
        float cv = conv_b[e];
#pragma unroll
        for (int zz = 0; zz < 2; ++zz)
            cv += convp[(size_t)zz * cstride + (size_t)b * HH + e];
        p += (theme[(size_t)b * HH + e] * cv + hbuf[(size_t)b * HH + e]) * out_w[e];
    }
    red[threadIdx.x] = p;
    __syncthreads();
    for (int s = 128; s > 0; s >>= 1) {
        if (threadIdx.x < s) red[threadIdx.x] += red[threadIdx.x + s];
        __syncthreads();
    }
    if (threadIdx.x == 0) out[b] = sigf(red[0] + out_b[0]);
}

// ---------------------------------------------------------------------------
extern "C" void kernel_launch(void* const* d_in, const int* in_sizes, int n_in,
                              void* d_out, int out_size, void* d_ws, size_t ws_size,
                              hipStream_t stream)
{
    const float* x       = (const float*)d_in[0];
    const float* timep   = (const float*)d_in[1];
    const float* kw      = (const float*)d_in[2];
    const float* kb      = (const float*)d_in[3];
    const float* rw      = (const float*)d_in[4];
    const float* rb      = (const float*)d_in[5];
    const float* scale_w = (const float*)d_in[6];
    const float* scale_b = (const float*)d_in[7];
    const float* resc_w  = (const float*)d_in[8];
    const float* resc_b  = (const float*)d_in[9];
    const float* conv_w  = (const float*)d_in[10];
    const float* conv_b  = (const float*)d_in[11];
    const float* out_w   = (const float*)d_in[12];
    const float* out_b   = (const float*)d_in[13];

    float* outp  = (float*)d_out;
    float* distp = outp + BATCH;

    char* cur = (char*)d_ws;
    auto carve = [&](size_t bytes) {
        char* p = cur;
        cur += (bytes + 255) & ~(size_t)255;
        return (void*)p;
    };
    __hip_bfloat16* W4     = (__hip_bfloat16*)carve((size_t)G4 * KPACK * 2);
    __hip_bfloat16* Wm     = (__hip_bfloat16*)carve((size_t)16 * KPACK * 2);
    __hip_bfloat16* xb     = (__hip_bfloat16*)carve((size_t)TT * BATCH * DD * 2);
    __hip_bfloat16* Hb0    = (__hip_bfloat16*)carve((size_t)BATCH * HH * 2);
    __hip_bfloat16* Hb1    = (__hip_bfloat16*)carve((size_t)BATCH * HH * 2);
    __hip_bfloat16* Lhb    = (__hip_bfloat16*)carve((size_t)BATCH * HH * KCONV * 2);
    __hip_bfloat16* convwb = (__hip_bfloat16*)carve((size_t)HH * HH * KCONV * 2);
    float* bias4 = (float*)carve(G4 * 4);
    float* tco4  = (float*)carve(G4 * 4);
    float* mbias = (float*)carve(64);
    float* mtco  = (float*)carve(64);
    unsigned* cnt = (unsigned*)carve(4096);   // 16 group counters, 256B apart
    float* hwin  = (float*)carve((size_t)KCONV * BATCH * HH * 4);
    float* ld    = (float*)carve((size_t)BATCH * KCONV * 4);
    float* mh    = (float*)carve((size_t)BATCH * HH * 4);
    float* s1    = (float*)carve((size_t)BATCH * CHW * 4);
    float* theme = (float*)carve((size_t)BATCH * HH * 4);
    float* convp = (float*)carve(2 * (size_t)BATCH * HH * 4);

    hipMemsetAsync(cnt, 0, 4096, stream);
    hipMemsetAsync(Hb0, 0, (size_t)BATCH * HH * 2, stream);
    prep_w4<<<G4, 256, 0, stream>>>(kw, kb, rw, rb, W4, bias4, tco4);
    prep_wm<<<16, 256, 0, stream>>>(kw, kb, rw, rb, Wm, mbias, mtco);
    cvt_kernel<<<(HH * HH * KCONV + 255) / 256, 256, 0, stream>>>(
        conv_w, convwb, HH * HH * KCONV);
    xcvt_kernel<<<(TT * BATCH * DD / 8 + 255) / 256, 256, 0, stream>>>(x, xb);

    // persistent cooperative recurrence (all TT steps)
    {
        void* args[] = {
            (void*)&Hb0, (void*)&Hb1, (void*)&xb, (void*)&timep,
            (void*)&W4, (void*)&Wm, (void*)&bias4, (void*)&tco4,
            (void*)&mbias, (void*)&mtco, (void*)&hwin, (void*)&distp,
            (void*)&cnt
        };
        hipLaunchCooperativeKernel((void*)persist_kernel, dim3(256), dim3(512),
                                   args, 0, stream);
    }

    window_kernel<<<(BATCH + 255) / 256, 256, 0, stream>>>(distp, ld);
    localh_kernel<<<(BATCH * HH) / 256, 256, 0, stream>>>(hwin, ld, Lhb, mh);

    // conv einsum: [B,7680]bf16 x [768,7680]bf16^T, K-split x2
    gemm_mfma<2><<<16 * 6 * 2, 256, 0, stream>>>(
        Lhb, HH * KCONV, convwb, HH * KCONV, convp, HH, (size_t)BATCH * HH,
        HH * KCONV, 16, 6);
    // scale (relu): [B,768] x [128,768]^T
    gemm_nt<2><<<dim3(CHW / BN, BATCH / BM), 256, 0, stream>>>(
        mh, HH, scale_w, HH, scale_b, s1, CHW, BATCH, CHW, HH);
    // rescale (sigmoid): [B,128] x [768,128]^T
    gemm_nt<3><<<dim3(HH / BN, BATCH / BM), 256, 0, stream>>>(
        s1, CHW, resc_w, CHW, resc_b, theme, HH, BATCH, HH, CHW);

    out_kernel<<<BATCH, 256, 0, stream>>>(
        theme, convp, (size_t)BATCH * HH, conv_b,
        hwin + (size_t)((TT - 1) % KCONV) * BATCH * HH,   // h_last
        out_w, out_b, outp);
}

// Round 18
// 4629.570 us; speedup vs baseline: 1.5015x; 1.0140x over previous
//
#include <hip/hip_runtime.h>
#include <hip/hip_bf16.h>
#include <math.h>
#include <stdint.h>

// Problem constants
#define BATCH 1024
#define TT    256
#define DD    256
#define HH    768
#define LL    6
#define KCONV 10
#define CHW   128
#define KPACK 1024     // D + H
#define G4    3072     // 4*H interleaved gate cols
#define BNT   192      // gate cols per block tile (48 channels x 4 gates)
#define GSTR  196      // epilogue LDS row stride (floats)

// persist LDS layout (depth-6 pipeline, 8 slots: 2 computing + 6 in flight;
// gl/ml alias slots 0..3 post-loop)
#define NSLOT   8
#define SLOT    17408      // A 4096 + B 13312
#define NS      (NSLOT * SLOT)   // 139264
#define ML_OFF  52224      // 64 x 16 f32 (aliases slot 3)
#define BIAS_OFF 139264    // past slot region; persistent
#define SMEM_SZ 140928

typedef __attribute__((ext_vector_type(8))) __bf16 bf16x8;
typedef __attribute__((ext_vector_type(4))) float f32x4;

__device__ __forceinline__ float sigf(float v) { return 1.0f / (1.0f + expf(-v)); }

#define SEL6(a, l) ((l)==0?a[0]:(l)==1?a[1]:(l)==2?a[2]:(l)==3?a[3]:(l)==4?a[4]:a[5])

// async global->LDS, 16B per lane; cached (L1+L2)
__device__ __forceinline__ void gload16(const void* g, void* l) {
    __builtin_amdgcn_global_load_lds(
        (const __attribute__((address_space(1))) unsigned int*)g,
        (__attribute__((address_space(3))) unsigned int*)l, 16, 0, 0);
}
// bypass L1+L2 (SC0|SC1): read from device coherence point (fresh h)
__device__ __forceinline__ void gload16_nc(const void* g, void* l) {
    __builtin_amdgcn_global_load_lds(
        (const __attribute__((address_space(1))) unsigned int*)g,
        (__attribute__((address_space(3))) unsigned int*)l, 16, 0, 0x11);
}

__device__ __forceinline__ unsigned short bf16bits(float v) {
    __hip_bfloat16 h(v);
    return *(unsigned short*)&h;
}

// per-wave counted vmcnt: wave 0 stages 3 chunks/tile (6/pair), others 2 (4/pair)
#define WAITV(a, b) do { \
    if (tid < 64) asm volatile("s_waitcnt vmcnt(" #a ")" ::: "memory"); \
    else          asm volatile("s_waitcnt vmcnt(" #b ")" ::: "memory"); \
} while (0)

// ---------------------------------------------------------------------------
// W4[n][1024] bf16, n = 4*e + q  <->  orig gate row 2L + q*H + e
// ---------------------------------------------------------------------------
__global__ __launch_bounds__(256) void prep_w4(
    const float* __restrict__ kw, const float* __restrict__ kb,
    const float* __restrict__ rw, const float* __restrict__ rb,
    __hip_bfloat16* __restrict__ W4, float* __restrict__ bias4, float* __restrict__ tco4)
{
    int n = blockIdx.x;
    int e = n >> 2, q = n & 3;
    int orig = 2 * LL + q * HH + e;
    int tid = threadIdx.x;
#pragma unroll
    for (int k = 0; k < 4; ++k) {
        int col = tid + k * 256;
        float v = (col < DD) ? kw[(size_t)orig * (DD + 1) + col]
                             : rw[(size_t)orig * (HH + 1) + (col - DD)];
        W4[(size_t)n * KPACK + col] = __hip_bfloat16(v);
    }
    if (tid == 0) {
        bias4[n] = kb[orig] + rb[orig];
        tco4[n]  = kw[(size_t)orig * (DD + 1) + DD] + rw[(size_t)orig * (HH + 1) + HH];
    }
}

// Masters: Wm[16][1024], rows 0..11 = orig rows 0..11, rows 12..15 zero.
__global__ __launch_bounds__(256) void prep_wm(
    const float* __restrict__ kw, const float* __restrict__ kb,
    const float* __restrict__ rw, const float* __restrict__ rb,
    __hip_bfloat16* __restrict__ Wm, float* __restrict__ mbias, float* __restrict__ mtco)
{
    int j = blockIdx.x;
    int tid = threadIdx.x;
#pragma unroll
    for (int k = 0; k < 4; ++k) {
        int col = tid + k * 256;
        float v = 0.0f;
        if (j < 12)
            v = (col < DD) ? kw[(size_t)j * (DD + 1) + col]
                           : rw[(size_t)j * (HH + 1) + (col - DD)];
        Wm[(size_t)j * KPACK + col] = __hip_bfloat16(v);
    }
    if (tid == 0 && j < 12) {
        mbias[j] = kb[j] + rb[j];
        mtco[j]  = kw[(size_t)j * (DD + 1) + DD] + rw[(size_t)j * (HH + 1) + HH];
    }
}

__global__ __launch_bounds__(256) void cvt_kernel(
    const float* __restrict__ src, __hip_bfloat16* __restrict__ dst, int n)
{
    int i = blockIdx.x * 256 + threadIdx.x;
    if (i < n) dst[i] = __hip_bfloat16(src[i]);
}

// x[b][t][d] fp32 -> xb[t][b][d] bf16 (one-time)
__global__ __launch_bounds__(256) void xcvt_kernel(
    const float* __restrict__ x, __hip_bfloat16* __restrict__ xb)
{
    size_t o = ((size_t)blockIdx.x * 256 + threadIdx.x) * 8;
    int t = (int)(o >> 18);
    int b = (int)(o >> 8) & 1023;
    int d = (int)(o & 255);
    const float* src = x + ((size_t)b * TT + t) * DD + d;
    float4 a = *(const float4*)src;
    float4 c = *(const float4*)(src + 4);
    unsigned short tmp[8];
    tmp[0] = bf16bits(a.x); tmp[1] = bf16bits(a.y);
    tmp[2] = bf16bits(a.z); tmp[3] = bf16bits(a.w);
    tmp[4] = bf16bits(c.x); tmp[5] = bf16bits(c.y);
    tmp[6] = bf16bits(c.z); tmp[7] = bf16bits(c.w);
    *(uint4*)((char*)xb + o * 2) = *(const uint4*)tmp;
}

// ---------------------------------------------------------------------------
// Persistent fused recurrence (r17 structure + T5 setprio around MFMA).
// 256 blocks (16 bm x 16 bn), 512 threads = 8 waves (2x4), wave 32x48.
// Group-local sync (16 bm-groups of 16 blocks; 16 counters 256B apart);
// poll deferred past the x-only peeled round.
// ---------------------------------------------------------------------------
__global__ __launch_bounds__(512, 1) void persist_kernel(
    __hip_bfloat16* __restrict__ Hb0,
    __hip_bfloat16* __restrict__ Hb1,
    const __hip_bfloat16* __restrict__ xb,
    const float* __restrict__ timep,
    const __hip_bfloat16* __restrict__ W4,
    const __hip_bfloat16* __restrict__ Wm,
    const float* __restrict__ bias4, const float* __restrict__ tco4,
    const float* __restrict__ mbias, const float* __restrict__ mtco,
    float* __restrict__ hwin,
    float* __restrict__ distp,
    unsigned* __restrict__ cnt)
{
    __shared__ __align__(16) char smem[SMEM_SZ];
    float* gl    = (float*)smem;               // 64 x GSTR (aliases slots 0..2)
    float* ml    = (float*)(smem + ML_OFF);    // 64 x 16 (aliases slot 3)
    float* biasL = (float*)(smem + BIAS_OFF);  // 192
    float* tcoL  = biasL + 192;
    float* mbL   = tcoL + 192;
    float* mtL   = mbL + 16;

    const int tid = threadIdx.x;
    const int bid = blockIdx.x;
    const int swz = (bid & 7) * 32 + (bid >> 3);   // XCD swizzle
    const int bm = swz & 15;
    const int bn = swz >> 4;

    const int lane = tid & 63;
    const int wid  = tid >> 6;
    const int wr   = wid >> 2, wc = wid & 3;       // 2 x 4 wave grid
    const int kg   = lane >> 4;
    const int r15  = lane & 15;
    const bool domast = (wid == 3) || (wid == 4);
    const int r  = tid >> 3;        // cell row 0..63
    const int qq = tid & 7;         // 6 channels at qq*6
    const int b  = bm * 64 + r;
    unsigned* cntg = cnt + bm * 64; // group counter (256B apart)

    if (tid < 192) { biasL[tid] = bias4[bn * BNT + tid]; tcoL[tid] = tco4[bn * BNT + tid]; }
    if (tid >= 256 && tid < 268) { mbL[tid - 256] = mbias[tid - 256]; mtL[tid - 256] = mtco[tid - 256]; }
    __syncthreads();

    float cst[6] = {0.f, 0.f, 0.f, 0.f, 0.f, 0.f};

    // ---- hoisted staging descriptors ----
    const int rowA = tid >> 2, kcA = tid & 3;
    const int swA  = kcA ^ ((rowA >> 1) & 3);
    const size_t aXoff = ((size_t)(bm * 64 + rowA) * DD + swA * 8) * 2;  // bytes
    const size_t aHoff = ((size_t)(bm * 64 + rowA) * HH + swA * 8) * 2;  // bytes
    const int aLds = tid * 16;
    auto bptr = [&](int cb) -> const char* {
        int row = cb >> 2, kc = cb & 3;
        int sw = kc ^ ((row >> 1) & 3);
        const __hip_bfloat16* src = (row < BNT)
            ? W4 + (size_t)(bn * BNT + row) * KPACK + sw * 8
            : Wm + (size_t)(row - BNT) * KPACK + sw * 8;
        return (const char*)src;
    };
    const char* bsrc0 = (tid >= 256) ? bptr(tid - 256) : (const char*)W4;
    const char* bsrc1 = bptr(tid + 256);
    const char* bsrc2 = (tid < 64) ? bptr(tid + 768) : (const char*)W4;
    const int bLds0 = 4096 + (tid - 256) * 16;
    const int bLds1 = 4096 + (tid + 256) * 16;
    const int bLds2 = 4096 + (tid + 768) * 16;

    // ---- hoisted compute frag LDS byte offsets ----
    int aOff[2], bOff[3];
#pragma unroll
    for (int m = 0; m < 2; ++m) {
        int ar = wr * 32 + m * 16 + r15;
        aOff[m] = (ar * 32 + ((kg ^ ((ar >> 1) & 3)) * 8)) * 2;
    }
#pragma unroll
    for (int n = 0; n < 3; ++n) {
        int br = wc * 48 + n * 16 + r15;
        bOff[n] = 4096 + (br * 32 + ((kg ^ ((br >> 1) & 3)) * 8)) * 2;
    }
    const int mrr = BNT + r15;
    const int mOff = 4096 + (mrr * 32 + ((kg ^ ((mrr >> 1) & 3)) * 8)) * 2;

    const char* hb0c = (const char*)Hb0;
    const char* hb1c = (const char*)Hb1;
    const char* xbt  = (const char*)xb;

    // per-step base pointers for A staging (set each step)
    const char* pxA = xbt + aXoff;
    const char* phA = hb0c + aHoff;

    auto stage = [&](int slotOff, int tile) {
        const int toff = tile * 64;
        if (tid < 256) {
            if (tile < 8) gload16(pxA + toff, smem + slotOff + aLds);
            else          gload16_nc(phA + (toff - 512), smem + slotOff + aLds);
        } else {
            gload16(bsrc0 + toff, smem + slotOff + bLds0);
        }
        gload16(bsrc1 + toff, smem + slotOff + bLds1);
        if (tid < 64) gload16(bsrc2 + toff, smem + slotOff + bLds2);
    };

    // initial prologue: tiles 0..5 of step 0 (all x, no h dep)
    stage(0 * SLOT, 0); stage(1 * SLOT, 1); stage(2 * SLOT, 2);
    stage(3 * SLOT, 3); stage(4 * SLOT, 4); stage(5 * SLOT, 5);

    for (int t = 0; t < TT; ++t) {
        const char* hbb = (t & 1) ? hb1c : hb0c;
        __hip_bfloat16* hbW = (t & 1) ? Hb0 : Hb1;
        phA = hbb + aHoff;

        f32x4 acc[2][3], accm[2];
#pragma unroll
        for (int m = 0; m < 2; ++m) {
#pragma unroll
            for (int n = 0; n < 3; ++n) acc[m][n] = (f32x4){0.f, 0.f, 0.f, 0.f};
            accm[m] = (f32x4){0.f, 0.f, 0.f, 0.f};
        }

        auto compute = [&](int slotOff) {
            const char* base = smem + slotOff;
            bf16x8 af[2], bv[3];
#pragma unroll
            for (int m = 0; m < 2; ++m) af[m] = *(const bf16x8*)(base + aOff[m]);
#pragma unroll
            for (int n = 0; n < 3; ++n) bv[n] = *(const bf16x8*)(base + bOff[n]);
            __builtin_amdgcn_s_setprio(1);          // T5: favor MFMA-entering wave
#pragma unroll
            for (int m = 0; m < 2; ++m)
#pragma unroll
                for (int n = 0; n < 3; ++n)
                    acc[m][n] = __builtin_amdgcn_mfma_f32_16x16x32_bf16(
                        af[m], bv[n], acc[m][n], 0, 0, 0);
            if (domast) {
                bf16x8 bmf = *(const bf16x8*)(base + mOff);
#pragma unroll
                for (int m = 0; m < 2; ++m)
                    accm[m] = __builtin_amdgcn_mfma_f32_16x16x32_bf16(
                        af[m], bmf, accm[m], 0, 0, 0);
            }
            __builtin_amdgcn_s_setprio(0);
        };

        // peeled round it=0: compute tiles 0,1; stage x tiles 6,7 -> slots 6,7
        WAITV(12, 8);
        __builtin_amdgcn_s_barrier();
        stage(6 * SLOT, 6); stage(7 * SLOT, 7);
        compute(0 * SLOT); compute(1 * SLOT);

        // deferred group poll (overlaps the peeled round's latency); wave 0
        // reaches the next barrier only after the poll, gating stage(8).
        if (t > 0 && tid == 0) {
            unsigned target = (unsigned)t * 16u;
            while (__hip_atomic_load(cntg, __ATOMIC_RELAXED, __HIP_MEMORY_SCOPE_AGENT) < target)
                __builtin_amdgcn_s_sleep(1);
        }

        // main pair loop: 2 tiles per barrier; tile k -> slot k & 7
        int c0 = 2 * SLOT;      // slot byte offset of tile it (it=2)
        int s0 = 0;             // slot byte offset of tile it+6 (8 -> slot 0)
#pragma unroll 1
        for (int it = 2; it < 32; it += 2) {
            if (it <= 26)      WAITV(12, 8);
            else if (it == 28) WAITV(6, 4);
            else { asm volatile("s_waitcnt vmcnt(0)" ::: "memory"); }
            __builtin_amdgcn_s_barrier();
            int c1 = c0 + SLOT; if (c1 >= NS) c1 -= NS;
            if (it <= 24) {
                int s1 = s0 + SLOT; if (s1 >= NS) s1 -= NS;
                stage(s0, it + 6); stage(s1, it + 7);
                s0 = s1 + SLOT; if (s0 >= NS) s0 -= NS;
            }
            compute(c0); compute(c1);
            c0 = c1 + SLOT; if (c0 >= NS) c0 -= NS;
        }
        __syncthreads();   // all ds_reads done -> gl/ml may alias slots

        // ---- epilogue: single-phase acc -> gl (64 rows), masters -> ml ----
#pragma unroll
        for (int m = 0; m < 2; ++m)
#pragma unroll
            for (int n = 0; n < 3; ++n) {
                int col = wc * 48 + n * 16 + r15;
                int rw0 = wr * 32 + m * 16 + kg * 4;
#pragma unroll
                for (int j = 0; j < 4; ++j)
                    gl[(rw0 + j) * GSTR + col] = acc[m][n][j];
            }
        if (domast) {
#pragma unroll
            for (int m = 0; m < 2; ++m) {
                int rw0 = wr * 32 + m * 16 + kg * 4;
#pragma unroll
                for (int j = 0; j < 4; ++j)
                    ml[(rw0 + j) * 16 + r15] = accm[m][j];
            }
        }
        __syncthreads();

        // ---- cell: row r, 6 channels at qq*6 ----
        const float tv = timep[(size_t)b * TT + t];

        float mv[12];
#pragma unroll
        for (int i2 = 0; i2 < 12; ++i2)
            mv[i2] = ml[r * 16 + i2] + mbL[i2] + tv * mtL[i2];

        float mxf = mv[0], mxi = mv[6];
#pragma unroll
        for (int i2 = 1; i2 < 6; ++i2) { mxf = fmaxf(mxf, mv[i2]); mxi = fmaxf(mxi, mv[6 + i2]); }
        float fr[6], ir[6];
        float sf = 0.f, si = 0.f;
#pragma unroll
        for (int i2 = 0; i2 < 6; ++i2) {
            fr[i2] = expf(mv[i2] - mxf);     sf += fr[i2];
            ir[i2] = expf(mv[6 + i2] - mxi); si += ir[i2];
        }
        float fm[6], im[6];
        float rsf = 1.0f / sf, rsi = 1.0f / si;
        fm[0] = fr[0] * rsf;
#pragma unroll
        for (int i2 = 1; i2 < 6; ++i2) fm[i2] = fm[i2 - 1] + fr[i2] * rsf;
        im[5] = ir[5] * rsi;
#pragma unroll
        for (int i2 = 4; i2 >= 0; --i2) im[i2] = im[i2 + 1] + ir[i2] * rsi;

        if (bn == 0 && qq == 0) {
            float dist = 1.0f - (fm[0] + fm[1] + fm[2] + fm[3] + fm[4] + fm[5]) * (1.0f / 6.0f);
            distp[(size_t)t * BATCH + b] = dist;
        }

        const int e0 = bn * 48 + qq * 6;
        const int l0 = e0 >> 7, l1 = (e0 + 5) >> 7;
        const float fmA = SEL6(fm, l0), imA = SEL6(im, l0);
        const float fmB = SEL6(fm, l1), imB = SEL6(im, l1);

        const bool wh = (t >= TT - KCONV);
        float* hw = hwin + (size_t)(t % KCONV) * BATCH * HH + (size_t)b * HH;

        unsigned short hsv[6];
#pragma unroll
        for (int j = 0; j < 6; ++j) {
            int el = qq * 6 + j;
            int e  = bn * 48 + el;
            f32x4 gv = *(const f32x4*)&gl[r * GSTR + el * 4];
            float fg = sigf(gv[0] + biasL[el * 4 + 0] + tv * tcoL[el * 4 + 0]);
            float ig = sigf(gv[1] + biasL[el * 4 + 1] + tv * tcoL[el * 4 + 1]);
            float og = sigf(gv[2] + biasL[el * 4 + 2] + tv * tcoL[el * 4 + 2]);
            float ci = tanhf(gv[3] + biasL[el * 4 + 3] + tv * tcoL[el * 4 + 3]);
            float cl = cst[j];
            bool hi = (e >> 7) != l0;
            float fmv = hi ? fmB : fmA;
            float imv = hi ? imB : imA;
            float ov = fmv * imv;
            float cn = ov * (fg * cl + ig * ci) + (fmv - ov) * cl + (imv - ov) * ci;
            float hn = og * tanhf(cn);
            cst[j] = cn;
            hsv[j] = bf16bits(hn);
            if (wh) hw[e] = hn;
        }
        {   // h -> hbW[b][e0..e0+5], write-through to coherence point
            unsigned w0 = (unsigned)hsv[0] | ((unsigned)hsv[1] << 16);
            unsigned w1 = (unsigned)hsv[2] | ((unsigned)hsv[3] << 16);
            unsigned w2 = (unsigned)hsv[4] | ((unsigned)hsv[5] << 16);
            uint64_t ad = (uint64_t)(uintptr_t)(hbW + (size_t)b * HH + e0);
            asm volatile(
                "global_store_dword %0, %1, off sc0 sc1\n\t"
                "global_store_dword %0, %2, off offset:4 sc0 sc1\n\t"
                "global_store_dword %0, %3, off offset:8 sc0 sc1"
                :: "v"(ad), "v"(w0), "v"(w1), "v"(w2) : "memory");
        }
        __syncthreads();   // gl/ml reads done; prefetch may overwrite slots

        // ---- boundary: arrive, prefetch x tiles 0-5; no extra barriers ----
        xbt += (size_t)BATCH * DD * 2;
        pxA = xbt + aXoff;
        if (t + 1 < TT) {
            asm volatile("s_waitcnt vmcnt(0)" ::: "memory");  // h stores acked
            if (tid == 0)
                __hip_atomic_fetch_add(cntg, 1u, __ATOMIC_RELAXED, __HIP_MEMORY_SCOPE_AGENT);
            stage(0 * SLOT, 0); stage(1 * SLOT, 1); stage(2 * SLOT, 2);
            stage(3 * SLOT, 3); stage(4 * SLOT, 4); stage(5 * SLOT, 5);
            // next step's first WAITV + barrier provides the sync
        }
    }
}

// ---------------------------------------------------------------------------
// bf16 MFMA NT GEMM for the conv einsum tail.
// ---------------------------------------------------------------------------
template <int SPLIT>
__global__ __launch_bounds__(256, 2) void gemm_mfma(
    const __hip_bfloat16* __restrict__ A, int lda,
    const __hip_bfloat16* __restrict__ W, int ldw,
    float* __restrict__ C, int ldc, size_t cstride, int Kdim, int nbm, int nbn)
{
    __shared__ unsigned short As[2][64 * 64];
    __shared__ unsigned short Bs[2][128 * 64];

    const int nwg = nbm * nbn * SPLIT;
    const int cpx = nwg >> 3;
    const int bid = blockIdx.x;
    const int swz = (bid & 7) * cpx + (bid >> 3);
    const int z   = swz % SPLIT;
    const int t2  = swz / SPLIT;
    const int bm  = t2 % nbm;
    const int bn  = t2 / nbm;
    const int kspan = Kdim / SPLIT;

    const int tid  = threadIdx.x;
    const int lane = tid & 63;
    const int wid  = tid >> 6;
    const int wr   = wid >> 1, wc = wid & 1;
    const int kg   = lane >> 4;
    const int r15  = lane & 15;

    f32x4 acc[2][4];
#pragma unroll
    for (int m = 0; m < 2; ++m)
#pragma unroll
        for (int n = 0; n < 4; ++n) acc[m][n] = (f32x4){0.f, 0.f, 0.f, 0.f};

    const __hip_bfloat16* Abase = A + (size_t)(bm * 64) * lda + (size_t)z * kspan;
    const __hip_bfloat16* Wbase = W + (size_t)(bn * 128) * ldw + (size_t)z * kspan;

    auto stage = [&](int buf, int k0) {
        unsigned short* Ad = &As[buf][0];
        unsigned short* Bd = &Bs[buf][0];
#pragma unroll
        for (int i = 0; i < 2; ++i) {
            int c = tid + i * 256;
            int row = c >> 3, kc = c & 7;
            gload16(Abase + (size_t)row * lda + k0 + ((kc ^ (row & 7)) * 8), Ad + c * 8);
        }
#pragma unroll
        for (int i = 0; i < 4; ++i) {
            int c = tid + i * 256;
            int row = c >> 3, kc = c & 7;
            gload16(Wbase + (size_t)row * ldw + k0 + ((kc ^ (row & 7)) * 8), Bd + c * 8);
        }
    };

    const int NIT = kspan / 64;
    stage(0, 0);
    int cur = 0;
    for (int it = 0; it < NIT; ++it) {
        if (it + 1 < NIT) {
            stage(cur ^ 1, (it + 1) * 64);
            asm volatile("s_waitcnt vmcnt(6)" ::: "memory");
        } else {
            asm volatile("s_waitcnt vmcnt(0)" ::: "memory");
        }
        __builtin_amdgcn_s_barrier();

#pragma unroll
        for (int ks = 0; ks < 2; ++ks) {
            const int kb = ks * 4 + kg;
            bf16x8 af[2], bv[4];
#pragma unroll
            for (int m = 0; m < 2; ++m) {
                int ar = wr * 32 + m * 16 + r15;
                af[m] = *(const bf16x8*)&As[cur][ar * 64 + ((kb ^ (ar & 7)) * 8)];
            }
#pragma unroll
            for (int n = 0; n < 4; ++n) {
                int br = wc * 64 + n * 16 + r15;
                bv[n] = *(const bf16x8*)&Bs[cur][br * 64 + ((kb ^ (br & 7)) * 8)];
            }
#pragma unroll
            for (int m = 0; m < 2; ++m)
#pragma unroll
                for (int n = 0; n < 4; ++n)
                    acc[m][n] = __builtin_amdgcn_mfma_f32_16x16x32_bf16(
                        af[m], bv[n], acc[m][n], 0, 0, 0);
        }
        __builtin_amdgcn_s_barrier();
        cur ^= 1;
    }

    float* Cp = C + (size_t)z * cstride;
    const int crow0 = bm * 64 + wr * 32 + (lane >> 4) * 4;
    const int ccol0 = bn * 128 + wc * 64 + r15;
#pragma unroll
    for (int m = 0; m < 2; ++m)
#pragma unroll
        for (int n = 0; n < 4; ++n)
#pragma unroll
            for (int j = 0; j < 4; ++j)
                Cp[(size_t)(crow0 + m * 16 + j) * ldc + ccol0 + n * 16] = acc[m][n][j];
}

// ---------------------------------------------------------------------------
// fp32 NT GEMM for the tiny tail matmuls. MODE 2: relu ; MODE 3: sigmoid
// ---------------------------------------------------------------------------
#define BM 64
#define BN 64
#define BK 32
template <int MODE>
__global__ __launch_bounds__(256) void gemm_nt(
    const float* __restrict__ A, int lda,
    const float* __restrict__ W, int ldw,
    const float* __restrict__ bias,
    float* __restrict__ C, int ldc, int M, int N, int Kdim)
{
    __shared__ float As[BK][BM + 4];
    __shared__ float Ws[BK][BN + 4];
    const int tid = threadIdx.x;
    const int bm = blockIdx.y * BM;
    const int bn = blockIdx.x * BN;
    const int tx = tid & 15;
    const int ty = tid >> 4;

    float acc[4][4];
#pragma unroll
    for (int i = 0; i < 4; ++i)
#pragma unroll
        for (int j = 0; j < 4; ++j) acc[i][j] = 0.0f;

    for (int k0 = 0; k0 < Kdim; k0 += BK) {
#pragma unroll
        for (int i = 0; i < (BM * BK) / 256; ++i) {
            int linear = tid + i * 256;
            int r = linear >> 5, kk = linear & 31;
            As[kk][r] = A[(size_t)(bm + r) * lda + k0 + kk];
        }
#pragma unroll
        for (int i = 0; i < (BN * BK) / 256; ++i) {
            int linear = tid + i * 256;
            int r = linear >> 5, kk = linear & 31;
            int gcol = bn + r;
            Ws[kk][r] = (gcol < N) ? W[(size_t)gcol * ldw + k0 + kk] : 0.0f;
        }
        __syncthreads();
#pragma unroll
        for (int kk = 0; kk < BK; ++kk) {
            float4 a4 = *(const float4*)&As[kk][ty * 4];
            float4 b4 = *(const float4*)&Ws[kk][tx * 4];
            float av[4] = {a4.x, a4.y, a4.z, a4.w};
            float bv[4] = {b4.x, b4.y, b4.z, b4.w};
#pragma unroll
            for (int i = 0; i < 4; ++i)
#pragma unroll
                for (int j = 0; j < 4; ++j)
                    acc[i][j] = fmaf(av[i], bv[j], acc[i][j]);
        }
        __syncthreads();
    }
#pragma unroll
    for (int i = 0; i < 4; ++i) {
        int row = bm + ty * 4 + i;
#pragma unroll
        for (int j = 0; j < 4; ++j) {
            int col = bn + tx * 4 + j;
            if (col < N) {
                float v = acc[i][j] + bias[col];
                if (MODE == 2) v = fmaxf(v, 0.0f);
                if (MODE == 3) v = sigf(v);
                C[(size_t)row * ldc + col] = v;
            }
        }
    }
}

// ---------------------------------------------------------------------------
__global__ __launch_bounds__(256) void window_kernel(
    const float* __restrict__ dist_out, float* __restrict__ ld)
{
    int b = blockIdx.x * blockDim.x + threadIdx.x;
    if (b >= BATCH) return;
    float w[KCONV];
    float run = 0.0f, m = -1e30f;
#pragma unroll
    for (int k = 0; k < KCONV; ++k) {
        run += dist_out[(size_t)(TT - KCONV + k) * BATCH + b];
        w[k] = run;
        m = fmaxf(m, run);
    }
    float s = 0.0f;
#pragma unroll
    for (int k = 0; k < KCONV; ++k) { w[k] = expf(w[k] - m); s += w[k]; }
    float inv = 1.0f / s;
#pragma unroll
    for (int k = 0; k < KCONV; ++k) ld[b * KCONV + k] = w[k] * inv;
}

__global__ __launch_bounds__(256) void localh_kernel(
    const float* __restrict__ hwin, const float* __restrict__ ld,
    __hip_bfloat16* __restrict__ Lhb, float* __restrict__ mh)
{
    int idx = blockIdx.x * 256 + threadIdx.x;
    int b = idx / HH;
    int e = idx - b * HH;
    float lv[KCONV];
#pragma unroll
    for (int k = 0; k < KCONV; ++k) lv[k] = ld[b * KCONV + k];
    float sum = 0.0f;
#pragma unroll
    for (int k = 0; k < KCONV; ++k) {
        int slot = (TT - KCONV + k) % KCONV;
        float v = hwin[(size_t)slot * BATCH * HH + (size_t)b * HH + e] * lv[k];
        Lhb[(size_t)b * (HH * KCONV) + e * KCONV + k] = __hip_bfloat16(v);
        sum += v;
    }
    mh[idx] = sum * (1.0f / KCONV);
}

__global__ __launch_bounds__(256) void out_kernel(
    const float* __restrict__ theme, const float* __restrict__ convp, size_t cstride,
    const float* __restrict__ conv_b, const float* __restrict__ hbuf,
    const float* __restrict__ out_w, const float* __restrict__ out_b,
    float* __restrict__ out)
{
    __shared__ float red[256];
    int b = blockIdx.x;
    float p = 0.0f;
    for (int e = threadIdx.x; e < HH; e += 256) {
        float cv = conv_b[e];
#pragma unroll
        for (int zz = 0; zz < 2; ++zz)
            cv += convp[(size_t)zz * cstride + (size_t)b * HH + e];
        p += (theme[(size_t)b * HH + e] * cv + hbuf[(size_t)b * HH + e]) * out_w[e];
    }
    red[threadIdx.x] = p;
    __syncthreads();
    for (int s = 128; s > 0; s >>= 1) {
        if (threadIdx.x < s) red[threadIdx.x] += red[threadIdx.x + s];
        __syncthreads();
    }
    if (threadIdx.x == 0) out[b] = sigf(red[0] + out_b[0]);
}

// ---------------------------------------------------------------------------
extern "C" void kernel_launch(void* const* d_in, const int* in_sizes, int n_in,
                              void* d_out, int out_size, void* d_ws, size_t ws_size,
                              hipStream_t stream)
{
    const float* x       = (const float*)d_in[0];
    const float* timep   = (const float*)d_in[1];
    const float* kw      = (const float*)d_in[2];
    const float* kb      = (const float*)d_in[3];
    const float* rw      = (const float*)d_in[4];
    const float* rb      = (const float*)d_in[5];
    const float* scale_w = (const float*)d_in[6];
    const float* scale_b = (const float*)d_in[7];
    const float* resc_w  = (const float*)d_in[8];
    const float* resc_b  = (const float*)d_in[9];
    const float* conv_w  = (const float*)d_in[10];
    const float* conv_b  = (const float*)d_in[11];
    const float* out_w   = (const float*)d_in[12];
    const float* out_b   = (const float*)d_in[13];

    float* outp  = (float*)d_out;
    float* distp = outp + BATCH;

    char* cur = (char*)d_ws;
    auto carve = [&](size_t bytes) {
        char* p = cur;
        cur += (bytes + 255) & ~(size_t)255;
        return (void*)p;
    };
    __hip_bfloat16* W4     = (__hip_bfloat16*)carve((size_t)G4 * KPACK * 2);
    __hip_bfloat16* Wm     = (__hip_bfloat16*)carve((size_t)16 * KPACK * 2);
    __hip_bfloat16* xb     = (__hip_bfloat16*)carve((size_t)TT * BATCH * DD * 2);
    __hip_bfloat16* Hb0    = (__hip_bfloat16*)carve((size_t)BATCH * HH * 2);
    __hip_bfloat16* Hb1    = (__hip_bfloat16*)carve((size_t)BATCH * HH * 2);
    __hip_bfloat16* Lhb    = (__hip_bfloat16*)carve((size_t)BATCH * HH * KCONV * 2);
    __hip_bfloat16* convwb = (__hip_bfloat16*)carve((size_t)HH * HH * KCONV * 2);
    float* bias4 = (float*)carve(G4 * 4);
    float* tco4  = (float*)carve(G4 * 4);
    float* mbias = (float*)carve(64);
    float* mtco  = (float*)carve(64);
    unsigned* cnt = (unsigned*)carve(4096);   // 16 group counters, 256B apart
    float* hwin  = (float*)carve((size_t)KCONV * BATCH * HH * 4);
    float* ld    = (float*)carve((size_t)BATCH * KCONV * 4);
    float* mh    = (float*)carve((size_t)BATCH * HH * 4);
    float* s1    = (float*)carve((size_t)BATCH * CHW * 4);
    float* theme = (float*)carve((size_t)BATCH * HH * 4);
    float* convp = (float*)carve(2 * (size_t)BATCH * HH * 4);

    hipMemsetAsync(cnt, 0, 4096, stream);
    hipMemsetAsync(Hb0, 0, (size_t)BATCH * HH * 2, stream);
    prep_w4<<<G4, 256, 0, stream>>>(kw, kb, rw, rb, W4, bias4, tco4);
    prep_wm<<<16, 256, 0, stream>>>(kw, kb, rw, rb, Wm, mbias, mtco);
    cvt_kernel<<<(HH * HH * KCONV + 255) / 256, 256, 0, stream>>>(
        conv_w, convwb, HH * HH * KCONV);
    xcvt_kernel<<<(TT * BATCH * DD / 8 + 255) / 256, 256, 0, stream>>>(x, xb);

    // persistent cooperative recurrence (all TT steps)
    {
        void* args[] = {
            (void*)&Hb0, (void*)&Hb1, (void*)&xb, (void*)&timep,
            (void*)&W4, (void*)&Wm, (void*)&bias4, (void*)&tco4,
            (void*)&mbias, (void*)&mtco, (void*)&hwin, (void*)&distp,
            (void*)&cnt
        };
        hipLaunchCooperativeKernel((void*)persist_kernel, dim3(256), dim3(512),
                                   args, 0, stream);
    }

    window_kernel<<<(BATCH + 255) / 256, 256, 0, stream>>>(distp, ld);
    localh_kernel<<<(BATCH * HH) / 256, 256, 0, stream>>>(hwin, ld, Lhb, mh);

    // conv einsum: [B,7680]bf16 x [768,7680]bf16^T, K-split x2
    gemm_mfma<2><<<16 * 6 * 2, 256, 0, stream>>>(
        Lhb, HH * KCONV, convwb, HH * KCONV, convp, HH, (size_t)BATCH * HH,
        HH * KCONV, 16, 6);
    // scale (relu): [B,768] x [128,768]^T
    gemm_nt<2><<<dim3(CHW / BN, BATCH / BM), 256, 0, stream>>>(
        mh, HH, scale_w, HH, scale_b, s1, CHW, BATCH, CHW, HH);
    // rescale (sigmoid): [B,128] x [768,128]^T
    gemm_nt<3><<<dim3(HH / BN, BATCH / BM), 256, 0, stream>>>(
        s1, CHW, resc_w, CHW, resc_b, theme, HH, BATCH, HH, CHW);

    out_kernel<<<BATCH, 256, 0, stream>>>(
        theme, convp, (size_t)BATCH * HH, conv_b,
        hwin + (size_t)((TT - 1) % KCONV) * BATCH * HH,   // h_last
        out_w, out_b, outp);
}

// Round 19
// 4496.952 us; speedup vs baseline: 1.5458x; 1.0295x over previous
//
#include <hip/hip_runtime.h>
#include <hip/hip_bf16.h>
#include <math.h>
#include <stdint.h>

// Problem constants
#define BATCH 1024
#define TT    256
#define DD    256
#define HH    768
#define LL    6
#define KCONV 10
#define CHW   128
#define KPACK 1024     // D + H
#define G4    3072     // 4*H interleaved gate cols
#define BNT   192      // gate cols per block tile (48 channels x 4 gates)
#define GSTR  196      // epilogue LDS row stride (floats)

// persist LDS layout (8 slots: 4 computing + 4 in flight;
// gl/ml alias slots 0..3 post-loop)
#define NSLOT   8
#define SLOT    17408      // A 4096 + B 13312
#define NS      (NSLOT * SLOT)   // 139264
#define ML_OFF  52224      // 64 x 16 f32 (aliases slot 3)
#define BIAS_OFF 139264    // past slot region; persistent
#define SMEM_SZ 140928

typedef __attribute__((ext_vector_type(8))) __bf16 bf16x8;
typedef __attribute__((ext_vector_type(4))) float f32x4;

__device__ __forceinline__ float sigf(float v) { return 1.0f / (1.0f + expf(-v)); }

#define SEL6(a, l) ((l)==0?a[0]:(l)==1?a[1]:(l)==2?a[2]:(l)==3?a[3]:(l)==4?a[4]:a[5])

// async global->LDS, 16B per lane; cached (L1+L2)
__device__ __forceinline__ void gload16(const void* g, void* l) {
    __builtin_amdgcn_global_load_lds(
        (const __attribute__((address_space(1))) unsigned int*)g,
        (__attribute__((address_space(3))) unsigned int*)l, 16, 0, 0);
}
// bypass L1+L2 (SC0|SC1): read from device coherence point (fresh h)
__device__ __forceinline__ void gload16_nc(const void* g, void* l) {
    __builtin_amdgcn_global_load_lds(
        (const __attribute__((address_space(1))) unsigned int*)g,
        (__attribute__((address_space(3))) unsigned int*)l, 16, 0, 0x11);
}

__device__ __forceinline__ unsigned short bf16bits(float v) {
    __hip_bfloat16 h(v);
    return *(unsigned short*)&h;
}

// per-wave counted vmcnt: wave 0 stages 3 chunks/tile, others 2
#define WAITV(a, b) do { \
    if (tid < 64) asm volatile("s_waitcnt vmcnt(" #a ")" ::: "memory"); \
    else          asm volatile("s_waitcnt vmcnt(" #b ")" ::: "memory"); \
} while (0)

// ---------------------------------------------------------------------------
// W4[n][1024] bf16, n = 4*e + q  <->  orig gate row 2L + q*H + e
// ---------------------------------------------------------------------------
__global__ __launch_bounds__(256) void prep_w4(
    const float* __restrict__ kw, const float* __restrict__ kb,
    const float* __restrict__ rw, const float* __restrict__ rb,
    __hip_bfloat16* __restrict__ W4, float* __restrict__ bias4, float* __restrict__ tco4)
{
    int n = blockIdx.x;
    int e = n >> 2, q = n & 3;
    int orig = 2 * LL + q * HH + e;
    int tid = threadIdx.x;
#pragma unroll
    for (int k = 0; k < 4; ++k) {
        int col = tid + k * 256;
        float v = (col < DD) ? kw[(size_t)orig * (DD + 1) + col]
                             : rw[(size_t)orig * (HH + 1) + (col - DD)];
        W4[(size_t)n * KPACK + col] = __hip_bfloat16(v);
    }
    if (tid == 0) {
        bias4[n] = kb[orig] + rb[orig];
        tco4[n]  = kw[(size_t)orig * (DD + 1) + DD] + rw[(size_t)orig * (HH + 1) + HH];
    }
}

// Masters: Wm[16][1024], rows 0..11 = orig rows 0..11, rows 12..15 zero.
__global__ __launch_bounds__(256) void prep_wm(
    const float* __restrict__ kw, const float* __restrict__ kb,
    const float* __restrict__ rw, const float* __restrict__ rb,
    __hip_bfloat16* __restrict__ Wm, float* __restrict__ mbias, float* __restrict__ mtco)
{
    int j = blockIdx.x;
    int tid = threadIdx.x;
#pragma unroll
    for (int k = 0; k < 4; ++k) {
        int col = tid + k * 256;
        float v = 0.0f;
        if (j < 12)
            v = (col < DD) ? kw[(size_t)j * (DD + 1) + col]
                           : rw[(size_t)j * (HH + 1) + (col - DD)];
        Wm[(size_t)j * KPACK + col] = __hip_bfloat16(v);
    }
    if (tid == 0 && j < 12) {
        mbias[j] = kb[j] + rb[j];
        mtco[j]  = kw[(size_t)j * (DD + 1) + DD] + rw[(size_t)j * (HH + 1) + HH];
    }
}

__global__ __launch_bounds__(256) void cvt_kernel(
    const float* __restrict__ src, __hip_bfloat16* __restrict__ dst, int n)
{
    int i = blockIdx.x * 256 + threadIdx.x;
    if (i < n) dst[i] = __hip_bfloat16(src[i]);
}

// x[b][t][d] fp32 -> xb[t][b][d] bf16 (one-time)
__global__ __launch_bounds__(256) void xcvt_kernel(
    const float* __restrict__ x, __hip_bfloat16* __restrict__ xb)
{
    size_t o = ((size_t)blockIdx.x * 256 + threadIdx.x) * 8;
    int t = (int)(o >> 18);
    int b = (int)(o >> 8) & 1023;
    int d = (int)(o & 255);
    const float* src = x + ((size_t)b * TT + t) * DD + d;
    float4 a = *(const float4*)src;
    float4 c = *(const float4*)(src + 4);
    unsigned short tmp[8];
    tmp[0] = bf16bits(a.x); tmp[1] = bf16bits(a.y);
    tmp[2] = bf16bits(a.z); tmp[3] = bf16bits(a.w);
    tmp[4] = bf16bits(c.x); tmp[5] = bf16bits(c.y);
    tmp[6] = bf16bits(c.z); tmp[7] = bf16bits(c.w);
    *(uint4*)((char*)xb + o * 2) = *(const uint4*)tmp;
}

// ---------------------------------------------------------------------------
// Persistent fused recurrence (r18 structure; 4 tiles per barrier round).
// 256 blocks (16 bm x 16 bn), 512 threads = 8 waves (2x4), wave 32x48.
// Round r computes tiles 4r..4r+3 (slots (4r)&7..) and stages tiles
// 4r+8..4r+11 into the slots consumed last round. 9 barrier rounds/step.
// Boundary prefetch = tiles 0..7 (the whole x-part); group poll deferred
// between round A (x compute) and round B's barrier (gates h staging).
// ---------------------------------------------------------------------------
__global__ __launch_bounds__(512, 1) void persist_kernel(
    __hip_bfloat16* __restrict__ Hb0,
    __hip_bfloat16* __restrict__ Hb1,
    const __hip_bfloat16* __restrict__ xb,
    const float* __restrict__ timep,
    const __hip_bfloat16* __restrict__ W4,
    const __hip_bfloat16* __restrict__ Wm,
    const float* __restrict__ bias4, const float* __restrict__ tco4,
    const float* __restrict__ mbias, const float* __restrict__ mtco,
    float* __restrict__ hwin,
    float* __restrict__ distp,
    unsigned* __restrict__ cnt)
{
    __shared__ __align__(16) char smem[SMEM_SZ];
    float* gl    = (float*)smem;               // 64 x GSTR (aliases slots 0..2)
    float* ml    = (float*)(smem + ML_OFF);    // 64 x 16 (aliases slot 3)
    float* biasL = (float*)(smem + BIAS_OFF);  // 192
    float* tcoL  = biasL + 192;
    float* mbL   = tcoL + 192;
    float* mtL   = mbL + 16;

    const int tid = threadIdx.x;
    const int bid = blockIdx.x;
    const int swz = (bid & 7) * 32 + (bid >> 3);   // XCD swizzle
    const int bm = swz & 15;
    const int bn = swz >> 4;

    const int lane = tid & 63;
    const int wid  = tid >> 6;
    const int wr   = wid >> 2, wc = wid & 3;       // 2 x 4 wave grid
    const int kg   = lane >> 4;
    const int r15  = lane & 15;
    const bool domast = (wid == 3) || (wid == 4);
    const int r  = tid >> 3;        // cell row 0..63
    const int qq = tid & 7;         // 6 channels at qq*6
    const int b  = bm * 64 + r;
    unsigned* cntg = cnt + bm * 64; // group counter (256B apart)

    if (tid < 192) { biasL[tid] = bias4[bn * BNT + tid]; tcoL[tid] = tco4[bn * BNT + tid]; }
    if (tid >= 256 && tid < 268) { mbL[tid - 256] = mbias[tid - 256]; mtL[tid - 256] = mtco[tid - 256]; }
    __syncthreads();

    float cst[6] = {0.f, 0.f, 0.f, 0.f, 0.f, 0.f};

    // ---- hoisted staging descriptors ----
    const int rowA = tid >> 2, kcA = tid & 3;
    const int swA  = kcA ^ ((rowA >> 1) & 3);
    const size_t aXoff = ((size_t)(bm * 64 + rowA) * DD + swA * 8) * 2;  // bytes
    const size_t aHoff = ((size_t)(bm * 64 + rowA) * HH + swA * 8) * 2;  // bytes
    const int aLds = tid * 16;
    auto bptr = [&](int cb) -> const char* {
        int row = cb >> 2, kc = cb & 3;
        int sw = kc ^ ((row >> 1) & 3);
        const __hip_bfloat16* src = (row < BNT)
            ? W4 + (size_t)(bn * BNT + row) * KPACK + sw * 8
            : Wm + (size_t)(row - BNT) * KPACK + sw * 8;
        return (const char*)src;
    };
    const char* bsrc0 = (tid >= 256) ? bptr(tid - 256) : (const char*)W4;
    const char* bsrc1 = bptr(tid + 256);
    const char* bsrc2 = (tid < 64) ? bptr(tid + 768) : (const char*)W4;
    const int bLds0 = 4096 + (tid - 256) * 16;
    const int bLds1 = 4096 + (tid + 256) * 16;
    const int bLds2 = 4096 + (tid + 768) * 16;

    // ---- hoisted compute frag LDS byte offsets ----
    int aOff[2], bOff[3];
#pragma unroll
    for (int m = 0; m < 2; ++m) {
        int ar = wr * 32 + m * 16 + r15;
        aOff[m] = (ar * 32 + ((kg ^ ((ar >> 1) & 3)) * 8)) * 2;
    }
#pragma unroll
    for (int n = 0; n < 3; ++n) {
        int br = wc * 48 + n * 16 + r15;
        bOff[n] = 4096 + (br * 32 + ((kg ^ ((br >> 1) & 3)) * 8)) * 2;
    }
    const int mrr = BNT + r15;
    const int mOff = 4096 + (mrr * 32 + ((kg ^ ((mrr >> 1) & 3)) * 8)) * 2;

    const char* hb0c = (const char*)Hb0;
    const char* hb1c = (const char*)Hb1;
    const char* xbt  = (const char*)xb;

    // per-step base pointers for A staging (set each step)
    const char* pxA = xbt + aXoff;
    const char* phA = hb0c + aHoff;

    auto stage = [&](int slotOff, int tile) {
        const int toff = tile * 64;
        if (tid < 256) {
            if (tile < 8) gload16(pxA + toff, smem + slotOff + aLds);
            else          gload16_nc(phA + (toff - 512), smem + slotOff + aLds);
        } else {
            gload16(bsrc0 + toff, smem + slotOff + bLds0);
        }
        gload16(bsrc1 + toff, smem + slotOff + bLds1);
        if (tid < 64) gload16(bsrc2 + toff, smem + slotOff + bLds2);
    };

    // initial prologue: tiles 0..7 of step 0 (all x, no h dep)
    stage(0 * SLOT, 0); stage(1 * SLOT, 1); stage(2 * SLOT, 2); stage(3 * SLOT, 3);
    stage(4 * SLOT, 4); stage(5 * SLOT, 5); stage(6 * SLOT, 6); stage(7 * SLOT, 7);

    for (int t = 0; t < TT; ++t) {
        const char* hbb = (t & 1) ? hb1c : hb0c;
        __hip_bfloat16* hbW = (t & 1) ? Hb0 : Hb1;
        phA = hbb + aHoff;

        f32x4 acc[2][3], accm[2];
#pragma unroll
        for (int m = 0; m < 2; ++m) {
#pragma unroll
            for (int n = 0; n < 3; ++n) acc[m][n] = (f32x4){0.f, 0.f, 0.f, 0.f};
            accm[m] = (f32x4){0.f, 0.f, 0.f, 0.f};
        }

        auto compute = [&](int slotOff) {
            const char* base = smem + slotOff;
            bf16x8 af[2], bv[3];
#pragma unroll
            for (int m = 0; m < 2; ++m) af[m] = *(const bf16x8*)(base + aOff[m]);
#pragma unroll
            for (int n = 0; n < 3; ++n) bv[n] = *(const bf16x8*)(base + bOff[n]);
            __builtin_amdgcn_s_setprio(1);          // T5: favor MFMA-entering wave
#pragma unroll
            for (int m = 0; m < 2; ++m)
#pragma unroll
                for (int n = 0; n < 3; ++n)
                    acc[m][n] = __builtin_amdgcn_mfma_f32_16x16x32_bf16(
                        af[m], bv[n], acc[m][n], 0, 0, 0);
            if (domast) {
                bf16x8 bmf = *(const bf16x8*)(base + mOff);
#pragma unroll
                for (int m = 0; m < 2; ++m)
                    accm[m] = __builtin_amdgcn_mfma_f32_16x16x32_bf16(
                        af[m], bmf, accm[m], 0, 0, 0);
            }
            __builtin_amdgcn_s_setprio(0);
        };

        // Round A: tiles 0-3 (slots 0-3); tiles 4-7 stay in flight
        WAITV(12, 8);
        __builtin_amdgcn_s_barrier();
        compute(0 * SLOT); compute(1 * SLOT); compute(2 * SLOT); compute(3 * SLOT);

        // deferred group poll (overlaps round A's tail); wave 0 reaches the
        // next barrier only after the poll, gating the first h staging.
        if (t > 0 && tid == 0) {
            unsigned target = (unsigned)t * 16u;
            while (__hip_atomic_load(cntg, __ATOMIC_RELAXED, __HIP_MEMORY_SCOPE_AGENT) < target)
                __builtin_amdgcn_s_sleep(1);
        }

        // Round B: tiles 4-7 (slots 4-7); stage h tiles 8-11 -> slots 0-3
        asm volatile("s_waitcnt vmcnt(0)" ::: "memory");
        __builtin_amdgcn_s_barrier();
        stage(0 * SLOT, 8); stage(1 * SLOT, 9); stage(2 * SLOT, 10); stage(3 * SLOT, 11);
        compute(4 * SLOT); compute(5 * SLOT); compute(6 * SLOT); compute(7 * SLOT);

        // Rounds C..G: it = 8,12,16,20,24 — compute tiles it..it+3, stage it+4..it+7
#pragma unroll 1
        for (int it = 8; it <= 24; it += 4) {
            asm volatile("s_waitcnt vmcnt(0)" ::: "memory");
            __builtin_amdgcn_s_barrier();
            const int cs = (it & 4) ? 4 * SLOT : 0;   // tiles it -> slot it&7
            const int ss = cs ^ (4 * SLOT);
            stage(ss, it + 4); stage(ss + SLOT, it + 5);
            stage(ss + 2 * SLOT, it + 6); stage(ss + 3 * SLOT, it + 7);
            compute(cs); compute(cs + SLOT);
            compute(cs + 2 * SLOT); compute(cs + 3 * SLOT);
        }

        // Round H: tiles 28-31 (slots 4-7)
        asm volatile("s_waitcnt vmcnt(0)" ::: "memory");
        __builtin_amdgcn_s_barrier();
        compute(4 * SLOT); compute(5 * SLOT); compute(6 * SLOT); compute(7 * SLOT);

        __syncthreads();   // all ds_reads done -> gl/ml may alias slots 0-3

        // ---- epilogue: single-phase acc -> gl (64 rows), masters -> ml ----
#pragma unroll
        for (int m = 0; m < 2; ++m)
#pragma unroll
            for (int n = 0; n < 3; ++n) {
                int col = wc * 48 + n * 16 + r15;
                int rw0 = wr * 32 + m * 16 + kg * 4;
#pragma unroll
                for (int j = 0; j < 4; ++j)
                    gl[(rw0 + j) * GSTR + col] = acc[m][n][j];
            }
        if (domast) {
#pragma unroll
            for (int m = 0; m < 2; ++m) {
                int rw0 = wr * 32 + m * 16 + kg * 4;
#pragma unroll
                for (int j = 0; j < 4; ++j)
                    ml[(rw0 + j) * 16 + r15] = accm[m][j];
            }
        }
        __syncthreads();

        // ---- cell: row r, 6 channels at qq*6 ----
        const float tv = timep[(size_t)b * TT + t];

        float mv[12];
#pragma unroll
        for (int i2 = 0; i2 < 12; ++i2)
            mv[i2] = ml[r * 16 + i2] + mbL[i2] + tv * mtL[i2];

        float mxf = mv[0], mxi = mv[6];
#pragma unroll
        for (int i2 = 1; i2 < 6; ++i2) { mxf = fmaxf(mxf, mv[i2]); mxi = fmaxf(mxi, mv[6 + i2]); }
        float fr[6], ir[6];
        float sf = 0.f, si = 0.f;
#pragma unroll
        for (int i2 = 0; i2 < 6; ++i2) {
            fr[i2] = expf(mv[i2] - mxf);     sf += fr[i2];
            ir[i2] = expf(mv[6 + i2] - mxi); si += ir[i2];
        }
        float fm[6], im[6];
        float rsf = 1.0f / sf, rsi = 1.0f / si;
        fm[0] = fr[0] * rsf;
#pragma unroll
        for (int i2 = 1; i2 < 6; ++i2) fm[i2] = fm[i2 - 1] + fr[i2] * rsf;
        im[5] = ir[5] * rsi;
#pragma unroll
        for (int i2 = 4; i2 >= 0; --i2) im[i2] = im[i2 + 1] + ir[i2] * rsi;

        if (bn == 0 && qq == 0) {
            float dist = 1.0f - (fm[0] + fm[1] + fm[2] + fm[3] + fm[4] + fm[5]) * (1.0f / 6.0f);
            distp[(size_t)t * BATCH + b] = dist;
        }

        const int e0 = bn * 48 + qq * 6;
        const int l0 = e0 >> 7, l1 = (e0 + 5) >> 7;
        const float fmA = SEL6(fm, l0), imA = SEL6(im, l0);
        const float fmB = SEL6(fm, l1), imB = SEL6(im, l1);

        const bool wh = (t >= TT - KCONV);
        float* hw = hwin + (size_t)(t % KCONV) * BATCH * HH + (size_t)b * HH;

        unsigned short hsv[6];
#pragma unroll
        for (int j = 0; j < 6; ++j) {
            int el = qq * 6 + j;
            int e  = bn * 48 + el;
            f32x4 gv = *(const f32x4*)&gl[r * GSTR + el * 4];
            float fg = sigf(gv[0] + biasL[el * 4 + 0] + tv * tcoL[el * 4 + 0]);
            float ig = sigf(gv[1] + biasL[el * 4 + 1] + tv * tcoL[el * 4 + 1]);
            float og = sigf(gv[2] + biasL[el * 4 + 2] + tv * tcoL[el * 4 + 2]);
            float ci = tanhf(gv[3] + biasL[el * 4 + 3] + tv * tcoL[el * 4 + 3]);
            float cl = cst[j];
            bool hi = (e >> 7) != l0;
            float fmv = hi ? fmB : fmA;
            float imv = hi ? imB : imA;
            float ov = fmv * imv;
            float cn = ov * (fg * cl + ig * ci) + (fmv - ov) * cl + (imv - ov) * ci;
            float hn = og * tanhf(cn);
            cst[j] = cn;
            hsv[j] = bf16bits(hn);
            if (wh) hw[e] = hn;
        }
        {   // h -> hbW[b][e0..e0+5], write-through to coherence point
            unsigned w0 = (unsigned)hsv[0] | ((unsigned)hsv[1] << 16);
            unsigned w1 = (unsigned)hsv[2] | ((unsigned)hsv[3] << 16);
            unsigned w2 = (unsigned)hsv[4] | ((unsigned)hsv[5] << 16);
            uint64_t ad = (uint64_t)(uintptr_t)(hbW + (size_t)b * HH + e0);
            asm volatile(
                "global_store_dword %0, %1, off sc0 sc1\n\t"
                "global_store_dword %0, %2, off offset:4 sc0 sc1\n\t"
                "global_store_dword %0, %3, off offset:8 sc0 sc1"
                :: "v"(ad), "v"(w0), "v"(w1), "v"(w2) : "memory");
        }
        __syncthreads();   // gl/ml reads done; prefetch may overwrite slots

        // ---- boundary: arrive, prefetch x tiles 0-7; no extra barriers ----
        xbt += (size_t)BATCH * DD * 2;
        pxA = xbt + aXoff;
        if (t + 1 < TT) {
            asm volatile("s_waitcnt vmcnt(0)" ::: "memory");  // h stores acked
            if (tid == 0)
                __hip_atomic_fetch_add(cntg, 1u, __ATOMIC_RELAXED, __HIP_MEMORY_SCOPE_AGENT);
            stage(0 * SLOT, 0); stage(1 * SLOT, 1); stage(2 * SLOT, 2); stage(3 * SLOT, 3);
            stage(4 * SLOT, 4); stage(5 * SLOT, 5); stage(6 * SLOT, 6); stage(7 * SLOT, 7);
            // next step's round-A WAITV + barrier provides the sync
        }
    }
}

// ---------------------------------------------------------------------------
// bf16 MFMA NT GEMM for the conv einsum tail.
// ---------------------------------------------------------------------------
template <int SPLIT>
__global__ __launch_bounds__(256, 2) void gemm_mfma(
    const __hip_bfloat16* __restrict__ A, int lda,
    const __hip_bfloat16* __restrict__ W, int ldw,
    float* __restrict__ C, int ldc, size_t cstride, int Kdim, int nbm, int nbn)
{
    __shared__ unsigned short As[2][64 * 64];
    __shared__ unsigned short Bs[2][128 * 64];

    const int nwg = nbm * nbn * SPLIT;
    const int cpx = nwg >> 3;
    const int bid = blockIdx.x;
    const int swz = (bid & 7) * cpx + (bid >> 3);
    const int z   = swz % SPLIT;
    const int t2  = swz / SPLIT;
    const int bm  = t2 % nbm;
    const int bn  = t2 / nbm;
    const int kspan = Kdim / SPLIT;

    const int tid  = threadIdx.x;
    const int lane = tid & 63;
    const int wid  = tid >> 6;
    const int wr   = wid >> 1, wc = wid & 1;
    const int kg   = lane >> 4;
    const int r15  = lane & 15;

    f32x4 acc[2][4];
#pragma unroll
    for (int m = 0; m < 2; ++m)
#pragma unroll
        for (int n = 0; n < 4; ++n) acc[m][n] = (f32x4){0.f, 0.f, 0.f, 0.f};

    const __hip_bfloat16* Abase = A + (size_t)(bm * 64) * lda + (size_t)z * kspan;
    const __hip_bfloat16* Wbase = W + (size_t)(bn * 128) * ldw + (size_t)z * kspan;

    auto stage = [&](int buf, int k0) {
        unsigned short* Ad = &As[buf][0];
        unsigned short* Bd = &Bs[buf][0];
#pragma unroll
        for (int i = 0; i < 2; ++i) {
            int c = tid + i * 256;
            int row = c >> 3, kc = c & 7;
            gload16(Abase + (size_t)row * lda + k0 + ((kc ^ (row & 7)) * 8), Ad + c * 8);
        }
#pragma unroll
        for (int i = 0; i < 4; ++i) {
            int c = tid + i * 256;
            int row = c >> 3, kc = c & 7;
            gload16(Wbase + (size_t)row * ldw + k0 + ((kc ^ (row & 7)) * 8), Bd + c * 8);
        }
    };

    const int NIT = kspan / 64;
    stage(0, 0);
    int cur = 0;
    for (int it = 0; it < NIT; ++it) {
        if (it + 1 < NIT) {
            stage(cur ^ 1, (it + 1) * 64);
            asm volatile("s_waitcnt vmcnt(6)" ::: "memory");
        } else {
            asm volatile("s_waitcnt vmcnt(0)" ::: "memory");
        }
        __builtin_amdgcn_s_barrier();

#pragma unroll
        for (int ks = 0; ks < 2; ++ks) {
            const int kb = ks * 4 + kg;
            bf16x8 af[2], bv[4];
#pragma unroll
            for (int m = 0; m < 2; ++m) {
                int ar = wr * 32 + m * 16 + r15;
                af[m] = *(const bf16x8*)&As[cur][ar * 64 + ((kb ^ (ar & 7)) * 8)];
            }
#pragma unroll
            for (int n = 0; n < 4; ++n) {
                int br = wc * 64 + n * 16 + r15;
                bv[n] = *(const bf16x8*)&Bs[cur][br * 64 + ((kb ^ (br & 7)) * 8)];
            }
#pragma unroll
            for (int m = 0; m < 2; ++m)
#pragma unroll
                for (int n = 0; n < 4; ++n)
                    acc[m][n] = __builtin_amdgcn_mfma_f32_16x16x32_bf16(
                        af[m], bv[n], acc[m][n], 0, 0, 0);
        }
        __builtin_amdgcn_s_barrier();
        cur ^= 1;
    }

    float* Cp = C + (size_t)z * cstride;
    const int crow0 = bm * 64 + wr * 32 + (lane >> 4) * 4;
    const int ccol0 = bn * 128 + wc * 64 + r15;
#pragma unroll
    for (int m = 0; m < 2; ++m)
#pragma unroll
        for (int n = 0; n < 4; ++n)
#pragma unroll
            for (int j = 0; j < 4; ++j)
                Cp[(size_t)(crow0 + m * 16 + j) * ldc + ccol0 + n * 16] = acc[m][n][j];
}

// ---------------------------------------------------------------------------
// fp32 NT GEMM for the tiny tail matmuls. MODE 2: relu ; MODE 3: sigmoid
// ---------------------------------------------------------------------------
#define BM 64
#define BN 64
#define BK 32
template <int MODE>
__global__ __launch_bounds__(256) void gemm_nt(
    const float* __restrict__ A, int lda,
    const float* __restrict__ W, int ldw,
    const float* __restrict__ bias,
    float* __restrict__ C, int ldc, int M, int N, int Kdim)
{
    __shared__ float As[BK][BM + 4];
    __shared__ float Ws[BK][BN + 4];
    const int tid = threadIdx.x;
    const int bm = blockIdx.y * BM;
    const int bn = blockIdx.x * BN;
    const int tx = tid & 15;
    const int ty = tid >> 4;

    float acc[4][4];
#pragma unroll
    for (int i = 0; i < 4; ++i)
#pragma unroll
        for (int j = 0; j < 4; ++j) acc[i][j] = 0.0f;

    for (int k0 = 0; k0 < Kdim; k0 += BK) {
#pragma unroll
        for (int i = 0; i < (BM * BK) / 256; ++i) {
            int linear = tid + i * 256;
            int r = linear >> 5, kk = linear & 31;
            As[kk][r] = A[(size_t)(bm + r) * lda + k0 + kk];
        }
#pragma unroll
        for (int i = 0; i < (BN * BK) / 256; ++i) {
            int linear = tid + i * 256;
            int r = linear >> 5, kk = linear & 31;
            int gcol = bn + r;
            Ws[kk][r] = (gcol < N) ? W[(size_t)gcol * ldw + k0 + kk] : 0.0f;
        }
        __syncthreads();
#pragma unroll
        for (int kk = 0; kk < BK; ++kk) {
            float4 a4 = *(const float4*)&As[kk][ty * 4];
            float4 b4 = *(const float4*)&Ws[kk][tx * 4];
            float av[4] = {a4.x, a4.y, a4.z, a4.w};
            float bv[4] = {b4.x, b4.y, b4.z, b4.w};
#pragma unroll
            for (int i = 0; i < 4; ++i)
#pragma unroll
                for (int j = 0; j < 4; ++j)
                    acc[i][j] = fmaf(av[i], bv[j], acc[i][j]);
        }
        __syncthreads();
    }
#pragma unroll
    for (int i = 0; i < 4; ++i) {
        int row = bm + ty * 4 + i;
#pragma unroll
        for (int j = 0; j < 4; ++j) {
            int col = bn + tx * 4 + j;
            if (col < N) {
                float v = acc[i][j] + bias[col];
                if (MODE == 2) v = fmaxf(v, 0.0f);
                if (MODE == 3) v = sigf(v);
                C[(size_t)row * ldc + col] = v;
            }
        }
    }
}

// ---------------------------------------------------------------------------
__global__ __launch_bounds__(256) void window_kernel(
    const float* __restrict__ dist_out, float* __restrict__ ld)
{
    int b = blockIdx.x * blockDim.x + threadIdx.x;
    if (b >= BATCH) return;
    float w[KCONV];
    float run = 0.0f, m = -1e30f;
#pragma unroll
    for (int k = 0; k < KCONV; ++k) {
        run += dist_out[(size_t)(TT - KCONV + k) * BATCH + b];
        w[k] = run;
        m = fmaxf(m, run);
    }
    float s = 0.0f;
#pragma unroll
    for (int k = 0; k < KCONV; ++k) { w[k] = expf(w[k] - m); s += w[k]; }
    float inv = 1.0f / s;
#pragma unroll
    for (int k = 0; k < KCONV; ++k) ld[b * KCONV + k] = w[k] * inv;
}

__global__ __launch_bounds__(256) void localh_kernel(
    const float* __restrict__ hwin, const float* __restrict__ ld,
    __hip_bfloat16* __restrict__ Lhb, float* __restrict__ mh)
{
    int idx = blockIdx.x * 256 + threadIdx.x;
    int b = idx / HH;
    int e = idx - b * HH;
    float lv[KCONV];
#pragma unroll
    for (int k = 0; k < KCONV; ++k) lv[k] = ld[b * KCONV + k];
    float sum = 0.0f;
#pragma unroll
    for (int k = 0; k < KCONV; ++k) {
        int slot = (TT - KCONV + k) % KCONV;
        float v = hwin[(size_t)slot * BATCH * HH + (size_t)b * HH + e] * lv[k];
        Lhb[(size_t)b * (HH * KCONV) + e * KCONV + k] = __hip_bfloat16(v);
        sum += v;
    }
    mh[idx] = sum * (1.0f / KCONV);
}

__global__ __launch_bounds__(256) void out_kernel(
    const float* __restrict__ theme, const float* __restrict__ convp, size_t cstride,
    const float* __restrict__ conv_b, const float* __restrict__ hbuf,
    const float* __restrict__ out_w, const float* __restrict__ out_b,
    float* __restrict__ out)
{
    __shared__ float red[256];
    int b = blockIdx.x;
    float p = 0.0f;
    for (int e = threadIdx.x; e < HH; e += 256) {
        float cv = conv_b[e];
#pragma unroll
        for (int zz = 0; zz < 2; ++zz)
            cv += convp[(size_t)zz * cstride + (size_t)b * HH + e];
        p += (theme[(size_t)b * HH + e] * cv + hbuf[(size_t)b * HH + e]) * out_w[e];
    }
    red[threadIdx.x] = p;
    __syncthreads();
    for (int s = 128; s > 0; s >>= 1) {
        if (threadIdx.x < s) red[threadIdx.x] += red[threadIdx.x + s];
        __syncthreads();
    }
    if (threadIdx.x == 0) out[b] = sigf(red[0] + out_b[0]);
}

// ---------------------------------------------------------------------------
extern "C" void kernel_launch(void* const* d_in, const int* in_sizes, int n_in,
                              void* d_out, int out_size, void* d_ws, size_t ws_size,
                              hipStream_t stream)
{
    const float* x       = (const float*)d_in[0];
    const float* timep   = (const float*)d_in[1];
    const float* kw      = (const float*)d_in[2];
    const float* kb      = (const float*)d_in[3];
    const float* rw      = (const float*)d_in[4];
    const float* rb      = (const float*)d_in[5];
    const float* scale_w = (const float*)d_in[6];
    const float* scale_b = (const float*)d_in[7];
    const float* resc_w  = (const float*)d_in[8];
    const float* resc_b  = (const float*)d_in[9];
    const float* conv_w  = (const float*)d_in[10];
    const float* conv_b  = (const float*)d_in[11];
    const float* out_w   = (const float*)d_in[12];
    const float* out_b   = (const float*)d_in[13];

    float* outp  = (float*)d_out;
    float* distp = outp + BATCH;

    char* cur = (char*)d_ws;
    auto carve = [&](size_t bytes) {
        char* p = cur;
        cur += (bytes + 255) & ~(size_t)255;
        return (void*)p;
    };
    __hip_bfloat16* W4     = (__hip_bfloat16*)carve((size_t)G4 * KPACK * 2);
    __hip_bfloat16* Wm     = (__hip_bfloat16*)carve((size_t)16 * KPACK * 2);
    __hip_bfloat16* xb     = (__hip_bfloat16*)carve((size_t)TT * BATCH * DD * 2);
    __hip_bfloat16* Hb0    = (__hip_bfloat16*)carve((size_t)BATCH * HH * 2);
    __hip_bfloat16* Hb1    = (__hip_bfloat16*)carve((size_t)BATCH * HH * 2);
    __hip_bfloat16* Lhb    = (__hip_bfloat16*)carve((size_t)BATCH * HH * KCONV * 2);
    __hip_bfloat16* convwb = (__hip_bfloat16*)carve((size_t)HH * HH * KCONV * 2);
    float* bias4 = (float*)carve(G4 * 4);
    float* tco4  = (float*)carve(G4 * 4);
    float* mbias = (float*)carve(64);
    float* mtco  = (float*)carve(64);
    unsigned* cnt = (unsigned*)carve(4096);   // 16 group counters, 256B apart
    float* hwin  = (float*)carve((size_t)KCONV * BATCH * HH * 4);
    float* ld    = (float*)carve((size_t)BATCH * KCONV * 4);
    float* mh    = (float*)carve((size_t)BATCH * HH * 4);
    float* s1    = (float*)carve((size_t)BATCH * CHW * 4);
    float* theme = (float*)carve((size_t)BATCH * HH * 4);
    float* convp = (float*)carve(2 * (size_t)BATCH * HH * 4);

    hipMemsetAsync(cnt, 0, 4096, stream);
    hipMemsetAsync(Hb0, 0, (size_t)BATCH * HH * 2, stream);
    prep_w4<<<G4, 256, 0, stream>>>(kw, kb, rw, rb, W4, bias4, tco4);
    prep_wm<<<16, 256, 0, stream>>>(kw, kb, rw, rb, Wm, mbias, mtco);
    cvt_kernel<<<(HH * HH * KCONV + 255) / 256, 256, 0, stream>>>(
        conv_w, convwb, HH * HH * KCONV);
    xcvt_kernel<<<(TT * BATCH * DD / 8 + 255) / 256, 256, 0, stream>>>(x, xb);

    // persistent cooperative recurrence (all TT steps)
    {
        void* args[] = {
            (void*)&Hb0, (void*)&Hb1, (void*)&xb, (void*)&timep,
            (void*)&W4, (void*)&Wm, (void*)&bias4, (void*)&tco4,
            (void*)&mbias, (void*)&mtco, (void*)&hwin, (void*)&distp,
            (void*)&cnt
        };
        hipLaunchCooperativeKernel((void*)persist_kernel, dim3(256), dim3(512),
                                   args, 0, stream);
    }

    window_kernel<<<(BATCH + 255) / 256, 256, 0, stream>>>(distp, ld);
    localh_kernel<<<(BATCH * HH) / 256, 256, 0, stream>>>(hwin, ld, Lhb, mh);

    // conv einsum: [B,7680]bf16 x [768,7680]bf16^T, K-split x2
    gemm_mfma<2><<<16 * 6 * 2, 256, 0, stream>>>(
        Lhb, HH * KCONV, convwb, HH * KCONV, convp, HH, (size_t)BATCH * HH,
        HH * KCONV, 16, 6);
    // scale (relu): [B,768] x [128,768]^T
    gemm_nt<2><<<dim3(CHW / BN, BATCH / BM), 256, 0, stream>>>(
        mh, HH, scale_w, HH, scale_b, s1, CHW, BATCH, CHW, HH);
    // rescale (sigmoid): [B,128] x [768,128]^T
    gemm_nt<3><<<dim3(HH / BN, BATCH / BM), 256, 0, stream>>>(
        s1, CHW, resc_w, CHW, resc_b, theme, HH, BATCH, HH, CHW);

    out_kernel<<<BATCH, 256, 0, stream>>>(
        theme, convp, (size_t)BATCH * HH, conv_b,
        hwin + (size_t)((TT - 1) % KCONV) * BATCH * HH,   // h_last
        out_w, out_b, outp);
}